// Round 1
// baseline (756.734 us; speedup 1.0000x reference)
//
#include <hip/hip_runtime.h>

// ---------------- constants ----------------
// N=50000 nodes, E=800000 edges, F_in=128, heads=4, C1=32 (concat->128), C2=64 (mean->64)

__device__ __forceinline__ float leakyrelu(float x) { return x >= 0.f ? x : 0.2f * x; }

// ---------------- dtype detection ----------------
// edge_index: int64 vs int32 storage. If int64 (little-endian), odd 32-bit words
// of the first 64 entries are all zero (node ids < 50000).
__global__ void detect_int_kernel(const int* __restrict__ ei, int* __restrict__ flag) {
    if (threadIdx.x == 0 && blockIdx.x == 0) {
        int allz = 1;
        for (int i = 0; i < 64; ++i) if (ei[2 * i + 1] != 0) { allz = 0; break; }
        *flag = allz;  // 1 => int64 storage
    }
}

// float inputs: bf16 vs f32 storage. For f32 storage, the low uint16 of each f32
// is random mantissa bits (~14% land in a sane bf16 exponent range); for bf16
// storage every uint16 is a genuine bf16 value (~100% sane for N(0,1)-ish data).
__global__ void detect_f_kernel(const void* __restrict__ xin, int* __restrict__ flagBF) {
    if (threadIdx.x == 0 && blockIdx.x == 0) {
        const unsigned short* u = (const unsigned short*)xin;
        int sane = 0;
        for (int i = 0; i < 256; ++i) {
            unsigned short v = u[2 * i];
            int ex = (v >> 7) & 0xFF;
            if (v == 0 || (ex >= 100 && ex <= 135)) sane++;
        }
        *flagBF = (sane >= 230) ? 1 : 0;  // 1 => bf16 storage
    }
}

// convert (bf16 or f32) -> f32
__global__ void cvt_kernel(const void* __restrict__ in, float* __restrict__ outp, int n,
                           const int* __restrict__ flagBF) {
    int i = blockIdx.x * blockDim.x + threadIdx.x;
    if (i >= n) return;
    if (*flagBF) {
        const unsigned short* u = (const unsigned short*)in;
        unsigned int w = ((unsigned int)u[i]) << 16;
        outp[i] = __uint_as_float(w);
    } else {
        outp[i] = ((const float*)in)[i];
    }
}

// ---------------- edge decode ----------------
__device__ __forceinline__ void edge_sd(const int* __restrict__ ei, int E, int e, int is64,
                                        int& src, int& dst) {
    if (e >= E) { src = dst = e - E; return; }  // self loops appended after edges
    if (is64) { src = ei[2 * e]; dst = ei[2 * E + 2 * e]; }
    else      { src = ei[e];     dst = ei[E + e]; }
}

// ---------------- CSR build ----------------
__global__ void hist_kernel(const int* __restrict__ ei, int E, int N,
                            const int* __restrict__ flag, int* __restrict__ deg) {
    int e = blockIdx.x * blockDim.x + threadIdx.x;
    if (e >= E + N) return;
    int src, dst; edge_sd(ei, E, e, *flag, src, dst);
    atomicAdd(&deg[dst], 1);
}

__global__ __launch_bounds__(1024) void scan_kernel(const int* __restrict__ deg,
                                                    int* __restrict__ rowptr, int n) {
    __shared__ int sm[1024];
    __shared__ int carry_s;
    int tid = threadIdx.x;
    if (tid == 0) carry_s = 0;
    __syncthreads();
    for (int base = 0; base < n; base += 1024) {
        int i = base + tid;
        int v = (i < n) ? deg[i] : 0;
        sm[tid] = v;
        __syncthreads();
        for (int off = 1; off < 1024; off <<= 1) {
            int t = (tid >= off) ? sm[tid - off] : 0;
            __syncthreads();
            sm[tid] += t;
            __syncthreads();
        }
        int carry = carry_s;
        if (i < n) rowptr[i] = carry + sm[tid] - v;  // exclusive
        __syncthreads();
        if (tid == 1023) carry_s = carry + sm[1023];
        __syncthreads();
    }
    if (tid == 0) rowptr[n] = carry_s;
}

__global__ void scatter_kernel(const int* __restrict__ ei, int E, int N,
                               const int* __restrict__ flag, const int* __restrict__ rowptr,
                               int* __restrict__ cnt, int* __restrict__ ecol) {
    int e = blockIdx.x * blockDim.x + threadIdx.x;
    if (e >= E + N) return;
    int src, dst; edge_sd(ei, E, e, *flag, src, dst);
    int pos = rowptr[dst] + atomicAdd(&cnt[dst], 1);
    ecol[pos] = src;
}

// ---------------- GEMM (f32, 64x64x32 tiles, 256 threads, 4x4 microtile) ----------------
#define BM 64
#define BN 64
#define BK 32
__global__ __launch_bounds__(256) void gemm_kernel(const float* __restrict__ A,
                                                   const float* __restrict__ B,
                                                   float* __restrict__ C, int M, int N, int K) {
    __shared__ float As[BK][BM + 1];  // +1 pad: kills 32-way bank conflict on the transposed store
    __shared__ float Bs[BK][BN];
    int tid = threadIdx.x;
    int tx = tid & 15, ty = tid >> 4;
    int bm = blockIdx.x * BM, bn = blockIdx.y * BN;
    float acc[4][4] = {};
    for (int k0 = 0; k0 < K; k0 += BK) {
#pragma unroll
        for (int i = 0; i < (BM * BK) / 256; ++i) {
            int idx = tid + i * 256;
            int m = idx >> 5, kk = idx & 31;
            int row = bm + m;
            As[kk][m] = (row < M) ? A[(size_t)row * K + k0 + kk] : 0.f;
        }
#pragma unroll
        for (int i = 0; i < (BK * BN) / 256; ++i) {
            int idx = tid + i * 256;
            int kk = idx >> 6, nn = idx & 63;
            Bs[kk][nn] = B[(size_t)(k0 + kk) * N + bn + nn];
        }
        __syncthreads();
#pragma unroll
        for (int kk = 0; kk < BK; ++kk) {
            float a[4], b[4];
#pragma unroll
            for (int i = 0; i < 4; ++i) a[i] = As[kk][ty * 4 + i];
#pragma unroll
            for (int j = 0; j < 4; ++j) b[j] = Bs[kk][tx * 4 + j];
#pragma unroll
            for (int i = 0; i < 4; ++i)
#pragma unroll
                for (int j = 0; j < 4; ++j) acc[i][j] = fmaf(a[i], b[j], acc[i][j]);
        }
        __syncthreads();
    }
#pragma unroll
    for (int i = 0; i < 4; ++i) {
        int row = bm + ty * 4 + i;
        if (row < M) {
#pragma unroll
            for (int j = 0; j < 4; ++j) C[(size_t)row * N + bn + tx * 4 + j] = acc[i][j];
        }
    }
}

// ---------------- attention dot products: a_src[n,h] = sum_c h[n,h,c]*att_src[h,c] ----------------
template <int C>
__global__ __launch_bounds__(C * 4) void attdot_kernel(const float* __restrict__ h,
                                                       const float* __restrict__ att_src,
                                                       const float* __restrict__ att_dst,
                                                       float* __restrict__ a_src,
                                                       float* __restrict__ a_dst) {
    constexpr int HC = C * 4;
    __shared__ float rs[HC], rd[HC];
    int n = blockIdx.x, tid = threadIdx.x;
    float v = h[(size_t)n * HC + tid];
    rs[tid] = v * att_src[tid];
    rd[tid] = v * att_dst[tid];
    __syncthreads();
    for (int off = C / 2; off > 0; off >>= 1) {
        if ((tid & (C - 1)) < off) { rs[tid] += rs[tid + off]; rd[tid] += rd[tid + off]; }
        __syncthreads();
    }
    if ((tid & (C - 1)) == 0) {
        int hh = tid / C;
        a_src[(size_t)n * 4 + hh] = rs[tid];
        a_dst[(size_t)n * 4 + hh] = rd[tid];
    }
}

// ---------------- per-node softmax + weighted aggregate ----------------
// block = one dst node, HC threads (thread = h*C + c). Exact segment max -> sum -> gather.
template <int C, bool CONCAT>
__global__ __launch_bounds__(C * 4) void aggregate_kernel(
    const float* __restrict__ hsrc, const float4* __restrict__ a_src4,
    const float4* __restrict__ a_dst4, const int* __restrict__ rowptr,
    const int* __restrict__ ecol, const float* __restrict__ bias, float* __restrict__ out) {
    constexpr int HC = C * 4;
    constexpr int CHUNK = 64;
    __shared__ float red[HC * 4];
    __shared__ float al[CHUNK * 4];
    __shared__ int si[CHUNK];
    __shared__ float m_s[4], inv_s[4];

    int n = blockIdx.x;
    int tid = threadIdx.x;
    int hh = tid / C;
    int start = rowptr[n], end = rowptr[n + 1];

    float4 ad4 = a_dst4[n];
    float adst_r[4] = {ad4.x, ad4.y, ad4.z, ad4.w};

    // pass A: per-head max over incoming edges
    float lm[4] = {-1e30f, -1e30f, -1e30f, -1e30f};
    for (int j = start + tid; j < end; j += HC) {
        int s = ecol[j];
        float4 as4 = a_src4[s];
        lm[0] = fmaxf(lm[0], leakyrelu(as4.x + adst_r[0]));
        lm[1] = fmaxf(lm[1], leakyrelu(as4.y + adst_r[1]));
        lm[2] = fmaxf(lm[2], leakyrelu(as4.z + adst_r[2]));
        lm[3] = fmaxf(lm[3], leakyrelu(as4.w + adst_r[3]));
    }
#pragma unroll
    for (int h2 = 0; h2 < 4; ++h2) red[h2 * HC + tid] = lm[h2];
    __syncthreads();
    for (int off = HC / 2; off > 0; off >>= 1) {
        if (tid < off) {
#pragma unroll
            for (int h2 = 0; h2 < 4; ++h2)
                red[h2 * HC + tid] = fmaxf(red[h2 * HC + tid], red[h2 * HC + tid + off]);
        }
        __syncthreads();
    }
    if (tid < 4) m_s[tid] = red[tid * HC];
    __syncthreads();
    float m_r[4] = {m_s[0], m_s[1], m_s[2], m_s[3]};
    __syncthreads();

    // pass B: per-head sum of exp(logit - m)
    float ls[4] = {0.f, 0.f, 0.f, 0.f};
    for (int j = start + tid; j < end; j += HC) {
        int s = ecol[j];
        float4 as4 = a_src4[s];
        ls[0] += __expf(leakyrelu(as4.x + adst_r[0]) - m_r[0]);
        ls[1] += __expf(leakyrelu(as4.y + adst_r[1]) - m_r[1]);
        ls[2] += __expf(leakyrelu(as4.z + adst_r[2]) - m_r[2]);
        ls[3] += __expf(leakyrelu(as4.w + adst_r[3]) - m_r[3]);
    }
#pragma unroll
    for (int h2 = 0; h2 < 4; ++h2) red[h2 * HC + tid] = ls[h2];
    __syncthreads();
    for (int off = HC / 2; off > 0; off >>= 1) {
        if (tid < off) {
#pragma unroll
            for (int h2 = 0; h2 < 4; ++h2) red[h2 * HC + tid] += red[h2 * HC + tid + off];
        }
        __syncthreads();
    }
    if (tid < 4) inv_s[tid] = 1.f / (red[tid * HC] + 1e-16f);
    __syncthreads();
    float inv_r[4] = {inv_s[0], inv_s[1], inv_s[2], inv_s[3]};
    __syncthreads();

    // pass C: alpha per chunk into LDS, then weighted gather of h[src] rows
    float acc = 0.f;
    for (int cs = start; cs < end; cs += CHUNK) {
        int len = min(CHUNK, end - cs);
        if (tid < len) {
            int s = ecol[cs + tid];
            si[tid] = s;
            float4 as4 = a_src4[s];
            al[tid * 4 + 0] = __expf(leakyrelu(as4.x + adst_r[0]) - m_r[0]) * inv_r[0];
            al[tid * 4 + 1] = __expf(leakyrelu(as4.y + adst_r[1]) - m_r[1]) * inv_r[1];
            al[tid * 4 + 2] = __expf(leakyrelu(as4.z + adst_r[2]) - m_r[2]) * inv_r[2];
            al[tid * 4 + 3] = __expf(leakyrelu(as4.w + adst_r[3]) - m_r[3]) * inv_r[3];
        }
        __syncthreads();
        for (int e2 = 0; e2 < len; ++e2) {
            float w = al[e2 * 4 + hh];
            acc = fmaf(w, hsrc[(size_t)si[e2] * HC + tid], acc);
        }
        __syncthreads();
    }

    if (CONCAT) {
        float o = acc + bias[tid];
        o = o > 0.f ? o : (__expf(o) - 1.f);  // ELU fused (next layer's input)
        out[(size_t)n * HC + tid] = o;
    } else {
        red[tid] = acc;
        __syncthreads();
        if (tid < C) {
            float o = 0.25f * (red[tid] + red[tid + C] + red[tid + 2 * C] + red[tid + 3 * C]) + bias[tid];
            out[(size_t)n * C + tid] = o;
        }
    }
}

// ---------------- launch ----------------
extern "C" void kernel_launch(void* const* d_in, const int* in_sizes, int n_in,
                              void* d_out, int out_size, void* d_ws, size_t ws_size,
                              hipStream_t stream) {
    const void* x_raw   = d_in[0];
    const int*  ei      = (const int*)d_in[1];
    const void* W1_raw  = d_in[2];
    const void* as1_raw = d_in[3];
    const void* ad1_raw = d_in[4];
    const void* b1_raw  = d_in[5];
    const void* W2_raw  = d_in[6];
    const void* as2_raw = d_in[7];
    const void* ad2_raw = d_in[8];
    const void* b2_raw  = d_in[9];
    float* out = (float*)d_out;

    const int F_IN = 128, HC1 = 128, HC2 = 256;
    const int N = in_sizes[0] / F_IN;   // 50000
    const int E = in_sizes[1] / 2;      // 800000
    const int ET = E + N;               // + self loops

    char* p = (char*)d_ws;
    auto alloc = [&](size_t bytes) { char* r = p; p += (bytes + 255) & ~(size_t)255; return r; };
    float* xf    = (float*)alloc((size_t)N * F_IN * 4);
    float* W1f   = (float*)alloc((size_t)F_IN * HC1 * 4);
    float* W2f   = (float*)alloc((size_t)HC1 * HC2 * 4);
    float* att1f = (float*)alloc(4 * HC1 * 4);   // att_src1 | att_dst1 packed: 2*128 floats
    float* att2f = (float*)alloc(4 * HC2 * 4);   // att_src2 | att_dst2
    float* b1f   = (float*)alloc(HC1 * 4);
    float* b2f   = (float*)alloc(64 * 4);
    float* h1    = (float*)alloc((size_t)N * HC1 * 4);
    float* hL1   = (float*)alloc((size_t)N * HC1 * 4);
    float* h2    = (float*)alloc((size_t)N * HC2 * 4);
    float* asrc1 = (float*)alloc((size_t)N * 4 * 4);
    float* adst1 = (float*)alloc((size_t)N * 4 * 4);
    float* asrc2 = (float*)alloc((size_t)N * 4 * 4);
    float* adst2 = (float*)alloc((size_t)N * 4 * 4);
    int* deg    = (int*)alloc((size_t)N * 4);
    int* rowptr = (int*)alloc((size_t)(N + 1) * 4);
    int* cnt    = (int*)alloc((size_t)N * 4);
    int* ecol   = (int*)alloc((size_t)ET * 4);
    int* flagI  = (int*)alloc(256);
    int* flagF  = (int*)alloc(256);

    hipMemsetAsync(deg, 0, (size_t)N * 4, stream);
    hipMemsetAsync(cnt, 0, (size_t)N * 4, stream);

    detect_int_kernel<<<1, 64, 0, stream>>>(ei, flagI);
    detect_f_kernel<<<1, 64, 0, stream>>>(x_raw, flagF);

    // up-convert float inputs (bf16 or f32 storage) to f32 scratch
    auto cvt = [&](const void* src, float* dst, int n) {
        cvt_kernel<<<(n + 255) / 256, 256, 0, stream>>>(src, dst, n, flagF);
    };
    cvt(x_raw, xf, N * F_IN);
    cvt(W1_raw, W1f, F_IN * HC1);
    cvt(W2_raw, W2f, HC1 * HC2);
    cvt(as1_raw, att1f, HC1);
    cvt(ad1_raw, att1f + HC1, HC1);
    cvt(as2_raw, att2f, HC2);
    cvt(ad2_raw, att2f + HC2, HC2);
    cvt(b1_raw, b1f, HC1);
    cvt(b2_raw, b2f, 64);

    // CSR (shared by both layers)
    int eblocks = (ET + 255) / 256;
    hist_kernel<<<eblocks, 256, 0, stream>>>(ei, E, N, flagI, deg);
    scan_kernel<<<1, 1024, 0, stream>>>(deg, rowptr, N);
    scatter_kernel<<<eblocks, 256, 0, stream>>>(ei, E, N, flagI, rowptr, cnt, ecol);

    // ---- layer 1 ----
    gemm_kernel<<<dim3((N + BM - 1) / BM, HC1 / BN), 256, 0, stream>>>(xf, W1f, h1, N, HC1, F_IN);
    attdot_kernel<32><<<N, 128, 0, stream>>>(h1, att1f, att1f + HC1, asrc1, adst1);
    aggregate_kernel<32, true><<<N, 128, 0, stream>>>(h1, (const float4*)asrc1,
                                                      (const float4*)adst1, rowptr, ecol, b1f, hL1);

    // ---- layer 2 ----
    gemm_kernel<<<dim3((N + BM - 1) / BM, HC2 / BN), 256, 0, stream>>>(hL1, W2f, h2, N, HC2, HC1);
    attdot_kernel<64><<<N, 256, 0, stream>>>(h2, att2f, att2f + HC2, asrc2, adst2);
    aggregate_kernel<64, false><<<N, 256, 0, stream>>>(h2, (const float4*)asrc2,
                                                       (const float4*)adst2, rowptr, ecol, b2f, out);
}

// Round 2
// 446.479 us; speedup vs baseline: 1.6949x; 1.6949x over previous
//
#include <hip/hip_runtime.h>

typedef unsigned int uint;
typedef unsigned short ushort;

// N=50000 nodes, E=800000 edges, F_in=128, heads=4, C1=32 (concat->128), C2=64 (mean->64)
// Both GEMMs have K=128.

__device__ __forceinline__ float leaky(float x) { return x >= 0.f ? x : 0.2f * x; }
__device__ __forceinline__ float b2f(ushort h) { return __uint_as_float(((uint)h) << 16); }
__device__ __forceinline__ ushort f2b(float f) {
    uint u = __float_as_uint(f);
    return (ushort)((u + 0x7FFF + ((u >> 16) & 1)) >> 16);  // RNE
}
__device__ __forceinline__ float rdlane_f(float x, int l) {
    return __int_as_float(__builtin_amdgcn_readlane(__float_as_int(x), l));
}

// ---------------- dtype detection (device-side; flags live in ws) ----------------
__global__ void detect_int_kernel(const int* __restrict__ ei, int* __restrict__ flag) {
    if (threadIdx.x == 0 && blockIdx.x == 0) {
        int allz = 1;
        for (int i = 0; i < 64; ++i) if (ei[2 * i + 1] != 0) { allz = 0; break; }
        *flag = allz;  // 1 => int64 storage
    }
}
__global__ void detect_f_kernel(const void* __restrict__ xin, int* __restrict__ flagBF) {
    if (threadIdx.x == 0 && blockIdx.x == 0) {
        const ushort* u = (const ushort*)xin;
        int sane = 0;
        for (int i = 0; i < 256; ++i) {
            ushort v = u[2 * i];
            int ex = (v >> 7) & 0xFF;
            if (v == 0 || (ex >= 100 && ex <= 135)) sane++;
        }
        *flagBF = (sane >= 230) ? 1 : 0;  // 1 => bf16 storage
    }
}

// (bf16|f32) -> f32 (small arrays: att vectors, biases)
__global__ void cvt_kernel(const void* __restrict__ in, float* __restrict__ outp, int n,
                           const int* __restrict__ flagBF) {
    int i = blockIdx.x * blockDim.x + threadIdx.x;
    if (i >= n) return;
    if (*flagBF) outp[i] = b2f(((const ushort*)in)[i]);
    else         outp[i] = ((const float*)in)[i];
}

// (bf16|f32) -> bf16 (x)
__global__ void cvt_bf_kernel(const void* __restrict__ in, ushort* __restrict__ outp, int n,
                              const int* __restrict__ flagBF) {
    int i = blockIdx.x * blockDim.x + threadIdx.x;
    if (i >= n) return;
    if (*flagBF) outp[i] = ((const ushort*)in)[i];
    else         outp[i] = f2b(((const float*)in)[i]);
}

// W [K][N] (bf16|f32) -> WT [N][K] bf16
__global__ void transpose_bf_kernel(const void* __restrict__ W, ushort* __restrict__ WT,
                                    int K, int N, const int* __restrict__ flagBF) {
    int idx = blockIdx.x * blockDim.x + threadIdx.x;
    if (idx >= K * N) return;
    int k = idx / N, n = idx % N;
    ushort v = (*flagBF) ? ((const ushort*)W)[idx] : f2b(((const float*)W)[idx]);
    WT[(size_t)n * K + k] = v;
}

// ---------------- edge decode + CSR build ----------------
__device__ __forceinline__ void edge_sd(const int* __restrict__ ei, int E, int e, int is64,
                                        int& src, int& dst) {
    if (e >= E) { src = dst = e - E; return; }  // self loops appended after edges
    if (is64) { src = ei[2 * e]; dst = ei[2 * E + 2 * e]; }
    else      { src = ei[e];     dst = ei[E + e]; }
}

__global__ void hist_kernel(const int* __restrict__ ei, int E, int N,
                            const int* __restrict__ flag, int* __restrict__ deg) {
    int e = blockIdx.x * blockDim.x + threadIdx.x;
    if (e >= E + N) return;
    int src, dst; edge_sd(ei, E, e, *flag, src, dst);
    atomicAdd(&deg[dst], 1);
}

__global__ __launch_bounds__(1024) void scan1_kernel(const int* __restrict__ deg,
                                                     int* __restrict__ tmp,
                                                     int* __restrict__ bsum, int n) {
    __shared__ int sm[1024];
    int tid = threadIdx.x, i = blockIdx.x * 1024 + tid;
    int v = (i < n) ? deg[i] : 0;
    sm[tid] = v;
    __syncthreads();
    for (int off = 1; off < 1024; off <<= 1) {
        int t = (tid >= off) ? sm[tid - off] : 0;
        __syncthreads();
        sm[tid] += t;
        __syncthreads();
    }
    if (i < n) tmp[i] = sm[tid] - v;  // exclusive
    if (tid == 1023) bsum[blockIdx.x] = sm[1023];
}

__global__ void scan2_kernel(int* __restrict__ bsum, int nb) {  // 1 block, 64 threads, nb<=64
    int lane = threadIdx.x;
    int v = (lane < nb) ? bsum[lane] : 0;
    int incl = v;
    for (int off = 1; off < 64; off <<= 1) {
        int t = __shfl_up(incl, off, 64);
        if (lane >= off) incl += t;
    }
    int total = __shfl(incl, nb - 1, 64);
    if (lane < nb) bsum[lane] = incl - v;  // exclusive
    if (lane == 0) bsum[nb] = total;
}

__global__ void scan3_kernel(const int* __restrict__ tmp, const int* __restrict__ bsum,
                             int* __restrict__ rowptr, int n, int nb) {
    int i = blockIdx.x * blockDim.x + threadIdx.x;
    if (i > n) return;
    rowptr[i] = (i == n) ? bsum[nb] : tmp[i] + bsum[i >> 10];
}

__global__ void scatter_kernel(const int* __restrict__ ei, int E, int N,
                               const int* __restrict__ flag, const int* __restrict__ rowptr,
                               int* __restrict__ cnt, int* __restrict__ ecol) {
    int e = blockIdx.x * blockDim.x + threadIdx.x;
    if (e >= E + N) return;
    int src, dst; edge_sd(ei, E, e, *flag, src, dst);
    int pos = rowptr[dst] + atomicAdd(&cnt[dst], 1);
    ecol[pos] = src;
}

// ---------------- MFMA GEMM: C[M][HC] = A[M][128] @ B, with BT[HC][128], all bf16 ----------------
typedef __attribute__((ext_vector_type(8))) short bf16x8;   // 8 bf16 = 4 VGPRs
typedef __attribute__((ext_vector_type(4))) float floatx4;

template <int HC>
__global__ __launch_bounds__(256) void gemm_mfma_kernel(const ushort* __restrict__ A,
                                                        const ushort* __restrict__ BT,
                                                        ushort* __restrict__ C, int M) {
    constexpr int K = 128;
    constexpr int NT = HC / 16;
    int lane = threadIdx.x & 63, wv = threadIdx.x >> 6;
    int row0 = (blockIdx.x * 4 + wv) * 16;
    if (row0 >= M) return;
    int m = lane & 15, quad = lane >> 4;
    // A fragment: lane holds A[row0+m][k0 + quad*8 .. +7]  (16B contiguous)
    const bf16x8* arow = (const bf16x8*)(A + (size_t)(row0 + m) * K);
    bf16x8 af[4];
#pragma unroll
    for (int kk = 0; kk < 4; ++kk) af[kk] = arow[4 * kk + quad];
    floatx4 acc[NT] = {};
#pragma unroll
    for (int nt = 0; nt < NT; ++nt) {
        const bf16x8* brow = (const bf16x8*)(BT + (size_t)(nt * 16 + m) * K);
#pragma unroll
        for (int kk = 0; kk < 4; ++kk) {
            bf16x8 bf_ = brow[4 * kk + quad];
            acc[nt] = __builtin_amdgcn_mfma_f32_16x16x32_bf16(af[kk], bf_, acc[nt], 0, 0, 0);
        }
    }
    // C/D layout: col = lane&15, row = quad*4 + reg   [verified mapping]
#pragma unroll
    for (int nt = 0; nt < NT; ++nt)
#pragma unroll
        for (int r = 0; r < 4; ++r)
            C[(size_t)(row0 + quad * 4 + r) * HC + nt * 16 + m] = f2b(acc[nt][r]);
}

// ---------------- attention dots: wave per node ----------------
template <int HC>
__global__ __launch_bounds__(256) void attdot_kernel(const ushort* __restrict__ h,
                                                     const float* __restrict__ att,  // src[HC]|dst[HC]
                                                     float* __restrict__ a_src,
                                                     float* __restrict__ a_dst, int N) {
    constexpr int VEC = HC / 64;
    int lane = threadIdx.x & 63, wv = threadIdx.x >> 6;
    int n = blockIdx.x * 4 + wv;
    if (n >= N) return;
    float ds = 0.f, dd = 0.f;
    const ushort* hp = h + (size_t)n * HC + lane * VEC;
#pragma unroll
    for (int i = 0; i < VEC; ++i) {
        float v = b2f(hp[i]);
        ds = fmaf(v, att[lane * VEC + i], ds);
        dd = fmaf(v, att[HC + lane * VEC + i], dd);
    }
#pragma unroll
    for (int off = 1; off < 16; off <<= 1) {
        ds += __shfl_xor(ds, off, 64);
        dd += __shfl_xor(dd, off, 64);
    }
    if ((lane & 15) == 0) {
        int hh = lane >> 4;
        a_src[(size_t)n * 4 + hh] = ds;
        a_dst[(size_t)n * 4 + hh] = dd;
    }
}

// ---------------- aggregate: wave per node, shuffle softmax, vectorized bf16 gather ----------------
template <int HC, bool CONCAT>
__global__ __launch_bounds__(256) void aggregate_kernel(
    const ushort* __restrict__ hsrc, const float4* __restrict__ a_src4,
    const float4* __restrict__ a_dst4, const int* __restrict__ rowptr,
    const int* __restrict__ ecol, const float* __restrict__ bias,
    void* __restrict__ outv, int N) {
    constexpr int VEC = HC / 64;  // channels per lane (2 or 4)
    int lane = threadIdx.x & 63, wv = threadIdx.x >> 6;
    int n = blockIdx.x * 4 + wv;
    if (n >= N) return;
    int start = rowptr[n], end = rowptr[n + 1];
    float4 ad = a_dst4[n];
    int hh = lane >> 4;  // head owning this lane's channels

    // pass 1: per-head max over edges
    float m0 = -1e30f, m1 = -1e30f, m2 = -1e30f, m3 = -1e30f;
    for (int cs = start; cs < end; cs += 64) {
        int j = cs + lane;
        bool v = j < end;
        int s = v ? ecol[j] : 0;
        float4 as = a_src4[s];
        float l0 = v ? leaky(as.x + ad.x) : -1e30f;
        float l1 = v ? leaky(as.y + ad.y) : -1e30f;
        float l2 = v ? leaky(as.z + ad.z) : -1e30f;
        float l3 = v ? leaky(as.w + ad.w) : -1e30f;
        m0 = fmaxf(m0, l0); m1 = fmaxf(m1, l1); m2 = fmaxf(m2, l2); m3 = fmaxf(m3, l3);
    }
#pragma unroll
    for (int off = 1; off < 64; off <<= 1) {
        m0 = fmaxf(m0, __shfl_xor(m0, off, 64));
        m1 = fmaxf(m1, __shfl_xor(m1, off, 64));
        m2 = fmaxf(m2, __shfl_xor(m2, off, 64));
        m3 = fmaxf(m3, __shfl_xor(m3, off, 64));
    }
    // pass 2: per-head sum of exp
    float s0 = 0.f, s1 = 0.f, s2 = 0.f, s3 = 0.f;
    for (int cs = start; cs < end; cs += 64) {
        int j = cs + lane;
        bool v = j < end;
        int s = v ? ecol[j] : 0;
        float4 as = a_src4[s];
        // invalid lanes: exp(-1e30 - m) flushes to 0
        s0 += __expf((v ? leaky(as.x + ad.x) : -1e30f) - m0);
        s1 += __expf((v ? leaky(as.y + ad.y) : -1e30f) - m1);
        s2 += __expf((v ? leaky(as.z + ad.z) : -1e30f) - m2);
        s3 += __expf((v ? leaky(as.w + ad.w) : -1e30f) - m3);
    }
#pragma unroll
    for (int off = 1; off < 64; off <<= 1) {
        s0 += __shfl_xor(s0, off, 64);
        s1 += __shfl_xor(s1, off, 64);
        s2 += __shfl_xor(s2, off, 64);
        s3 += __shfl_xor(s3, off, 64);
    }
    float i0 = 1.f / (s0 + 1e-16f), i1 = 1.f / (s1 + 1e-16f);
    float i2 = 1.f / (s2 + 1e-16f), i3 = 1.f / (s3 + 1e-16f);

    // pass 3: alpha (lane-per-edge) + wave-wide vectorized gather
    float acc[VEC] = {};
    for (int cs = start; cs < end; cs += 64) {
        int j = cs + lane;
        bool v = j < end;
        int s = v ? ecol[j] : 0;
        float4 as = a_src4[s];
        float a0 = __expf(leaky(as.x + ad.x) - m0) * i0;  // garbage if !v, never read
        float a1 = __expf(leaky(as.y + ad.y) - m1) * i1;
        float a2 = __expf(leaky(as.z + ad.z) - m2) * i2;
        float a3 = __expf(leaky(as.w + ad.w) - m3) * i3;
        int len = min(64, end - cs);
        for (int e = 0; e < len; ++e) {
            int se = __builtin_amdgcn_readlane(s, e);          // uniform edge -> SGPR src
            float w0 = rdlane_f(a0, e), w1 = rdlane_f(a1, e);
            float w2 = rdlane_f(a2, e), w3 = rdlane_f(a3, e);
            float w = hh < 2 ? (hh == 0 ? w0 : w1) : (hh == 2 ? w2 : w3);
            const ushort* rp = hsrc + (size_t)se * HC + lane * VEC;
            if (VEC == 2) {
                uint hv = *(const uint*)rp;
                acc[0] = fmaf(w, b2f((ushort)(hv & 0xffff)), acc[0]);
                acc[1] = fmaf(w, b2f((ushort)(hv >> 16)), acc[1]);
            } else {
                uint2 hv = *(const uint2*)rp;
                acc[0] = fmaf(w, b2f((ushort)(hv.x & 0xffff)), acc[0]);
                acc[1] = fmaf(w, b2f((ushort)(hv.x >> 16)), acc[1]);
                acc[2] = fmaf(w, b2f((ushort)(hv.y & 0xffff)), acc[2]);
                acc[3] = fmaf(w, b2f((ushort)(hv.y >> 16)), acc[3]);
            }
        }
    }

    if (CONCAT) {  // bias + ELU, store bf16 (next layer's GEMM input); VEC==2
        float o0 = acc[0] + bias[lane * 2 + 0];
        float o1 = acc[1] + bias[lane * 2 + 1];
        o0 = o0 > 0.f ? o0 : __expf(o0) - 1.f;
        o1 = o1 > 0.f ? o1 : __expf(o1) - 1.f;
        ((uint*)outv)[(size_t)n * (HC / 2) + lane] = (uint)f2b(o0) | ((uint)f2b(o1) << 16);
    } else {  // mean over 4 heads + bias, store f32; VEC==4
#pragma unroll
        for (int i = 0; i < VEC; ++i) {
            acc[i] += __shfl_xor(acc[i], 16, 64);
            acc[i] += __shfl_xor(acc[i], 32, 64);
        }
        if (lane < 16) {
            float4 o;
            o.x = 0.25f * acc[0] + bias[4 * lane + 0];
            o.y = 0.25f * acc[1] + bias[4 * lane + 1];
            o.z = 0.25f * acc[2] + bias[4 * lane + 2];
            o.w = 0.25f * acc[3] + bias[4 * lane + 3];
            ((float4*)((float*)outv + (size_t)n * 64))[lane] = o;
        }
    }
}

// ---------------- launch ----------------
extern "C" void kernel_launch(void* const* d_in, const int* in_sizes, int n_in,
                              void* d_out, int out_size, void* d_ws, size_t ws_size,
                              hipStream_t stream) {
    const void* x_raw   = d_in[0];
    const int*  ei      = (const int*)d_in[1];
    const void* W1_raw  = d_in[2];
    const void* as1_raw = d_in[3];
    const void* ad1_raw = d_in[4];
    const void* b1_raw  = d_in[5];
    const void* W2_raw  = d_in[6];
    const void* as2_raw = d_in[7];
    const void* ad2_raw = d_in[8];
    const void* b2_raw  = d_in[9];

    const int F_IN = 128, HC1 = 128, HC2 = 256;
    const int N = in_sizes[0] / F_IN;   // 50000
    const int E = in_sizes[1] / 2;      // 800000
    const int ET = E + N;
    const int NB = (N + 1023) / 1024;   // scan blocks

    char* p = (char*)d_ws;
    auto alloc = [&](size_t bytes) { char* r = p; p += (bytes + 255) & ~(size_t)255; return r; };
    ushort* xbf   = (ushort*)alloc((size_t)N * F_IN * 2);
    ushort* W1T   = (ushort*)alloc((size_t)HC1 * F_IN * 2);
    ushort* W2T   = (ushort*)alloc((size_t)HC2 * HC1 * 2);
    float*  att1f = (float*)alloc(2 * HC1 * 4);
    float*  att2f = (float*)alloc(2 * HC2 * 4);
    float*  b1f   = (float*)alloc(HC1 * 4);
    float*  b2f   = (float*)alloc(64 * 4);
    ushort* h1    = (ushort*)alloc((size_t)N * HC1 * 2);
    ushort* hL1   = (ushort*)alloc((size_t)N * HC1 * 2);
    ushort* h2    = (ushort*)alloc((size_t)N * HC2 * 2);
    float*  asrc1 = (float*)alloc((size_t)N * 4 * 4);
    float*  adst1 = (float*)alloc((size_t)N * 4 * 4);
    float*  asrc2 = (float*)alloc((size_t)N * 4 * 4);
    float*  adst2 = (float*)alloc((size_t)N * 4 * 4);
    int* deg    = (int*)alloc((size_t)N * 4);
    int* tmp    = (int*)alloc((size_t)N * 4);
    int* bsum   = (int*)alloc(128 * 4);
    int* rowptr = (int*)alloc((size_t)(N + 1) * 4);
    int* cnt    = (int*)alloc((size_t)N * 4);
    int* ecol   = (int*)alloc((size_t)ET * 4);
    int* flagI  = (int*)alloc(256);
    int* flagF  = (int*)alloc(256);

    hipMemsetAsync(deg, 0, (size_t)N * 4, stream);
    hipMemsetAsync(cnt, 0, (size_t)N * 4, stream);

    detect_int_kernel<<<1, 64, 0, stream>>>(ei, flagI);
    detect_f_kernel<<<1, 64, 0, stream>>>(x_raw, flagF);

    // input prep
    cvt_bf_kernel<<<(N * F_IN + 255) / 256, 256, 0, stream>>>(x_raw, xbf, N * F_IN, flagF);
    transpose_bf_kernel<<<(F_IN * HC1 + 255) / 256, 256, 0, stream>>>(W1_raw, W1T, F_IN, HC1, flagF);
    transpose_bf_kernel<<<(HC1 * HC2 + 255) / 256, 256, 0, stream>>>(W2_raw, W2T, HC1, HC2, flagF);
    cvt_kernel<<<1, HC1, 0, stream>>>(as1_raw, att1f, HC1, flagF);
    cvt_kernel<<<1, HC1, 0, stream>>>(ad1_raw, att1f + HC1, HC1, flagF);
    cvt_kernel<<<1, HC2, 0, stream>>>(as2_raw, att2f, HC2, flagF);
    cvt_kernel<<<1, HC2, 0, stream>>>(ad2_raw, att2f + HC2, HC2, flagF);
    cvt_kernel<<<1, HC1, 0, stream>>>(b1_raw, b1f, HC1, flagF);
    cvt_kernel<<<1, 64, 0, stream>>>(b2_raw, b2f, 64, flagF);

    // CSR by dst (shared by both layers)
    int eblocks = (ET + 255) / 256;
    hist_kernel<<<eblocks, 256, 0, stream>>>(ei, E, N, flagI, deg);
    scan1_kernel<<<NB, 1024, 0, stream>>>(deg, tmp, bsum, N);
    scan2_kernel<<<1, 64, 0, stream>>>(bsum, NB);
    scan3_kernel<<<(N + 256) / 256, 256, 0, stream>>>(tmp, bsum, rowptr, N, NB);
    scatter_kernel<<<eblocks, 256, 0, stream>>>(ei, E, N, flagI, rowptr, cnt, ecol);

    int nblocks4 = (N + 3) / 4;
    // ---- layer 1 ----
    gemm_mfma_kernel<HC1><<<(N + 63) / 64, 256, 0, stream>>>(xbf, W1T, h1, N);
    attdot_kernel<HC1><<<nblocks4, 256, 0, stream>>>(h1, att1f, asrc1, adst1, N);
    aggregate_kernel<HC1, true><<<nblocks4, 256, 0, stream>>>(
        h1, (const float4*)asrc1, (const float4*)adst1, rowptr, ecol, b1f, hL1, N);
    // ---- layer 2 ----
    gemm_mfma_kernel<HC2><<<(N + 63) / 64, 256, 0, stream>>>(hL1, W2T, h2, N);
    attdot_kernel<HC2><<<nblocks4, 256, 0, stream>>>(h2, att2f, asrc2, adst2, N);
    aggregate_kernel<HC2, false><<<nblocks4, 256, 0, stream>>>(
        h2, (const float4*)asrc2, (const float4*)adst2, rowptr, ecol, b2f, d_out, N);
}

// Round 4
// 375.486 us; speedup vs baseline: 2.0153x; 1.1891x over previous
//
#include <hip/hip_runtime.h>

typedef unsigned int uint;
typedef unsigned short ushort;

// N=50000 nodes, E=800000 edges, F_in=128, heads=4, C1=32 (concat->128), C2=64 (mean->64)

__device__ __forceinline__ float leaky(float x) { return x >= 0.f ? x : 0.2f * x; }
__device__ __forceinline__ float b2f(ushort h) { return __uint_as_float(((uint)h) << 16); }
__device__ __forceinline__ ushort f2b(float f) {
    uint u = __float_as_uint(f);
    return (ushort)((u + 0x7FFF + ((u >> 16) & 1)) >> 16);  // RNE
}

// ---------------- dtype detection (device-side; flags in ws) ----------------
__global__ void detect_kernel(const int* __restrict__ ei, const void* __restrict__ xin,
                              int* __restrict__ flagI, int* __restrict__ flagF) {
    if (threadIdx.x == 0) {
        int allz = 1;
        for (int i = 0; i < 64; ++i) if (ei[2 * i + 1] != 0) { allz = 0; break; }
        *flagI = allz;  // 1 => int64 storage
    }
    if (threadIdx.x == 1) {
        const ushort* u = (const ushort*)xin;
        int sane = 0;
        for (int i = 0; i < 256; ++i) {
            ushort v = u[2 * i];
            int ex = (v >> 7) & 0xFF;
            if (v == 0 || (ex >= 100 && ex <= 135)) sane++;
        }
        *flagF = (sane >= 230) ? 1 : 0;  // 1 => bf16 storage
    }
}

// ---------------- fused prep: x->bf16, W1^T, W2^T, small f32 cvts ----------------
// NOTE param order here is (x, W1, W2, as1, ad1, b1, as2, ad2, b2) — the call site
// must map d_in as (0, 2, 6, 3, 4, 5, 7, 8, 9). R3's bug was passing d_in[3..] in
// harness order, feeding att_src1 as W2.
__global__ void prep_kernel(const void* __restrict__ x, const void* __restrict__ W1,
                            const void* __restrict__ W2, const void* __restrict__ as1,
                            const void* __restrict__ ad1, const void* __restrict__ b1,
                            const void* __restrict__ as2, const void* __restrict__ ad2,
                            const void* __restrict__ b2, ushort* __restrict__ xbf,
                            ushort* __restrict__ W1T, ushort* __restrict__ W2T,
                            float* __restrict__ att1, float* __restrict__ att2,
                            float* __restrict__ b1f, float* __restrict__ b2f_,
                            int NX, const int* __restrict__ flagF) {
    int bf = *flagF;
    int b = blockIdx.x, t = threadIdx.x;
    int nxb = (NX + 255) / 256;
    if (b < nxb) {
        int i = b * 256 + t;
        if (i < NX) xbf[i] = bf ? ((const ushort*)x)[i] : f2b(((const float*)x)[i]);
        return;
    }
    b -= nxb;
    if (b < 64) {  // W1 [128][128] -> W1T [n][k]
        int i = b * 256 + t;
        int k = i >> 7, n = i & 127;
        W1T[n * 128 + k] = bf ? ((const ushort*)W1)[i] : f2b(((const float*)W1)[i]);
        return;
    }
    b -= 64;
    if (b < 128) {  // W2 [128][256] -> W2T [n][k]
        int i = b * 256 + t;
        int k = i >> 8, n = i & 255;
        W2T[(size_t)n * 128 + k] = bf ? ((const ushort*)W2)[i] : f2b(((const float*)W2)[i]);
        return;
    }
    b -= 128;
    int i = b * 256 + t;  // small arrays: 960 total
    float v;
    if (i < 128)       { v = bf ? b2f(((const ushort*)as1)[i])       : ((const float*)as1)[i];       att1[i] = v; }
    else if (i < 256)  { v = bf ? b2f(((const ushort*)ad1)[i - 128]) : ((const float*)ad1)[i - 128]; att1[i] = v; }
    else if (i < 512)  { v = bf ? b2f(((const ushort*)as2)[i - 256]) : ((const float*)as2)[i - 256]; att2[i - 256] = v; }
    else if (i < 768)  { v = bf ? b2f(((const ushort*)ad2)[i - 512]) : ((const float*)ad2)[i - 512]; att2[i - 256] = v; }
    else if (i < 896)  { v = bf ? b2f(((const ushort*)b1)[i - 768])  : ((const float*)b1)[i - 768];  b1f[i - 768] = v; }
    else if (i < 960)  { v = bf ? b2f(((const ushort*)b2)[i - 896])  : ((const float*)b2)[i - 896];  b2f_[i - 896] = v; }
}

// ---------------- edge decode + CSR build ----------------
__device__ __forceinline__ void edge_sd(const int* __restrict__ ei, int E, int e, int is64,
                                        int& src, int& dst) {
    if (e >= E) { src = dst = e - E; return; }  // self loops appended after edges
    if (is64) { src = ei[2 * e]; dst = ei[2 * E + 2 * e]; }
    else      { src = ei[e];     dst = ei[E + e]; }
}

__global__ void hist_kernel(const int* __restrict__ ei, int E, int N,
                            const int* __restrict__ flag, int* __restrict__ deg) {
    int e = blockIdx.x * blockDim.x + threadIdx.x;
    if (e >= E + N) return;
    int src, dst; edge_sd(ei, E, e, *flag, src, dst);
    atomicAdd(&deg[dst], 1);
}

__global__ __launch_bounds__(1024) void scan1_kernel(const int* __restrict__ deg,
                                                     int* __restrict__ tmp,
                                                     int* __restrict__ bsum, int n) {
    __shared__ int sm[1024];
    int tid = threadIdx.x, i = blockIdx.x * 1024 + tid;
    int v = (i < n) ? deg[i] : 0;
    sm[tid] = v;
    __syncthreads();
    for (int off = 1; off < 1024; off <<= 1) {
        int t = (tid >= off) ? sm[tid - off] : 0;
        __syncthreads();
        sm[tid] += t;
        __syncthreads();
    }
    if (i < n) tmp[i] = sm[tid] - v;  // exclusive
    if (tid == 1023) bsum[blockIdx.x] = sm[1023];
}

__global__ void scan2_kernel(int* __restrict__ bsum, int nb) {  // 1 block, 64 lanes, nb<=64
    int lane = threadIdx.x;
    int v = (lane < nb) ? bsum[lane] : 0;
    int incl = v;
    for (int off = 1; off < 64; off <<= 1) {
        int t = __shfl_up(incl, off, 64);
        if (lane >= off) incl += t;
    }
    int total = __shfl(incl, nb - 1, 64);
    if (lane < nb) bsum[lane] = incl - v;  // exclusive
    if (lane == 0) bsum[nb] = total;
}

__global__ void scan3_kernel(const int* __restrict__ tmp, const int* __restrict__ bsum,
                             int* __restrict__ rowptr, int* __restrict__ cnt, int n, int nb) {
    int i = blockIdx.x * blockDim.x + threadIdx.x;
    if (i > n) return;
    rowptr[i] = (i == n) ? bsum[nb] : tmp[i] + bsum[i >> 10];
    if (i < n) cnt[i] = 0;
}

__global__ void scatter_kernel(const int* __restrict__ ei, int E, int N,
                               const int* __restrict__ flag, const int* __restrict__ rowptr,
                               int* __restrict__ cnt, int* __restrict__ ecol) {
    int e = blockIdx.x * blockDim.x + threadIdx.x;
    if (e >= E + N) return;
    int src, dst; edge_sd(ei, E, e, *flag, src, dst);
    int pos = rowptr[dst] + atomicAdd(&cnt[dst], 1);
    ecol[pos] = src;
}

// ---------------- MFMA GEMM + fused attdot epilogue ----------------
typedef __attribute__((ext_vector_type(8))) short bf16x8;   // 8 bf16 = 4 VGPRs
typedef __attribute__((ext_vector_type(4))) float floatx4;

template <int HC>
__global__ __launch_bounds__(256) void gemm_mfma_kernel(
    const ushort* __restrict__ A, const ushort* __restrict__ BT, ushort* __restrict__ C,
    const float* __restrict__ att, float4* __restrict__ asrc4, float4* __restrict__ adst4, int M) {
    constexpr int K = 128, NT = HC / 16, NTPH = HC / 64;  // NTPH = col-tiles per head
    int lane = threadIdx.x & 63, wv = threadIdx.x >> 6;
    int row0 = (blockIdx.x * 4 + wv) * 16;
    if (row0 >= M) return;
    int m = lane & 15, quad = lane >> 4;
    int rowa = min(row0 + m, M - 1);
    const bf16x8* arow = (const bf16x8*)(A + (size_t)rowa * K);
    bf16x8 af[4];
#pragma unroll
    for (int kk = 0; kk < 4; ++kk) af[kk] = arow[4 * kk + quad];
    floatx4 acc[NT] = {};
#pragma unroll
    for (int nt = 0; nt < NT; ++nt) {
        const bf16x8* brow = (const bf16x8*)(BT + (size_t)(nt * 16 + m) * K);
#pragma unroll
        for (int kk = 0; kk < 4; ++kk)
            acc[nt] = __builtin_amdgcn_mfma_f32_16x16x32_bf16(af[kk], brow[4 * kk + quad], acc[nt], 0, 0, 0);
    }
    // C/D layout: col = lane&15, row = quad*4 + reg
#pragma unroll
    for (int nt = 0; nt < NT; ++nt)
#pragma unroll
        for (int r = 0; r < 4; ++r) {
            int row = row0 + quad * 4 + r;
            if (row < M) C[(size_t)row * HC + nt * 16 + m] = f2b(acc[nt][r]);
        }
    // fused attention dots: a_src[row][h] = sum_ch C[row][ch]*att_src[ch]
    float attS[NT], attD[NT];
#pragma unroll
    for (int nt = 0; nt < NT; ++nt) { attS[nt] = att[nt * 16 + m]; attD[nt] = att[HC + nt * 16 + m]; }
#pragma unroll
    for (int r = 0; r < 4; ++r) {
        float ps[4] = {0, 0, 0, 0}, pd[4] = {0, 0, 0, 0};
#pragma unroll
        for (int nt = 0; nt < NT; ++nt) {
            int h = nt / NTPH;
            ps[h] = fmaf(acc[nt][r], attS[nt], ps[h]);
            pd[h] = fmaf(acc[nt][r], attD[nt], pd[h]);
        }
#pragma unroll
        for (int off = 1; off < 16; off <<= 1) {
#pragma unroll
            for (int h = 0; h < 4; ++h) {
                ps[h] += __shfl_xor(ps[h], off, 64);
                pd[h] += __shfl_xor(pd[h], off, 64);
            }
        }
        int row = row0 + quad * 4 + r;
        if (m == 0 && row < M) {
            asrc4[row] = make_float4(ps[0], ps[1], ps[2], ps[3]);
            adst4[row] = make_float4(pd[0], pd[1], pd[2], pd[3]);
        }
    }
}

// ---------------- aggregate: wave/node, register-cached softmax, 2-edge-parallel gather ----------------
template <int HC, bool CONCAT>
__global__ __launch_bounds__(256) void aggregate_kernel(
    const ushort* __restrict__ hsrc, const float4* __restrict__ a_src4,
    const float4* __restrict__ a_dst4, const int* __restrict__ rowptr,
    const int* __restrict__ ecol, const float* __restrict__ bias,
    void* __restrict__ outv, int N) {
    constexpr int CPL = HC / 32;  // channels per lane in gather (4 or 8)
    __shared__ float alds[4][256];
    int lane = threadIdx.x & 63, wv = threadIdx.x >> 6;
    int n = blockIdx.x * 4 + wv;
    if (n >= N) return;
    int start = rowptr[n], end = rowptr[n + 1], deg = end - start;
    float4 ad = a_dst4[n];
    int c = lane & 31, p = lane >> 5, hh = c >> 3;  // half-wave p handles edge e+p; head = c>>3

    float m0, m1, m2, m3, i0, i1, i2, i3;
    int sv = 0;
    float e0 = 0.f, e1 = 0.f, e2 = 0.f, e3 = 0.f;  // fast-path exp numerators
    bool fast = (deg <= 64);
    if (fast) {
        bool v = lane < deg;
        sv = v ? ecol[start + lane] : 0;
        float4 as = a_src4[sv];
        float l0 = v ? leaky(as.x + ad.x) : -1e30f;
        float l1 = v ? leaky(as.y + ad.y) : -1e30f;
        float l2 = v ? leaky(as.z + ad.z) : -1e30f;
        float l3 = v ? leaky(as.w + ad.w) : -1e30f;
        m0 = l0; m1 = l1; m2 = l2; m3 = l3;
#pragma unroll
        for (int off = 1; off < 64; off <<= 1) {
            m0 = fmaxf(m0, __shfl_xor(m0, off, 64));
            m1 = fmaxf(m1, __shfl_xor(m1, off, 64));
            m2 = fmaxf(m2, __shfl_xor(m2, off, 64));
            m3 = fmaxf(m3, __shfl_xor(m3, off, 64));
        }
        e0 = __expf(l0 - m0); e1 = __expf(l1 - m1);
        e2 = __expf(l2 - m2); e3 = __expf(l3 - m3);
        float s0 = e0, s1 = e1, s2 = e2, s3 = e3;
#pragma unroll
        for (int off = 1; off < 64; off <<= 1) {
            s0 += __shfl_xor(s0, off, 64); s1 += __shfl_xor(s1, off, 64);
            s2 += __shfl_xor(s2, off, 64); s3 += __shfl_xor(s3, off, 64);
        }
        i0 = 1.f / (s0 + 1e-16f); i1 = 1.f / (s1 + 1e-16f);
        i2 = 1.f / (s2 + 1e-16f); i3 = 1.f / (s3 + 1e-16f);
    } else {  // rare general path (deg > 64): chunked 2-pass
        m0 = m1 = m2 = m3 = -1e30f;
        for (int cs = start; cs < end; cs += 64) {
            int j = cs + lane; bool v = j < end;
            int s = v ? ecol[j] : 0;
            float4 as = a_src4[s];
            if (v) {
                m0 = fmaxf(m0, leaky(as.x + ad.x)); m1 = fmaxf(m1, leaky(as.y + ad.y));
                m2 = fmaxf(m2, leaky(as.z + ad.z)); m3 = fmaxf(m3, leaky(as.w + ad.w));
            }
        }
#pragma unroll
        for (int off = 1; off < 64; off <<= 1) {
            m0 = fmaxf(m0, __shfl_xor(m0, off, 64));
            m1 = fmaxf(m1, __shfl_xor(m1, off, 64));
            m2 = fmaxf(m2, __shfl_xor(m2, off, 64));
            m3 = fmaxf(m3, __shfl_xor(m3, off, 64));
        }
        float s0 = 0, s1 = 0, s2 = 0, s3 = 0;
        for (int cs = start; cs < end; cs += 64) {
            int j = cs + lane; bool v = j < end;
            int s = v ? ecol[j] : 0;
            float4 as = a_src4[s];
            if (v) {
                s0 += __expf(leaky(as.x + ad.x) - m0); s1 += __expf(leaky(as.y + ad.y) - m1);
                s2 += __expf(leaky(as.z + ad.z) - m2); s3 += __expf(leaky(as.w + ad.w) - m3);
            }
        }
#pragma unroll
        for (int off = 1; off < 64; off <<= 1) {
            s0 += __shfl_xor(s0, off, 64); s1 += __shfl_xor(s1, off, 64);
            s2 += __shfl_xor(s2, off, 64); s3 += __shfl_xor(s3, off, 64);
        }
        i0 = 1.f / (s0 + 1e-16f); i1 = 1.f / (s1 + 1e-16f);
        i2 = 1.f / (s2 + 1e-16f); i3 = 1.f / (s3 + 1e-16f);
    }

    float acc[CPL] = {};
    for (int cs = start; cs < end; cs += 64) {
        int len = min(64, end - cs);
        float a0, a1, a2, a3;
        if (fast) {
            a0 = e0 * i0; a1 = e1 * i1; a2 = e2 * i2; a3 = e3 * i3;  // 0 for invalid lanes
        } else {
            int j = cs + lane; bool v = j < end;
            sv = v ? ecol[j] : 0;
            float4 as = a_src4[sv];
            a0 = v ? __expf(leaky(as.x + ad.x) - m0) * i0 : 0.f;
            a1 = v ? __expf(leaky(as.y + ad.y) - m1) * i1 : 0.f;
            a2 = v ? __expf(leaky(as.z + ad.z) - m2) * i2 : 0.f;
            a3 = v ? __expf(leaky(as.w + ad.w) - m3) * i3 : 0.f;
        }
        *(float4*)&alds[wv][lane * 4] = make_float4(a0, a1, a2, a3);
        // inner gather: 2 edges/step (half-wave each), 2 steps in flight
        for (int e = 0; e < len; e += 4) {
            int idx0 = e + p, idx1 = e + 2 + p;  // <=63 always; invalid slots have alpha=0
            int se0 = __shfl(sv, idx0, 64), se1 = __shfl(sv, idx1, 64);
            float w0 = alds[wv][idx0 * 4 + hh], w1 = alds[wv][idx1 * 4 + hh];
            const ushort* rp0 = hsrc + (size_t)se0 * HC + c * CPL;
            const ushort* rp1 = hsrc + (size_t)se1 * HC + c * CPL;
            if (CPL == 4) {
                uint2 h0 = *(const uint2*)rp0;
                uint2 h1 = *(const uint2*)rp1;
                acc[0] = fmaf(w0, __uint_as_float(h0.x << 16), acc[0]);
                acc[1] = fmaf(w0, __uint_as_float(h0.x & 0xffff0000u), acc[1]);
                acc[2] = fmaf(w0, __uint_as_float(h0.y << 16), acc[2]);
                acc[3] = fmaf(w0, __uint_as_float(h0.y & 0xffff0000u), acc[3]);
                acc[0] = fmaf(w1, __uint_as_float(h1.x << 16), acc[0]);
                acc[1] = fmaf(w1, __uint_as_float(h1.x & 0xffff0000u), acc[1]);
                acc[2] = fmaf(w1, __uint_as_float(h1.y << 16), acc[2]);
                acc[3] = fmaf(w1, __uint_as_float(h1.y & 0xffff0000u), acc[3]);
            } else {
                uint4 h0 = *(const uint4*)rp0;
                uint4 h1 = *(const uint4*)rp1;
                acc[0] = fmaf(w0, __uint_as_float(h0.x << 16), acc[0]);
                acc[1] = fmaf(w0, __uint_as_float(h0.x & 0xffff0000u), acc[1]);
                acc[2] = fmaf(w0, __uint_as_float(h0.y << 16), acc[2]);
                acc[3] = fmaf(w0, __uint_as_float(h0.y & 0xffff0000u), acc[3]);
                acc[4] = fmaf(w0, __uint_as_float(h0.z << 16), acc[4]);
                acc[5] = fmaf(w0, __uint_as_float(h0.z & 0xffff0000u), acc[5]);
                acc[6] = fmaf(w0, __uint_as_float(h0.w << 16), acc[6]);
                acc[7] = fmaf(w0, __uint_as_float(h0.w & 0xffff0000u), acc[7]);
                acc[0] = fmaf(w1, __uint_as_float(h1.x << 16), acc[0]);
                acc[1] = fmaf(w1, __uint_as_float(h1.x & 0xffff0000u), acc[1]);
                acc[2] = fmaf(w1, __uint_as_float(h1.y << 16), acc[2]);
                acc[3] = fmaf(w1, __uint_as_float(h1.y & 0xffff0000u), acc[3]);
                acc[4] = fmaf(w1, __uint_as_float(h1.z << 16), acc[4]);
                acc[5] = fmaf(w1, __uint_as_float(h1.z & 0xffff0000u), acc[5]);
                acc[6] = fmaf(w1, __uint_as_float(h1.w << 16), acc[6]);
                acc[7] = fmaf(w1, __uint_as_float(h1.w & 0xffff0000u), acc[7]);
            }
        }
    }
    // combine the two half-wave edge partials
#pragma unroll
    for (int i = 0; i < CPL; ++i) acc[i] += __shfl_xor(acc[i], 32, 64);

    if (CONCAT) {  // bias + ELU, store bf16 (next layer's GEMM input); CPL==4
        if (lane < 32) {
            float o[4];
#pragma unroll
            for (int i = 0; i < 4; ++i) {
                o[i] = acc[i] + bias[c * 4 + i];
                o[i] = o[i] > 0.f ? o[i] : __expf(o[i]) - 1.f;
            }
            uint2 pk;
            pk.x = (uint)f2b(o[0]) | ((uint)f2b(o[1]) << 16);
            pk.y = (uint)f2b(o[2]) | ((uint)f2b(o[3]) << 16);
            ((uint2*)outv)[(size_t)n * 32 + c] = pk;
        }
    } else {  // mean over heads + bias, f32 out; CPL==8, head = c>>3
#pragma unroll
        for (int i = 0; i < CPL; ++i) {
            acc[i] += __shfl_xor(acc[i], 8, 64);
            acc[i] += __shfl_xor(acc[i], 16, 64);
        }
        if (lane < 8) {
            float* op = (float*)outv + (size_t)n * 64 + lane * 8;
            float4 o0, o1;
            o0.x = 0.25f * acc[0] + bias[lane * 8 + 0];
            o0.y = 0.25f * acc[1] + bias[lane * 8 + 1];
            o0.z = 0.25f * acc[2] + bias[lane * 8 + 2];
            o0.w = 0.25f * acc[3] + bias[lane * 8 + 3];
            o1.x = 0.25f * acc[4] + bias[lane * 8 + 4];
            o1.y = 0.25f * acc[5] + bias[lane * 8 + 5];
            o1.z = 0.25f * acc[6] + bias[lane * 8 + 6];
            o1.w = 0.25f * acc[7] + bias[lane * 8 + 7];
            ((float4*)op)[0] = o0;
            ((float4*)op)[1] = o1;
        }
    }
}

// ---------------- launch ----------------
extern "C" void kernel_launch(void* const* d_in, const int* in_sizes, int n_in,
                              void* d_out, int out_size, void* d_ws, size_t ws_size,
                              hipStream_t stream) {
    // setup_inputs order: x, edge_index, W1, att_src1, att_dst1, bias1, W2, att_src2, att_dst2, bias2
    const void* x_raw  = d_in[0];
    const int*  ei     = (const int*)d_in[1];
    const void* W1_p   = d_in[2];
    const void* as1_p  = d_in[3];
    const void* ad1_p  = d_in[4];
    const void* b1_p   = d_in[5];
    const void* W2_p   = d_in[6];
    const void* as2_p  = d_in[7];
    const void* ad2_p  = d_in[8];
    const void* b2_p   = d_in[9];

    const int F_IN = 128, HC1 = 128, HC2 = 256;
    const int N = in_sizes[0] / F_IN;   // 50000
    const int E = in_sizes[1] / 2;      // 800000
    const int ET = E + N;
    const int NB = (N + 1023) / 1024;

    char* p = (char*)d_ws;
    auto alloc = [&](size_t bytes) { char* r = p; p += (bytes + 255) & ~(size_t)255; return r; };
    ushort* xbf   = (ushort*)alloc((size_t)N * F_IN * 2);
    ushort* W1T   = (ushort*)alloc((size_t)HC1 * F_IN * 2);
    ushort* W2T   = (ushort*)alloc((size_t)HC2 * HC1 * 2);
    float*  att1f = (float*)alloc(2 * HC1 * 4);
    float*  att2f = (float*)alloc(2 * HC2 * 4);
    float*  b1f   = (float*)alloc(HC1 * 4);
    float*  b2f   = (float*)alloc(64 * 4);
    ushort* h1    = (ushort*)alloc((size_t)N * HC1 * 2);
    ushort* hL1   = (ushort*)alloc((size_t)N * HC1 * 2);
    ushort* h2    = (ushort*)alloc((size_t)N * HC2 * 2);
    float*  asrc1 = (float*)alloc((size_t)N * 4 * 4);
    float*  adst1 = (float*)alloc((size_t)N * 4 * 4);
    float*  asrc2 = (float*)alloc((size_t)N * 4 * 4);
    float*  adst2 = (float*)alloc((size_t)N * 4 * 4);
    int* deg    = (int*)alloc((size_t)2 * N * 4);  // deg | cnt adjacent
    int* cnt    = deg + N;
    int* tmp    = (int*)alloc((size_t)N * 4);
    int* bsum   = (int*)alloc(128 * 4);
    int* rowptr = (int*)alloc((size_t)(N + 1) * 4);
    int* ecol   = (int*)alloc((size_t)ET * 4);
    int* flagI  = (int*)alloc(256);
    int* flagF  = (int*)alloc(256);

    hipMemsetAsync(deg, 0, (size_t)N * 4, stream);  // cnt zeroed in scan3

    detect_kernel<<<1, 64, 0, stream>>>(ei, x_raw, flagI, flagF);

    int NX = N * F_IN;
    int nxb = (NX + 255) / 256;
    // FIX (R3 bug): argument order must be x, W1, W2, as1, ad1, b1, as2, ad2, b2
    prep_kernel<<<nxb + 64 + 128 + 4, 256, 0, stream>>>(
        x_raw, W1_p, W2_p, as1_p, ad1_p, b1_p, as2_p, ad2_p, b2_p,
        xbf, W1T, W2T, att1f, att2f, b1f, b2f, NX, flagF);

    // CSR by dst (shared by both layers)
    int eblocks = (ET + 255) / 256;
    hist_kernel<<<eblocks, 256, 0, stream>>>(ei, E, N, flagI, deg);
    scan1_kernel<<<NB, 1024, 0, stream>>>(deg, tmp, bsum, N);
    scan2_kernel<<<1, 64, 0, stream>>>(bsum, NB);
    scan3_kernel<<<(N + 256) / 256, 256, 0, stream>>>(tmp, bsum, rowptr, cnt, N, NB);
    scatter_kernel<<<eblocks, 256, 0, stream>>>(ei, E, N, flagI, rowptr, cnt, ecol);

    int nblocks4 = (N + 3) / 4;
    // ---- layer 1 ----
    gemm_mfma_kernel<HC1><<<(N + 63) / 64, 256, 0, stream>>>(
        xbf, W1T, h1, att1f, (float4*)asrc1, (float4*)adst1, N);
    aggregate_kernel<HC1, true><<<nblocks4, 256, 0, stream>>>(
        h1, (const float4*)asrc1, (const float4*)adst1, rowptr, ecol, b1f, hL1, N);
    // ---- layer 2 ----
    gemm_mfma_kernel<HC2><<<(N + 63) / 64, 256, 0, stream>>>(
        hL1, W2T, h2, att2f, (float4*)asrc2, (float4*)adst2, N);
    aggregate_kernel<HC2, false><<<nblocks4, 256, 0, stream>>>(
        h2, (const float4*)asrc2, (const float4*)adst2, rowptr, ecol, b2f, d_out, N);
}

// Round 5
// 350.288 us; speedup vs baseline: 2.1603x; 1.0719x over previous
//
#include <hip/hip_runtime.h>

typedef unsigned int uint;
typedef unsigned short ushort;

// N=50000 nodes, E=800000 edges, F_in=128, heads=4, C1=32 (concat->128), C2=64 (mean->64)

__device__ __forceinline__ float leaky(float x) { return x >= 0.f ? x : 0.2f * x; }
__device__ __forceinline__ float b2f(ushort h) { return __uint_as_float(((uint)h) << 16); }
__device__ __forceinline__ ushort f2b(float f) {
    uint u = __float_as_uint(f);
    return (ushort)((u + 0x7FFF + ((u >> 16) & 1)) >> 16);  // RNE
}

#if defined(__has_builtin)
#if __has_builtin(__builtin_amdgcn_fdot2_f32_bf16)
#define HAS_DOT2 1
#endif
#endif
#ifndef HAS_DOT2
#define HAS_DOT2 0
#endif

#if HAS_DOT2
typedef __bf16 bf16v2 __attribute__((ext_vector_type(2)));
__device__ __forceinline__ float dot2bf(uint h2, uint w2, float c) {
    return __builtin_amdgcn_fdot2_f32_bf16(__builtin_bit_cast(bf16v2, h2),
                                           __builtin_bit_cast(bf16v2, w2), c, false);
}
#endif

// ---------------- dtype detection (parallel; flags in ws) ----------------
__global__ void detect_kernel(const int* __restrict__ ei, const void* __restrict__ xin,
                              int* __restrict__ flagI, int* __restrict__ flagF) {
    __shared__ int s_sane, s_odd;
    int t = threadIdx.x;  // 256 threads
    if (t == 0) { s_sane = 0; s_odd = 0; }
    __syncthreads();
    if (t < 64 && ei[2 * t + 1] != 0) atomicOr(&s_odd, 1);
    ushort v = ((const ushort*)xin)[2 * t];
    int ex = (v >> 7) & 0xFF;
    if (v == 0 || (ex >= 100 && ex <= 135)) atomicAdd(&s_sane, 1);
    __syncthreads();
    if (t == 0) { *flagI = (s_odd == 0); *flagF = (s_sane >= 230); }
}

// ---------------- fused prep: x->bf16, W1^T, W2^T, small cvts, dst histogram ----------------
// param order (x, W1, W2, as1, ad1, b1, as2, ad2, b2): call site maps d_in (0,2,6,3,4,5,7,8,9)!
__global__ void prep_kernel(const void* __restrict__ x, const void* __restrict__ W1,
                            const void* __restrict__ W2, const void* __restrict__ as1,
                            const void* __restrict__ ad1, const void* __restrict__ b1,
                            const void* __restrict__ as2, const void* __restrict__ ad2,
                            const void* __restrict__ b2, ushort* __restrict__ xbf,
                            ushort* __restrict__ W1T, ushort* __restrict__ W2T,
                            float* __restrict__ att1, float* __restrict__ att2,
                            float* __restrict__ b1f, float* __restrict__ b2f_,
                            const int* __restrict__ ei, int E, int ET, int* __restrict__ deg,
                            int NX, const int* __restrict__ flagF, const int* __restrict__ flagI) {
    int bf = *flagF;
    int b = blockIdx.x, t = threadIdx.x;
    int nxb = (NX + 255) / 256;
    if (b < nxb) {
        int i = b * 256 + t;
        if (i < NX) xbf[i] = bf ? ((const ushort*)x)[i] : f2b(((const float*)x)[i]);
        return;
    }
    b -= nxb;
    if (b < 64) {  // W1 [128][128] -> W1T [n][k]
        int i = b * 256 + t;
        int k = i >> 7, n = i & 127;
        W1T[n * 128 + k] = bf ? ((const ushort*)W1)[i] : f2b(((const float*)W1)[i]);
        return;
    }
    b -= 64;
    if (b < 128) {  // W2 [128][256] -> W2T [n][k]
        int i = b * 256 + t;
        int k = i >> 8, n = i & 255;
        W2T[(size_t)n * 128 + k] = bf ? ((const ushort*)W2)[i] : f2b(((const float*)W2)[i]);
        return;
    }
    b -= 128;
    if (b < 4) {  // small arrays: 960 total
        int i = b * 256 + t;
        float v;
        if (i < 128)      { v = bf ? b2f(((const ushort*)as1)[i])       : ((const float*)as1)[i];       att1[i] = v; }
        else if (i < 256) { v = bf ? b2f(((const ushort*)ad1)[i - 128]) : ((const float*)ad1)[i - 128]; att1[i] = v; }
        else if (i < 512) { v = bf ? b2f(((const ushort*)as2)[i - 256]) : ((const float*)as2)[i - 256]; att2[i - 256] = v; }
        else if (i < 768) { v = bf ? b2f(((const ushort*)ad2)[i - 512]) : ((const float*)ad2)[i - 512]; att2[i - 256] = v; }
        else if (i < 896) { v = bf ? b2f(((const ushort*)b1)[i - 768])  : ((const float*)b1)[i - 768];  b1f[i - 768] = v; }
        else if (i < 960) { v = bf ? b2f(((const ushort*)b2)[i - 896])  : ((const float*)b2)[i - 896];  b2f_[i - 896] = v; }
        return;
    }
    b -= 4;
    {  // dst histogram (self loops appended after edges)
        int e = b * 256 + t;
        if (e < ET) {
            int dst = (e >= E) ? (e - E) : ((*flagI) ? ei[2 * E + 2 * e] : ei[E + e]);
            atomicAdd(&deg[dst], 1);
        }
    }
}

// ---------------- CSR scan + scatter ----------------
__global__ __launch_bounds__(1024) void scan1_kernel(const int* __restrict__ deg,
                                                     int* __restrict__ tmp,
                                                     int* __restrict__ bsum, int n) {
    __shared__ int ws[16];
    int tid = threadIdx.x, lane = tid & 63, wid = tid >> 6;
    int i = blockIdx.x * 1024 + tid;
    int v = (i < n) ? deg[i] : 0;
    int incl = v;
#pragma unroll
    for (int off = 1; off < 64; off <<= 1) {
        int t2 = __shfl_up(incl, off, 64);
        if (lane >= off) incl += t2;
    }
    if (lane == 63) ws[wid] = incl;
    __syncthreads();
    if (tid < 16) {
        int wv_ = ws[tid], winc = wv_;
#pragma unroll
        for (int off = 1; off < 16; off <<= 1) {
            int t2 = __shfl_up(winc, off, 16);
            if (tid >= off) winc += t2;
        }
        ws[tid] = winc - wv_;  // exclusive wave offset
    }
    __syncthreads();
    int excl = incl - v + ws[wid];
    if (i < n) tmp[i] = excl;
    if (tid == 1023) bsum[blockIdx.x] = excl + v;
}

__global__ void scan2_kernel(int* __restrict__ bsum, int nb) {  // 1 block, 64 lanes, nb<=64
    int lane = threadIdx.x;
    int v = (lane < nb) ? bsum[lane] : 0;
    int incl = v;
    for (int off = 1; off < 64; off <<= 1) {
        int t = __shfl_up(incl, off, 64);
        if (lane >= off) incl += t;
    }
    int total = __shfl(incl, nb - 1, 64);
    if (lane < nb) bsum[lane] = incl - v;
    if (lane == 0) bsum[nb] = total;
}

__global__ void scan3_kernel(const int* __restrict__ tmp, const int* __restrict__ bsum,
                             int* __restrict__ rowptr, int* __restrict__ cnt, int n, int nb) {
    int i = blockIdx.x * blockDim.x + threadIdx.x;
    if (i > n) return;
    rowptr[i] = (i == n) ? bsum[nb] : tmp[i] + bsum[i >> 10];
    if (i < n) cnt[i] = 0;
}

__global__ void scatter_kernel(const int* __restrict__ ei, int E, int N,
                               const int* __restrict__ flag, const int* __restrict__ rowptr,
                               int* __restrict__ cnt, int* __restrict__ ecol) {
    int e = blockIdx.x * blockDim.x + threadIdx.x;
    if (e >= E + N) return;
    int src, dst;
    if (e >= E) { src = dst = e - E; }
    else if (*flag) { src = ei[2 * e]; dst = ei[2 * E + 2 * e]; }
    else            { src = ei[e];     dst = ei[E + e]; }
    int pos = rowptr[dst] + atomicAdd(&cnt[dst], 1);
    ecol[pos] = src;
}

// ---------------- MFMA GEMM + fused attdot epilogue ----------------
typedef __attribute__((ext_vector_type(8))) short bf16x8;
typedef __attribute__((ext_vector_type(4))) float floatx4;

template <int HC>
__global__ __launch_bounds__(256) void gemm_mfma_kernel(
    const ushort* __restrict__ A, const ushort* __restrict__ BT, ushort* __restrict__ C,
    const float* __restrict__ att, float4* __restrict__ asrc4, float4* __restrict__ adst4, int M) {
    constexpr int K = 128, NT = HC / 16, NTPH = HC / 64;
    int lane = threadIdx.x & 63, wv = threadIdx.x >> 6;
    int row0 = (blockIdx.x * 4 + wv) * 16;
    if (row0 >= M) return;
    int m = lane & 15, quad = lane >> 4;
    int rowa = min(row0 + m, M - 1);
    const bf16x8* arow = (const bf16x8*)(A + (size_t)rowa * K);
    bf16x8 af[4];
#pragma unroll
    for (int kk = 0; kk < 4; ++kk) af[kk] = arow[4 * kk + quad];
    floatx4 acc[NT] = {};
#pragma unroll
    for (int nt = 0; nt < NT; ++nt) {
        const bf16x8* brow = (const bf16x8*)(BT + (size_t)(nt * 16 + m) * K);
#pragma unroll
        for (int kk = 0; kk < 4; ++kk)
            acc[nt] = __builtin_amdgcn_mfma_f32_16x16x32_bf16(af[kk], brow[4 * kk + quad], acc[nt], 0, 0, 0);
    }
    // C/D layout: col = lane&15, row = quad*4 + reg
#pragma unroll
    for (int nt = 0; nt < NT; ++nt)
#pragma unroll
        for (int r = 0; r < 4; ++r) {
            int row = row0 + quad * 4 + r;
            if (row < M) C[(size_t)row * HC + nt * 16 + m] = f2b(acc[nt][r]);
        }
    float attS[NT], attD[NT];
#pragma unroll
    for (int nt = 0; nt < NT; ++nt) { attS[nt] = att[nt * 16 + m]; attD[nt] = att[HC + nt * 16 + m]; }
#pragma unroll
    for (int r = 0; r < 4; ++r) {
        float ps[4] = {0, 0, 0, 0}, pd[4] = {0, 0, 0, 0};
#pragma unroll
        for (int nt = 0; nt < NT; ++nt) {
            int h = nt / NTPH;
            ps[h] = fmaf(acc[nt][r], attS[nt], ps[h]);
            pd[h] = fmaf(acc[nt][r], attD[nt], pd[h]);
        }
#pragma unroll
        for (int off = 1; off < 16; off <<= 1) {
#pragma unroll
            for (int h = 0; h < 4; ++h) {
                ps[h] += __shfl_xor(ps[h], off, 64);
                pd[h] += __shfl_xor(pd[h], off, 64);
            }
        }
        int row = row0 + quad * 4 + r;
        if (m == 0 && row < M) {
            asrc4[row] = make_float4(ps[0], ps[1], ps[2], ps[3]);
            adst4[row] = make_float4(pd[0], pd[1], pd[2], pd[3]);
        }
    }
}

// ---------------- aggregate: wave/node, no-max softmax, bf16-pair dot2 gather ----------------
// Unnormalized weights e=exp(clamp(l,60)) accumulated; 1/(s+eps) applied per node at the end.
// Weights stored bf16 in LDS; sum computed from the ROUNDED weights so rounding cancels in ratio.
template <int HC, bool CONCAT>
__global__ __launch_bounds__(256) void aggregate_kernel(
    const ushort* __restrict__ hsrc, const float4* __restrict__ a_src4,
    const float4* __restrict__ a_dst4, const int* __restrict__ rowptr,
    const int* __restrict__ ecol, const float* __restrict__ bias,
    void* __restrict__ outv, int N) {
    constexpr int CPL = HC / 64;            // channels per lane (2 or 4), full-wave row
    constexpr int SH = (HC == 128) ? 7 : 8; // log2(HC)
    __shared__ ushort elds[4][4][68];       // [wave][head][edge] bf16 weights (+4 pad: banks+align)
    int lane = threadIdx.x & 63, wv = threadIdx.x >> 6;
    int n = blockIdx.x * 4 + wv;
    if (n >= N) return;
    int start = rowptr[n], end = rowptr[n + 1], deg = end - start;
    float4 ad = a_dst4[n];
    int hh = lane >> 4;        // head owning this lane's channels (both HC cases)
    uint laneoff = lane * CPL; // ushort offset within a row
    float acc[CPL] = {};
    float i0, i1, i2, i3;

    // inner gather over one <=64-edge chunk: 4 edges per iteration, 2 dot2-pairs
    auto gather = [&](int sv, int len) {
        const uint2* wb = (const uint2*)(&elds[wv][hh][0]);
        for (int e = 0; e < len; e += 4) {  // overshoot slots have weight 0, sv 0
            int sA0 = __builtin_amdgcn_readlane(sv, e);
            int sA1 = __builtin_amdgcn_readlane(sv, e + 1);
            int sB0 = __builtin_amdgcn_readlane(sv, e + 2);
            int sB1 = __builtin_amdgcn_readlane(sv, e + 3);
            uint2 w = wb[e >> 2];  // .x = w(e)|w(e+1)<<16 ; .y = w(e+2)|w(e+3)<<16
            if (CPL == 2) {
                uint hA0 = *(const uint*)(hsrc + (((uint)sA0) << SH) + laneoff);
                uint hA1 = *(const uint*)(hsrc + (((uint)sA1) << SH) + laneoff);
                uint hB0 = *(const uint*)(hsrc + (((uint)sB0) << SH) + laneoff);
                uint hB1 = *(const uint*)(hsrc + (((uint)sB1) << SH) + laneoff);
#if HAS_DOT2
                acc[0] = dot2bf(__builtin_amdgcn_perm(hA0, hA1, 0x01000504), w.x, acc[0]);
                acc[1] = dot2bf(__builtin_amdgcn_perm(hA0, hA1, 0x03020706), w.x, acc[1]);
                acc[0] = dot2bf(__builtin_amdgcn_perm(hB0, hB1, 0x01000504), w.y, acc[0]);
                acc[1] = dot2bf(__builtin_amdgcn_perm(hB0, hB1, 0x03020706), w.y, acc[1]);
#else
                float wA0 = __uint_as_float(w.x << 16), wA1 = __uint_as_float(w.x & 0xffff0000u);
                float wB0 = __uint_as_float(w.y << 16), wB1 = __uint_as_float(w.y & 0xffff0000u);
                acc[0] = fmaf(wA0, __uint_as_float(hA0 << 16), acc[0]);
                acc[1] = fmaf(wA0, __uint_as_float(hA0 & 0xffff0000u), acc[1]);
                acc[0] = fmaf(wA1, __uint_as_float(hA1 << 16), acc[0]);
                acc[1] = fmaf(wA1, __uint_as_float(hA1 & 0xffff0000u), acc[1]);
                acc[0] = fmaf(wB0, __uint_as_float(hB0 << 16), acc[0]);
                acc[1] = fmaf(wB0, __uint_as_float(hB0 & 0xffff0000u), acc[1]);
                acc[0] = fmaf(wB1, __uint_as_float(hB1 << 16), acc[0]);
                acc[1] = fmaf(wB1, __uint_as_float(hB1 & 0xffff0000u), acc[1]);
#endif
            } else {
                uint2 hA0 = *(const uint2*)(hsrc + (((uint)sA0) << SH) + laneoff);
                uint2 hA1 = *(const uint2*)(hsrc + (((uint)sA1) << SH) + laneoff);
                uint2 hB0 = *(const uint2*)(hsrc + (((uint)sB0) << SH) + laneoff);
                uint2 hB1 = *(const uint2*)(hsrc + (((uint)sB1) << SH) + laneoff);
#if HAS_DOT2
                acc[0] = dot2bf(__builtin_amdgcn_perm(hA0.x, hA1.x, 0x01000504), w.x, acc[0]);
                acc[1] = dot2bf(__builtin_amdgcn_perm(hA0.x, hA1.x, 0x03020706), w.x, acc[1]);
                acc[2] = dot2bf(__builtin_amdgcn_perm(hA0.y, hA1.y, 0x01000504), w.x, acc[2]);
                acc[3] = dot2bf(__builtin_amdgcn_perm(hA0.y, hA1.y, 0x03020706), w.x, acc[3]);
                acc[0] = dot2bf(__builtin_amdgcn_perm(hB0.x, hB1.x, 0x01000504), w.y, acc[0]);
                acc[1] = dot2bf(__builtin_amdgcn_perm(hB0.x, hB1.x, 0x03020706), w.y, acc[1]);
                acc[2] = dot2bf(__builtin_amdgcn_perm(hB0.y, hB1.y, 0x01000504), w.y, acc[2]);
                acc[3] = dot2bf(__builtin_amdgcn_perm(hB0.y, hB1.y, 0x03020706), w.y, acc[3]);
#else
                float wA0 = __uint_as_float(w.x << 16), wA1 = __uint_as_float(w.x & 0xffff0000u);
                float wB0 = __uint_as_float(w.y << 16), wB1 = __uint_as_float(w.y & 0xffff0000u);
                acc[0] = fmaf(wA0, __uint_as_float(hA0.x << 16), acc[0]);
                acc[1] = fmaf(wA0, __uint_as_float(hA0.x & 0xffff0000u), acc[1]);
                acc[2] = fmaf(wA0, __uint_as_float(hA0.y << 16), acc[2]);
                acc[3] = fmaf(wA0, __uint_as_float(hA0.y & 0xffff0000u), acc[3]);
                acc[0] = fmaf(wA1, __uint_as_float(hA1.x << 16), acc[0]);
                acc[1] = fmaf(wA1, __uint_as_float(hA1.x & 0xffff0000u), acc[1]);
                acc[2] = fmaf(wA1, __uint_as_float(hA1.y << 16), acc[2]);
                acc[3] = fmaf(wA1, __uint_as_float(hA1.y & 0xffff0000u), acc[3]);
                acc[0] = fmaf(wB0, __uint_as_float(hB0.x << 16), acc[0]);
                acc[1] = fmaf(wB0, __uint_as_float(hB0.x & 0xffff0000u), acc[1]);
                acc[2] = fmaf(wB0, __uint_as_float(hB0.y << 16), acc[2]);
                acc[3] = fmaf(wB0, __uint_as_float(hB0.y & 0xffff0000u), acc[3]);
                acc[0] = fmaf(wB1, __uint_as_float(hB1.x << 16), acc[0]);
                acc[1] = fmaf(wB1, __uint_as_float(hB1.x & 0xffff0000u), acc[1]);
                acc[2] = fmaf(wB1, __uint_as_float(hB1.y << 16), acc[2]);
                acc[3] = fmaf(wB1, __uint_as_float(hB1.y & 0xffff0000u), acc[3]);
#endif
            }
        }
    };

    if (deg <= 64) {  // fast path: one chunk, everything in registers/LDS, no barriers
        bool v = lane < deg;
        int sv = v ? ecol[start + lane] : 0;
        float4 as = a_src4[sv];
        float e0 = v ? __expf(fminf(leaky(as.x + ad.x), 60.f)) : 0.f;
        float e1 = v ? __expf(fminf(leaky(as.y + ad.y), 60.f)) : 0.f;
        float e2 = v ? __expf(fminf(leaky(as.z + ad.z), 60.f)) : 0.f;
        float e3 = v ? __expf(fminf(leaky(as.w + ad.w), 60.f)) : 0.f;
        ushort r0 = f2b(e0), r1 = f2b(e1), r2 = f2b(e2), r3 = f2b(e3);
        elds[wv][0][lane] = r0; elds[wv][1][lane] = r1;
        elds[wv][2][lane] = r2; elds[wv][3][lane] = r3;
        float s0 = b2f(r0), s1 = b2f(r1), s2 = b2f(r2), s3 = b2f(r3);
#pragma unroll
        for (int off = 1; off < 64; off <<= 1) {
            s0 += __shfl_xor(s0, off, 64); s1 += __shfl_xor(s1, off, 64);
            s2 += __shfl_xor(s2, off, 64); s3 += __shfl_xor(s3, off, 64);
        }
        i0 = 1.f / (s0 + 1e-16f); i1 = 1.f / (s1 + 1e-16f);
        i2 = 1.f / (s2 + 1e-16f); i3 = 1.f / (s3 + 1e-16f);
        gather(sv, deg);
    } else {  // rare: deg > 64, chunked
        float s0 = 0, s1 = 0, s2 = 0, s3 = 0;
        for (int cs = start; cs < end; cs += 64) {
            int j = cs + lane; bool v = j < end;
            int s = v ? ecol[j] : 0;
            float4 as = a_src4[s];
            if (v) {
                s0 += b2f(f2b(__expf(fminf(leaky(as.x + ad.x), 60.f))));
                s1 += b2f(f2b(__expf(fminf(leaky(as.y + ad.y), 60.f))));
                s2 += b2f(f2b(__expf(fminf(leaky(as.z + ad.z), 60.f))));
                s3 += b2f(f2b(__expf(fminf(leaky(as.w + ad.w), 60.f))));
            }
        }
#pragma unroll
        for (int off = 1; off < 64; off <<= 1) {
            s0 += __shfl_xor(s0, off, 64); s1 += __shfl_xor(s1, off, 64);
            s2 += __shfl_xor(s2, off, 64); s3 += __shfl_xor(s3, off, 64);
        }
        i0 = 1.f / (s0 + 1e-16f); i1 = 1.f / (s1 + 1e-16f);
        i2 = 1.f / (s2 + 1e-16f); i3 = 1.f / (s3 + 1e-16f);
        for (int cs = start; cs < end; cs += 64) {
            int j = cs + lane; bool v = j < end;
            int sv = v ? ecol[j] : 0;
            float4 as = a_src4[sv];
            float e0 = v ? __expf(fminf(leaky(as.x + ad.x), 60.f)) : 0.f;
            float e1 = v ? __expf(fminf(leaky(as.y + ad.y), 60.f)) : 0.f;
            float e2 = v ? __expf(fminf(leaky(as.z + ad.z), 60.f)) : 0.f;
            float e3 = v ? __expf(fminf(leaky(as.w + ad.w), 60.f)) : 0.f;
            elds[wv][0][lane] = f2b(e0); elds[wv][1][lane] = f2b(e1);
            elds[wv][2][lane] = f2b(e2); elds[wv][3][lane] = f2b(e3);
            gather(sv, min(64, end - cs));
        }
    }

    float ih = (lane < 32) ? (lane < 16 ? i0 : i1) : (lane < 48 ? i2 : i3);
#pragma unroll
    for (int i = 0; i < CPL; ++i) acc[i] *= ih;

    if (CONCAT) {  // bias + ELU, store bf16 (next layer's GEMM input); CPL==2
        float o0 = acc[0] + bias[2 * lane + 0];
        float o1 = acc[1] + bias[2 * lane + 1];
        o0 = o0 > 0.f ? o0 : __expf(o0) - 1.f;
        o1 = o1 > 0.f ? o1 : __expf(o1) - 1.f;
        ((uint*)outv)[(size_t)n * 64 + lane] = (uint)f2b(o0) | ((uint)f2b(o1) << 16);
    } else {  // mean over 4 heads + bias, f32 out; CPL==4
#pragma unroll
        for (int i = 0; i < CPL; ++i) {
            acc[i] += __shfl_xor(acc[i], 16, 64);
            acc[i] += __shfl_xor(acc[i], 32, 64);
        }
        if (lane < 16) {
            float4 o;
            o.x = 0.25f * acc[0] + bias[4 * lane + 0];
            o.y = 0.25f * acc[1] + bias[4 * lane + 1];
            o.z = 0.25f * acc[2] + bias[4 * lane + 2];
            o.w = 0.25f * acc[3] + bias[4 * lane + 3];
            ((float4*)outv)[(size_t)n * 16 + lane] = o;
        }
    }
}

// ---------------- launch ----------------
extern "C" void kernel_launch(void* const* d_in, const int* in_sizes, int n_in,
                              void* d_out, int out_size, void* d_ws, size_t ws_size,
                              hipStream_t stream) {
    // setup_inputs order: x, edge_index, W1, att_src1, att_dst1, bias1, W2, att_src2, att_dst2, bias2
    const void* x_raw = d_in[0];
    const int*  ei    = (const int*)d_in[1];
    const void* W1_p  = d_in[2];
    const void* as1_p = d_in[3];
    const void* ad1_p = d_in[4];
    const void* b1_p  = d_in[5];
    const void* W2_p  = d_in[6];
    const void* as2_p = d_in[7];
    const void* ad2_p = d_in[8];
    const void* b2_p  = d_in[9];

    const int F_IN = 128, HC1 = 128, HC2 = 256;
    const int N = in_sizes[0] / F_IN;   // 50000
    const int E = in_sizes[1] / 2;      // 800000
    const int ET = E + N;
    const int NB = (N + 1023) / 1024;

    char* p = (char*)d_ws;
    auto alloc = [&](size_t bytes) { char* r = p; p += (bytes + 255) & ~(size_t)255; return r; };
    ushort* xbf   = (ushort*)alloc((size_t)N * F_IN * 2);
    ushort* W1T   = (ushort*)alloc((size_t)HC1 * F_IN * 2);
    ushort* W2T   = (ushort*)alloc((size_t)HC2 * HC1 * 2);
    float*  att1f = (float*)alloc(2 * HC1 * 4);
    float*  att2f = (float*)alloc(2 * HC2 * 4);
    float*  b1f   = (float*)alloc(HC1 * 4);
    float*  b2f   = (float*)alloc(64 * 4);
    ushort* h1    = (ushort*)alloc((size_t)N * HC1 * 2);
    ushort* hL1   = (ushort*)alloc((size_t)N * HC1 * 2);
    ushort* h2    = (ushort*)alloc((size_t)N * HC2 * 2);
    float*  asrc1 = (float*)alloc((size_t)N * 4 * 4);
    float*  adst1 = (float*)alloc((size_t)N * 4 * 4);
    float*  asrc2 = (float*)alloc((size_t)N * 4 * 4);
    float*  adst2 = (float*)alloc((size_t)N * 4 * 4);
    int* deg    = (int*)alloc((size_t)2 * N * 4);  // deg | cnt adjacent
    int* cnt    = deg + N;
    int* tmp    = (int*)alloc((size_t)N * 4);
    int* bsum   = (int*)alloc(128 * 4);
    int* rowptr = (int*)alloc((size_t)(N + 1) * 4);
    int* ecol   = (int*)alloc((size_t)ET * 4);
    int* flagI  = (int*)alloc(256);
    int* flagF  = (int*)alloc(256);

    hipMemsetAsync(deg, 0, (size_t)N * 4, stream);  // cnt zeroed in scan3

    detect_kernel<<<1, 256, 0, stream>>>(ei, x_raw, flagI, flagF);

    int NX = N * F_IN;
    int nxb = (NX + 255) / 256;
    int eblocks = (ET + 255) / 256;
    // arg order: x, W1, W2, as1, ad1, b1, as2, ad2, b2  (d_in 0,2,6,3,4,5,7,8,9)
    prep_kernel<<<nxb + 64 + 128 + 4 + eblocks, 256, 0, stream>>>(
        x_raw, W1_p, W2_p, as1_p, ad1_p, b1_p, as2_p, ad2_p, b2_p,
        xbf, W1T, W2T, att1f, att2f, b1f, b2f, ei, E, ET, deg, NX, flagF, flagI);

    scan1_kernel<<<NB, 1024, 0, stream>>>(deg, tmp, bsum, N);
    scan2_kernel<<<1, 64, 0, stream>>>(bsum, NB);
    scan3_kernel<<<(N + 256) / 256, 256, 0, stream>>>(tmp, bsum, rowptr, cnt, N, NB);
    scatter_kernel<<<eblocks, 256, 0, stream>>>(ei, E, N, flagI, rowptr, cnt, ecol);

    int nblocks4 = (N + 3) / 4;
    // ---- layer 1 ----
    gemm_mfma_kernel<HC1><<<(N + 63) / 64, 256, 0, stream>>>(
        xbf, W1T, h1, att1f, (float4*)asrc1, (float4*)adst1, N);
    aggregate_kernel<HC1, true><<<nblocks4, 256, 0, stream>>>(
        h1, (const float4*)asrc1, (const float4*)adst1, rowptr, ecol, b1f, hL1, N);
    // ---- layer 2 ----
    gemm_mfma_kernel<HC2><<<(N + 63) / 64, 256, 0, stream>>>(
        hL1, W2T, h2, att2f, (float4*)asrc2, (float4*)adst2, N);
    aggregate_kernel<HC2, false><<<nblocks4, 256, 0, stream>>>(
        h2, (const float4*)asrc2, (const float4*)adst2, rowptr, ecol, b2f, d_out, N);
}

// Round 6
// 344.255 us; speedup vs baseline: 2.1982x; 1.0175x over previous
//
#include <hip/hip_runtime.h>

typedef unsigned int uint;
typedef unsigned short ushort;

// N=50000 nodes, E=800000 edges, F_in=128, heads=4, C1=32 (concat->128), C2=64 (mean->64)

__device__ __forceinline__ float leaky(float x) { return x >= 0.f ? x : 0.2f * x; }
__device__ __forceinline__ float b2f(ushort h) { return __uint_as_float(((uint)h) << 16); }
__device__ __forceinline__ ushort f2b(float f) {
    uint u = __float_as_uint(f);
    return (ushort)((u + 0x7FFF + ((u >> 16) & 1)) >> 16);  // RNE
}

#if defined(__has_builtin)
#if __has_builtin(__builtin_amdgcn_fdot2_f32_bf16)
#define HAS_DOT2 1
#endif
#endif
#ifndef HAS_DOT2
#define HAS_DOT2 0
#endif

#if HAS_DOT2
typedef __bf16 bf16v2 __attribute__((ext_vector_type(2)));
__device__ __forceinline__ float dot2bf(uint h2, uint w2, float c) {
    return __builtin_amdgcn_fdot2_f32_bf16(__builtin_bit_cast(bf16v2, h2),
                                           __builtin_bit_cast(bf16v2, w2), c, false);
}
#define DOT2PAIR(hE, hE1, wpk, a0, a1)                                  \
    a0 = dot2bf(__builtin_amdgcn_perm(hE, hE1, 0x01000504), wpk, a0);   \
    a1 = dot2bf(__builtin_amdgcn_perm(hE, hE1, 0x03020706), wpk, a1);
#else
#define DOT2PAIR(hE, hE1, wpk, a0, a1)                                  \
    {                                                                   \
        float wlo = __uint_as_float((wpk) << 16);                       \
        float whi = __uint_as_float((wpk) & 0xffff0000u);               \
        a0 = fmaf(wlo, __uint_as_float((hE) << 16), a0);                \
        a1 = fmaf(wlo, __uint_as_float((hE) & 0xffff0000u), a1);        \
        a0 = fmaf(whi, __uint_as_float((hE1) << 16), a0);               \
        a1 = fmaf(whi, __uint_as_float((hE1) & 0xffff0000u), a1);       \
    }
#endif

// ---------------- dtype detection (parallel; flags in ws) ----------------
__global__ void detect_kernel(const int* __restrict__ ei, const void* __restrict__ xin,
                              int* __restrict__ flagI, int* __restrict__ flagF) {
    __shared__ int s_sane, s_odd;
    int t = threadIdx.x;  // 256 threads
    if (t == 0) { s_sane = 0; s_odd = 0; }
    __syncthreads();
    if (t < 64 && ei[2 * t + 1] != 0) atomicOr(&s_odd, 1);
    ushort v = ((const ushort*)xin)[2 * t];
    int ex = (v >> 7) & 0xFF;
    if (v == 0 || (ex >= 100 && ex <= 135)) atomicAdd(&s_sane, 1);
    __syncthreads();
    if (t == 0) { *flagI = (s_odd == 0); *flagF = (s_sane >= 230); }
}

// ---------------- fused prep: x->bf16, W1^T, W2^T, small cvts, dst histogram ----------------
// param order (x, W1, W2, as1, ad1, b1, as2, ad2, b2): call site maps d_in (0,2,6,3,4,5,7,8,9)!
__global__ void prep_kernel(const void* __restrict__ x, const void* __restrict__ W1,
                            const void* __restrict__ W2, const void* __restrict__ as1,
                            const void* __restrict__ ad1, const void* __restrict__ b1,
                            const void* __restrict__ as2, const void* __restrict__ ad2,
                            const void* __restrict__ b2, ushort* __restrict__ xbf,
                            ushort* __restrict__ W1T, ushort* __restrict__ W2T,
                            float* __restrict__ att1, float* __restrict__ att2,
                            float* __restrict__ b1f, float* __restrict__ b2f_,
                            const int* __restrict__ ei, int E, int ET, int* __restrict__ deg,
                            int NX, const int* __restrict__ flagF, const int* __restrict__ flagI) {
    int bf = *flagF;
    int b = blockIdx.x, t = threadIdx.x;
    int nxb = (NX + 255) / 256;
    if (b < nxb) {
        int i = b * 256 + t;
        if (i < NX) xbf[i] = bf ? ((const ushort*)x)[i] : f2b(((const float*)x)[i]);
        return;
    }
    b -= nxb;
    if (b < 64) {  // W1 [128][128] -> W1T [n][k]
        int i = b * 256 + t;
        int k = i >> 7, n = i & 127;
        W1T[n * 128 + k] = bf ? ((const ushort*)W1)[i] : f2b(((const float*)W1)[i]);
        return;
    }
    b -= 64;
    if (b < 128) {  // W2 [128][256] -> W2T [n][k]
        int i = b * 256 + t;
        int k = i >> 8, n = i & 255;
        W2T[(size_t)n * 128 + k] = bf ? ((const ushort*)W2)[i] : f2b(((const float*)W2)[i]);
        return;
    }
    b -= 128;
    if (b < 4) {  // small arrays: 960 total
        int i = b * 256 + t;
        float v;
        if (i < 128)      { v = bf ? b2f(((const ushort*)as1)[i])       : ((const float*)as1)[i];       att1[i] = v; }
        else if (i < 256) { v = bf ? b2f(((const ushort*)ad1)[i - 128]) : ((const float*)ad1)[i - 128]; att1[i] = v; }
        else if (i < 512) { v = bf ? b2f(((const ushort*)as2)[i - 256]) : ((const float*)as2)[i - 256]; att2[i - 256] = v; }
        else if (i < 768) { v = bf ? b2f(((const ushort*)ad2)[i - 512]) : ((const float*)ad2)[i - 512]; att2[i - 256] = v; }
        else if (i < 896) { v = bf ? b2f(((const ushort*)b1)[i - 768])  : ((const float*)b1)[i - 768];  b1f[i - 768] = v; }
        else if (i < 960) { v = bf ? b2f(((const ushort*)b2)[i - 896])  : ((const float*)b2)[i - 896];  b2f_[i - 896] = v; }
        return;
    }
    b -= 4;
    {  // dst histogram (self loops appended after edges)
        int e = b * 256 + t;
        if (e < ET) {
            int dst = (e >= E) ? (e - E) : ((*flagI) ? ei[2 * E + 2 * e] : ei[E + e]);
            atomicAdd(&deg[dst], 1);
        }
    }
}

// ---------------- CSR scan + scatter ----------------
__global__ __launch_bounds__(1024) void scan1_kernel(const int* __restrict__ deg,
                                                     int* __restrict__ tmp,
                                                     int* __restrict__ bsum, int n) {
    __shared__ int ws[16];
    int tid = threadIdx.x, lane = tid & 63, wid = tid >> 6;
    int i = blockIdx.x * 1024 + tid;
    int v = (i < n) ? deg[i] : 0;
    int incl = v;
#pragma unroll
    for (int off = 1; off < 64; off <<= 1) {
        int t2 = __shfl_up(incl, off, 64);
        if (lane >= off) incl += t2;
    }
    if (lane == 63) ws[wid] = incl;
    __syncthreads();
    if (tid < 16) {
        int wv_ = ws[tid], winc = wv_;
#pragma unroll
        for (int off = 1; off < 16; off <<= 1) {
            int t2 = __shfl_up(winc, off, 16);
            if (tid >= off) winc += t2;
        }
        ws[tid] = winc - wv_;  // exclusive wave offset
    }
    __syncthreads();
    int excl = incl - v + ws[wid];
    if (i < n) tmp[i] = excl;
    if (tid == 1023) bsum[blockIdx.x] = excl + v;
}

__global__ void scan2_kernel(int* __restrict__ bsum, int nb) {  // 1 block, 64 lanes, nb<=64
    int lane = threadIdx.x;
    int v = (lane < nb) ? bsum[lane] : 0;
    int incl = v;
    for (int off = 1; off < 64; off <<= 1) {
        int t = __shfl_up(incl, off, 64);
        if (lane >= off) incl += t;
    }
    int total = __shfl(incl, nb - 1, 64);
    if (lane < nb) bsum[lane] = incl - v;
    if (lane == 0) bsum[nb] = total;
}

__global__ void scan3_kernel(const int* __restrict__ tmp, const int* __restrict__ bsum,
                             int* __restrict__ rowptr, int* __restrict__ cnt, int n, int nb) {
    int i = blockIdx.x * blockDim.x + threadIdx.x;
    if (i > n) return;
    rowptr[i] = (i == n) ? bsum[nb] : tmp[i] + bsum[i >> 10];
    if (i < n) cnt[i] = 0;
}

__global__ void scatter_kernel(const int* __restrict__ ei, int E, int N,
                               const int* __restrict__ flag, const int* __restrict__ rowptr,
                               int* __restrict__ cnt, int* __restrict__ ecol) {
    int e = blockIdx.x * blockDim.x + threadIdx.x;
    if (e >= E + N) return;
    int src, dst;
    if (e >= E) { src = dst = e - E; }
    else if (*flag) { src = ei[2 * e]; dst = ei[2 * E + 2 * e]; }
    else            { src = ei[e];     dst = ei[E + e]; }
    int pos = rowptr[dst] + atomicAdd(&cnt[dst], 1);
    ecol[pos] = src;
}

// ---------------- MFMA GEMM + fused attdot epilogue ----------------
typedef __attribute__((ext_vector_type(8))) short bf16x8;
typedef __attribute__((ext_vector_type(4))) float floatx4;

template <int HC>
__global__ __launch_bounds__(256) void gemm_mfma_kernel(
    const ushort* __restrict__ A, const ushort* __restrict__ BT, ushort* __restrict__ C,
    const float* __restrict__ att, float4* __restrict__ asrc4, float4* __restrict__ adst4, int M) {
    constexpr int K = 128, NT = HC / 16, NTPH = HC / 64;
    int lane = threadIdx.x & 63, wv = threadIdx.x >> 6;
    int row0 = (blockIdx.x * 4 + wv) * 16;
    if (row0 >= M) return;
    int m = lane & 15, quad = lane >> 4;
    int rowa = min(row0 + m, M - 1);
    const bf16x8* arow = (const bf16x8*)(A + (size_t)rowa * K);
    bf16x8 af[4];
#pragma unroll
    for (int kk = 0; kk < 4; ++kk) af[kk] = arow[4 * kk + quad];
    floatx4 acc[NT] = {};
#pragma unroll
    for (int nt = 0; nt < NT; ++nt) {
        const bf16x8* brow = (const bf16x8*)(BT + (size_t)(nt * 16 + m) * K);
#pragma unroll
        for (int kk = 0; kk < 4; ++kk)
            acc[nt] = __builtin_amdgcn_mfma_f32_16x16x32_bf16(af[kk], brow[4 * kk + quad], acc[nt], 0, 0, 0);
    }
    // C/D layout: col = lane&15, row = quad*4 + reg
#pragma unroll
    for (int nt = 0; nt < NT; ++nt)
#pragma unroll
        for (int r = 0; r < 4; ++r) {
            int row = row0 + quad * 4 + r;
            if (row < M) C[(size_t)row * HC + nt * 16 + m] = f2b(acc[nt][r]);
        }
    float attS[NT], attD[NT];
#pragma unroll
    for (int nt = 0; nt < NT; ++nt) { attS[nt] = att[nt * 16 + m]; attD[nt] = att[HC + nt * 16 + m]; }
#pragma unroll
    for (int r = 0; r < 4; ++r) {
        float ps[4] = {0, 0, 0, 0}, pd[4] = {0, 0, 0, 0};
#pragma unroll
        for (int nt = 0; nt < NT; ++nt) {
            int h = nt / NTPH;
            ps[h] = fmaf(acc[nt][r], attS[nt], ps[h]);
            pd[h] = fmaf(acc[nt][r], attD[nt], pd[h]);
        }
#pragma unroll
        for (int off = 1; off < 16; off <<= 1) {
#pragma unroll
            for (int h = 0; h < 4; ++h) {
                ps[h] += __shfl_xor(ps[h], off, 64);
                pd[h] += __shfl_xor(pd[h], off, 64);
            }
        }
        int row = row0 + quad * 4 + r;
        if (m == 0 && row < M) {
            asrc4[row] = make_float4(ps[0], ps[1], ps[2], ps[3]);
            adst4[row] = make_float4(pd[0], pd[1], pd[2], pd[3]);
        }
    }
}

// ---------------- aggregate: wave/node, no-max softmax, 8-edge-deep dot2 gather ----------------
// Unnormalized weights e=exp(clamp(l,60)) accumulated; 1/(s+eps) applied per node at the end.
// Weights stored bf16 in LDS (sum computed from ROUNDED weights so rounding cancels in ratio).
// Gather processes 8 edges/iter with all 8 row-loads issued before use (MLP=8).
template <int HC, bool CONCAT>
__global__ __launch_bounds__(256) void aggregate_kernel(
    const ushort* __restrict__ hsrc, const float4* __restrict__ a_src4,
    const float4* __restrict__ a_dst4, const int* __restrict__ rowptr,
    const int* __restrict__ ecol, const float* __restrict__ bias,
    void* __restrict__ outv, int N) {
    constexpr int CPL = HC / 64;            // channels per lane (2 or 4), full-wave row
    constexpr int SH = (HC == 128) ? 7 : 8; // log2(HC)
    __shared__ __align__(16) ushort elds[4][4][72];  // [wave][head][edge] bf16 w (72: 16B-aligned stride)
    int lane = threadIdx.x & 63, wv = threadIdx.x >> 6;
    int n = blockIdx.x * 4 + wv;
    if (n >= N) return;
    int start = rowptr[n], end = rowptr[n + 1], deg = end - start;
    float4 ad = a_dst4[n];
    int hh = lane >> 4;        // head owning this lane's channels (both HC cases)
    uint laneoff = lane * CPL; // ushort offset within a row
    float acc[CPL] = {};
    float i0, i1, i2, i3;

    // gather one <=64-edge chunk: 8 edges/iter, 8 loads in flight, one ds_read_b128 of weights
    auto gather = [&](int sv, int len) {
        const uint4* wb = (const uint4*)(&elds[wv][hh][0]);
        for (int e = 0; e < len; e += 8) {  // overshoot slots: weight 0, sv 0
            int s0 = __builtin_amdgcn_readlane(sv, e);
            int s1 = __builtin_amdgcn_readlane(sv, e + 1);
            int s2 = __builtin_amdgcn_readlane(sv, e + 2);
            int s3 = __builtin_amdgcn_readlane(sv, e + 3);
            int s4 = __builtin_amdgcn_readlane(sv, e + 4);
            int s5 = __builtin_amdgcn_readlane(sv, e + 5);
            int s6 = __builtin_amdgcn_readlane(sv, e + 6);
            int s7 = __builtin_amdgcn_readlane(sv, e + 7);
            uint4 w = wb[e >> 3];  // 8 bf16 weights: .x=e,e+1 .y=e+2,e+3 .z=e+4,e+5 .w=e+6,e+7
            if (CPL == 2) {
                uint h0 = *(const uint*)(hsrc + (((uint)s0) << SH) + laneoff);
                uint h1 = *(const uint*)(hsrc + (((uint)s1) << SH) + laneoff);
                uint h2 = *(const uint*)(hsrc + (((uint)s2) << SH) + laneoff);
                uint h3 = *(const uint*)(hsrc + (((uint)s3) << SH) + laneoff);
                uint h4 = *(const uint*)(hsrc + (((uint)s4) << SH) + laneoff);
                uint h5 = *(const uint*)(hsrc + (((uint)s5) << SH) + laneoff);
                uint h6 = *(const uint*)(hsrc + (((uint)s6) << SH) + laneoff);
                uint h7 = *(const uint*)(hsrc + (((uint)s7) << SH) + laneoff);
                DOT2PAIR(h0, h1, w.x, acc[0], acc[1]);
                DOT2PAIR(h2, h3, w.y, acc[0], acc[1]);
                DOT2PAIR(h4, h5, w.z, acc[0], acc[1]);
                DOT2PAIR(h6, h7, w.w, acc[0], acc[1]);
            } else {
                uint2 h0 = *(const uint2*)(hsrc + (((uint)s0) << SH) + laneoff);
                uint2 h1 = *(const uint2*)(hsrc + (((uint)s1) << SH) + laneoff);
                uint2 h2 = *(const uint2*)(hsrc + (((uint)s2) << SH) + laneoff);
                uint2 h3 = *(const uint2*)(hsrc + (((uint)s3) << SH) + laneoff);
                uint2 h4 = *(const uint2*)(hsrc + (((uint)s4) << SH) + laneoff);
                uint2 h5 = *(const uint2*)(hsrc + (((uint)s5) << SH) + laneoff);
                uint2 h6 = *(const uint2*)(hsrc + (((uint)s6) << SH) + laneoff);
                uint2 h7 = *(const uint2*)(hsrc + (((uint)s7) << SH) + laneoff);
                DOT2PAIR(h0.x, h1.x, w.x, acc[0], acc[1]);
                DOT2PAIR(h0.y, h1.y, w.x, acc[2], acc[3]);
                DOT2PAIR(h2.x, h3.x, w.y, acc[0], acc[1]);
                DOT2PAIR(h2.y, h3.y, w.y, acc[2], acc[3]);
                DOT2PAIR(h4.x, h5.x, w.z, acc[0], acc[1]);
                DOT2PAIR(h4.y, h5.y, w.z, acc[2], acc[3]);
                DOT2PAIR(h6.x, h7.x, w.w, acc[0], acc[1]);
                DOT2PAIR(h6.y, h7.y, w.w, acc[2], acc[3]);
            }
        }
    };

    if (deg <= 64) {  // fast path: one chunk, no barriers
        bool v = lane < deg;
        int sv = v ? ecol[start + lane] : 0;
        float4 as = a_src4[sv];
        float e0 = v ? __expf(fminf(leaky(as.x + ad.x), 60.f)) : 0.f;
        float e1 = v ? __expf(fminf(leaky(as.y + ad.y), 60.f)) : 0.f;
        float e2 = v ? __expf(fminf(leaky(as.z + ad.z), 60.f)) : 0.f;
        float e3 = v ? __expf(fminf(leaky(as.w + ad.w), 60.f)) : 0.f;
        ushort r0 = f2b(e0), r1 = f2b(e1), r2 = f2b(e2), r3 = f2b(e3);
        elds[wv][0][lane] = r0; elds[wv][1][lane] = r1;
        elds[wv][2][lane] = r2; elds[wv][3][lane] = r3;
        float s0 = b2f(r0), s1 = b2f(r1), s2 = b2f(r2), s3 = b2f(r3);
#pragma unroll
        for (int off = 1; off < 64; off <<= 1) {
            s0 += __shfl_xor(s0, off, 64); s1 += __shfl_xor(s1, off, 64);
            s2 += __shfl_xor(s2, off, 64); s3 += __shfl_xor(s3, off, 64);
        }
        i0 = 1.f / (s0 + 1e-16f); i1 = 1.f / (s1 + 1e-16f);
        i2 = 1.f / (s2 + 1e-16f); i3 = 1.f / (s3 + 1e-16f);
        gather(sv, deg);
    } else {  // rare: deg > 64, chunked
        float s0 = 0, s1 = 0, s2 = 0, s3 = 0;
        for (int cs = start; cs < end; cs += 64) {
            int j = cs + lane; bool v = j < end;
            int s = v ? ecol[j] : 0;
            float4 as = a_src4[s];
            if (v) {
                s0 += b2f(f2b(__expf(fminf(leaky(as.x + ad.x), 60.f))));
                s1 += b2f(f2b(__expf(fminf(leaky(as.y + ad.y), 60.f))));
                s2 += b2f(f2b(__expf(fminf(leaky(as.z + ad.z), 60.f))));
                s3 += b2f(f2b(__expf(fminf(leaky(as.w + ad.w), 60.f))));
            }
        }
#pragma unroll
        for (int off = 1; off < 64; off <<= 1) {
            s0 += __shfl_xor(s0, off, 64); s1 += __shfl_xor(s1, off, 64);
            s2 += __shfl_xor(s2, off, 64); s3 += __shfl_xor(s3, off, 64);
        }
        i0 = 1.f / (s0 + 1e-16f); i1 = 1.f / (s1 + 1e-16f);
        i2 = 1.f / (s2 + 1e-16f); i3 = 1.f / (s3 + 1e-16f);
        for (int cs = start; cs < end; cs += 64) {
            int j = cs + lane; bool v = j < end;
            int sv = v ? ecol[j] : 0;
            float4 as = a_src4[sv];
            float e0 = v ? __expf(fminf(leaky(as.x + ad.x), 60.f)) : 0.f;
            float e1 = v ? __expf(fminf(leaky(as.y + ad.y), 60.f)) : 0.f;
            float e2 = v ? __expf(fminf(leaky(as.z + ad.z), 60.f)) : 0.f;
            float e3 = v ? __expf(fminf(leaky(as.w + ad.w), 60.f)) : 0.f;
            elds[wv][0][lane] = f2b(e0); elds[wv][1][lane] = f2b(e1);
            elds[wv][2][lane] = f2b(e2); elds[wv][3][lane] = f2b(e3);
            gather(sv, min(64, end - cs));
        }
    }

    float ih = (lane < 32) ? (lane < 16 ? i0 : i1) : (lane < 48 ? i2 : i3);
#pragma unroll
    for (int i = 0; i < CPL; ++i) acc[i] *= ih;

    if (CONCAT) {  // bias + ELU, store bf16 (next layer's GEMM input); CPL==2
        float o0 = acc[0] + bias[2 * lane + 0];
        float o1 = acc[1] + bias[2 * lane + 1];
        o0 = o0 > 0.f ? o0 : __expf(o0) - 1.f;
        o1 = o1 > 0.f ? o1 : __expf(o1) - 1.f;
        ((uint*)outv)[(size_t)n * 64 + lane] = (uint)f2b(o0) | ((uint)f2b(o1) << 16);
    } else {  // mean over 4 heads + bias, f32 out; CPL==4
#pragma unroll
        for (int i = 0; i < CPL; ++i) {
            acc[i] += __shfl_xor(acc[i], 16, 64);
            acc[i] += __shfl_xor(acc[i], 32, 64);
        }
        if (lane < 16) {
            float4 o;
            o.x = 0.25f * acc[0] + bias[4 * lane + 0];
            o.y = 0.25f * acc[1] + bias[4 * lane + 1];
            o.z = 0.25f * acc[2] + bias[4 * lane + 2];
            o.w = 0.25f * acc[3] + bias[4 * lane + 3];
            ((float4*)outv)[(size_t)n * 16 + lane] = o;
        }
    }
}

// ---------------- launch ----------------
extern "C" void kernel_launch(void* const* d_in, const int* in_sizes, int n_in,
                              void* d_out, int out_size, void* d_ws, size_t ws_size,
                              hipStream_t stream) {
    // setup_inputs order: x, edge_index, W1, att_src1, att_dst1, bias1, W2, att_src2, att_dst2, bias2
    const void* x_raw = d_in[0];
    const int*  ei    = (const int*)d_in[1];
    const void* W1_p  = d_in[2];
    const void* as1_p = d_in[3];
    const void* ad1_p = d_in[4];
    const void* b1_p  = d_in[5];
    const void* W2_p  = d_in[6];
    const void* as2_p = d_in[7];
    const void* ad2_p = d_in[8];
    const void* b2_p  = d_in[9];

    const int F_IN = 128, HC1 = 128, HC2 = 256;
    const int N = in_sizes[0] / F_IN;   // 50000
    const int E = in_sizes[1] / 2;      // 800000
    const int ET = E + N;
    const int NB = (N + 1023) / 1024;

    char* p = (char*)d_ws;
    auto alloc = [&](size_t bytes) { char* r = p; p += (bytes + 255) & ~(size_t)255; return r; };
    ushort* xbf   = (ushort*)alloc((size_t)N * F_IN * 2);
    ushort* W1T   = (ushort*)alloc((size_t)HC1 * F_IN * 2);
    ushort* W2T   = (ushort*)alloc((size_t)HC2 * HC1 * 2);
    float*  att1f = (float*)alloc(2 * HC1 * 4);
    float*  att2f = (float*)alloc(2 * HC2 * 4);
    float*  b1f   = (float*)alloc(HC1 * 4);
    float*  b2f   = (float*)alloc(64 * 4);
    ushort* h1    = (ushort*)alloc((size_t)N * HC1 * 2);
    ushort* hL1   = (ushort*)alloc((size_t)N * HC1 * 2);
    ushort* h2    = (ushort*)alloc((size_t)N * HC2 * 2);
    float*  asrc1 = (float*)alloc((size_t)N * 4 * 4);
    float*  adst1 = (float*)alloc((size_t)N * 4 * 4);
    float*  asrc2 = (float*)alloc((size_t)N * 4 * 4);
    float*  adst2 = (float*)alloc((size_t)N * 4 * 4);
    int* deg    = (int*)alloc((size_t)2 * N * 4);  // deg | cnt adjacent
    int* cnt    = deg + N;
    int* tmp    = (int*)alloc((size_t)N * 4);
    int* bsum   = (int*)alloc(128 * 4);
    int* rowptr = (int*)alloc((size_t)(N + 1) * 4);
    int* ecol   = (int*)alloc((size_t)ET * 4);
    int* flagI  = (int*)alloc(256);
    int* flagF  = (int*)alloc(256);

    hipMemsetAsync(deg, 0, (size_t)N * 4, stream);  // cnt zeroed in scan3

    detect_kernel<<<1, 256, 0, stream>>>(ei, x_raw, flagI, flagF);

    int NX = N * F_IN;
    int nxb = (NX + 255) / 256;
    int eblocks = (ET + 255) / 256;
    // arg order: x, W1, W2, as1, ad1, b1, as2, ad2, b2  (d_in 0,2,6,3,4,5,7,8,9)
    prep_kernel<<<nxb + 64 + 128 + 4 + eblocks, 256, 0, stream>>>(
        x_raw, W1_p, W2_p, as1_p, ad1_p, b1_p, as2_p, ad2_p, b2_p,
        xbf, W1T, W2T, att1f, att2f, b1f, b2f, ei, E, ET, deg, NX, flagF, flagI);

    scan1_kernel<<<NB, 1024, 0, stream>>>(deg, tmp, bsum, N);
    scan2_kernel<<<1, 64, 0, stream>>>(bsum, NB);
    scan3_kernel<<<(N + 256) / 256, 256, 0, stream>>>(tmp, bsum, rowptr, cnt, N, NB);
    scatter_kernel<<<eblocks, 256, 0, stream>>>(ei, E, N, flagI, rowptr, cnt, ecol);

    int nblocks4 = (N + 3) / 4;
    // ---- layer 1 ----
    gemm_mfma_kernel<HC1><<<(N + 63) / 64, 256, 0, stream>>>(
        xbf, W1T, h1, att1f, (float4*)asrc1, (float4*)adst1, N);
    aggregate_kernel<HC1, true><<<nblocks4, 256, 0, stream>>>(
        h1, (const float4*)asrc1, (const float4*)adst1, rowptr, ecol, b1f, hL1, N);
    // ---- layer 2 ----
    gemm_mfma_kernel<HC2><<<(N + 63) / 64, 256, 0, stream>>>(
        hL1, W2T, h2, att2f, (float4*)asrc2, (float4*)adst2, N);
    aggregate_kernel<HC2, false><<<nblocks4, 256, 0, stream>>>(
        h2, (const float4*)asrc2, (const float4*)adst2, rowptr, ecol, b2f, d_out, N);
}

// Round 8
// 341.872 us; speedup vs baseline: 2.2135x; 1.0070x over previous
//
#include <hip/hip_runtime.h>

typedef unsigned int uint;
typedef unsigned short ushort;

// N=50000 nodes, E=800000 edges, F_in=128, heads=4, C1=32 (concat->128), C2=64 (mean->64)
// R8: layer 1 = R6 (proven): gemm1(x->h1, fused attdot1) -> agg1(h1->hL1, bias+ELU, fused attdot2).
// Layer 2 restructured PER-HEAD (R7's bug fixed): z2^h = softmax_h-agg(hL1) [N,4,128] bf16,
// out = z2 @ W2stackT + b2 with W2sT[c][h*128+k] = 0.25*W2[k][h*64+c]  (K=512 MFMA GEMM).

__device__ __forceinline__ float leaky(float x) { return x >= 0.f ? x : 0.2f * x; }
__device__ __forceinline__ float b2f(ushort h) { return __uint_as_float(((uint)h) << 16); }
__device__ __forceinline__ ushort f2b(float f) {
    uint u = __float_as_uint(f);
    return (ushort)((u + 0x7FFF + ((u >> 16) & 1)) >> 16);  // RNE
}

#if defined(__has_builtin)
#if __has_builtin(__builtin_amdgcn_fdot2_f32_bf16)
#define HAS_DOT2 1
#endif
#endif
#ifndef HAS_DOT2
#define HAS_DOT2 0
#endif

#if HAS_DOT2
typedef __bf16 bf16v2 __attribute__((ext_vector_type(2)));
__device__ __forceinline__ float dot2bf(uint h2, uint w2, float c) {
    return __builtin_amdgcn_fdot2_f32_bf16(__builtin_bit_cast(bf16v2, h2),
                                           __builtin_bit_cast(bf16v2, w2), c, false);
}
// identical perm calls across heads are CSE'd by the compiler
#define DOT2PAIR(hE, hE1, wpk, a0, a1)                                  \
    a0 = dot2bf(__builtin_amdgcn_perm(hE, hE1, 0x01000504), wpk, a0);   \
    a1 = dot2bf(__builtin_amdgcn_perm(hE, hE1, 0x03020706), wpk, a1);
#else
#define DOT2PAIR(hE, hE1, wpk, a0, a1)                                  \
    {                                                                   \
        float wlo = __uint_as_float((wpk) << 16);                       \
        float whi = __uint_as_float((wpk) & 0xffff0000u);               \
        a0 = fmaf(wlo, __uint_as_float((hE) << 16), a0);                \
        a1 = fmaf(wlo, __uint_as_float((hE) & 0xffff0000u), a1);        \
        a0 = fmaf(whi, __uint_as_float((hE1) << 16), a0);               \
        a1 = fmaf(whi, __uint_as_float((hE1) & 0xffff0000u), a1);       \
    }
#endif

// ---------------- dtype detection ----------------
__global__ void detect_kernel(const int* __restrict__ ei, const void* __restrict__ xin,
                              int* __restrict__ flagI, int* __restrict__ flagF) {
    __shared__ int s_sane, s_odd;
    int t = threadIdx.x;  // 256 threads
    if (t == 0) { s_sane = 0; s_odd = 0; }
    __syncthreads();
    if (t < 64 && ei[2 * t + 1] != 0) atomicOr(&s_odd, 1);
    ushort v = ((const ushort*)xin)[2 * t];
    int ex = (v >> 7) & 0xFF;
    if (v == 0 || (ex >= 100 && ex <= 135)) atomicAdd(&s_sane, 1);
    __syncthreads();
    if (t == 0) { *flagI = (s_odd == 0); *flagF = (s_sane >= 230); }
}

__device__ __forceinline__ float rdf(const void* p_, int i, int bf) {
    return bf ? b2f(((const ushort*)p_)[i]) : ((const float*)p_)[i];
}

// ---------------- prep: x->bf16, W1^T, att1/b1/b2 cvts, dst histogram ----------------
// signature (x, W1, as1, ad1, b1, b2, ...) -- call site maps d_in (0, 2, 3, 4, 5, 9)
__global__ void prep_kernel(const void* __restrict__ x, const void* __restrict__ W1,
                            const void* __restrict__ as1, const void* __restrict__ ad1,
                            const void* __restrict__ b1, const void* __restrict__ b2,
                            ushort* __restrict__ xbf, ushort* __restrict__ W1T,
                            float* __restrict__ att1, float* __restrict__ b1f,
                            float* __restrict__ b2f_,
                            const int* __restrict__ ei, int E, int ET, int* __restrict__ deg,
                            int NX, const int* __restrict__ flagF, const int* __restrict__ flagI) {
    int bf = *flagF;
    int b = blockIdx.x, t = threadIdx.x;
    int nxb = (NX + 255) / 256;
    if (b < nxb) {
        int i = b * 256 + t;
        if (i < NX) xbf[i] = bf ? ((const ushort*)x)[i] : f2b(((const float*)x)[i]);
        return;
    }
    b -= nxb;
    if (b < 64) {  // W1 [128 k][128 n] -> W1T [n][k]
        int i = b * 256 + t;
        int k = i >> 7, n = i & 127;
        W1T[n * 128 + k] = bf ? ((const ushort*)W1)[i] : f2b(((const float*)W1)[i]);
        return;
    }
    b -= 64;
    if (b < 2) {  // smalls: 512 idx
        int i = b * 256 + t;
        if (i < 128)      att1[i] = rdf(as1, i, bf);
        else if (i < 256) att1[i] = rdf(ad1, i - 128, bf);
        else if (i < 384) b1f[i - 256] = rdf(b1, i - 256, bf);
        else if (i < 448) b2f_[i - 384] = rdf(b2, i - 384, bf);
        return;
    }
    b -= 2;
    {  // dst histogram (self loops appended after edges)
        int e = b * 256 + t;
        if (e < ET) {
            int dst = (e >= E) ? (e - E) : ((*flagI) ? ei[2 * E + 2 * e] : ei[E + e]);
            atomicAdd(&deg[dst], 1);
        }
    }
}

// ---------------- prep2: folded attention-2 vectors + stacked mean-folded W2 ----------------
// w2t8[o][k] = sum_{c<64} W2[k][h*64+c]*att2_{sd}[h][c],  o=sd*4+h  (sd=0:src,1:dst)
// W2sT[c][h*128+k] = bf16(0.25*W2[k][h*64+c])   c<64
__global__ void prep2_kernel(const void* __restrict__ W2, const void* __restrict__ as2,
                             const void* __restrict__ ad2, float* __restrict__ w2t8,
                             ushort* __restrict__ W2sT, const int* __restrict__ flagF) {
    int bf = *flagF;
    int b = blockIdx.x, t = threadIdx.x;
    if (b < 4) {
        int idx = b * 256 + t;  // 1024 = 8 o x 128 k
        int o = idx >> 7, k = idx & 127, h = o & 3;
        const void* att = (o < 4) ? as2 : ad2;
        float s = 0.f;
        for (int c = 0; c < 64; ++c) s += rdf(W2, k * 256 + h * 64 + c, bf) * rdf(att, h * 64 + c, bf);
        w2t8[o * 128 + k] = s;
        return;
    }
    b -= 4;
    {  // 128 blocks: 32768 = 64 c x 512 hk
        int idx = b * 256 + t;
        int c = idx >> 9, hk = idx & 511;
        int h = hk >> 7, k = hk & 127;
        W2sT[c * 512 + hk] = f2b(0.25f * rdf(W2, k * 256 + h * 64 + c, bf));
    }
}

// ---------------- CSR scan + scatter ----------------
__global__ __launch_bounds__(1024) void scan1_kernel(const int* __restrict__ deg,
                                                     int* __restrict__ tmp,
                                                     int* __restrict__ bsum, int n) {
    __shared__ int ws[16];
    int tid = threadIdx.x, lane = tid & 63, wid = tid >> 6;
    int i = blockIdx.x * 1024 + tid;
    int v = (i < n) ? deg[i] : 0;
    int incl = v;
#pragma unroll
    for (int off = 1; off < 64; off <<= 1) {
        int t2 = __shfl_up(incl, off, 64);
        if (lane >= off) incl += t2;
    }
    if (lane == 63) ws[wid] = incl;
    __syncthreads();
    if (tid < 16) {
        int wv_ = ws[tid], winc = wv_;
#pragma unroll
        for (int off = 1; off < 16; off <<= 1) {
            int t2 = __shfl_up(winc, off, 16);
            if (tid >= off) winc += t2;
        }
        ws[tid] = winc - wv_;
    }
    __syncthreads();
    int excl = incl - v + ws[wid];
    if (i < n) tmp[i] = excl;
    if (tid == 1023) bsum[blockIdx.x] = excl + v;
}

__global__ void scan2_kernel(int* __restrict__ bsum, int nb) {
    int lane = threadIdx.x;
    int v = (lane < nb) ? bsum[lane] : 0;
    int incl = v;
    for (int off = 1; off < 64; off <<= 1) {
        int t = __shfl_up(incl, off, 64);
        if (lane >= off) incl += t;
    }
    int total = __shfl(incl, nb - 1, 64);
    if (lane < nb) bsum[lane] = incl - v;
    if (lane == 0) bsum[nb] = total;
}

__global__ void scan3_kernel(const int* __restrict__ tmp, const int* __restrict__ bsum,
                             int* __restrict__ rowptr, int* __restrict__ cnt, int n, int nb) {
    int i = blockIdx.x * blockDim.x + threadIdx.x;
    if (i > n) return;
    rowptr[i] = (i == n) ? bsum[nb] : tmp[i] + bsum[i >> 10];
    if (i < n) cnt[i] = 0;
}

__global__ void scatter_kernel(const int* __restrict__ ei, int E, int N,
                               const int* __restrict__ flag, const int* __restrict__ rowptr,
                               int* __restrict__ cnt, int* __restrict__ ecol) {
    int e = blockIdx.x * blockDim.x + threadIdx.x;
    if (e >= E + N) return;
    int src, dst;
    if (e >= E) { src = dst = e - E; }
    else if (*flag) { src = ei[2 * e]; dst = ei[2 * E + 2 * e]; }
    else            { src = ei[e];     dst = ei[E + e]; }
    int pos = rowptr[dst] + atomicAdd(&cnt[dst], 1);
    ecol[pos] = src;
}

// ---------------- gemm1: h1 = x@W1 (bf16) + fused attdot1 (R6-proven) ----------------
typedef __attribute__((ext_vector_type(8))) short bf16x8;
typedef __attribute__((ext_vector_type(4))) float floatx4;

__global__ __launch_bounds__(256) void gemm1_kernel(
    const ushort* __restrict__ A, const ushort* __restrict__ BT, ushort* __restrict__ C,
    const float* __restrict__ att, float4* __restrict__ asrc4, float4* __restrict__ adst4, int M) {
    constexpr int K = 128, NT = 8;  // HC=128
    int lane = threadIdx.x & 63, wv = threadIdx.x >> 6;
    int row0 = (blockIdx.x * 4 + wv) * 16;
    if (row0 >= M) return;
    int m = lane & 15, quad = lane >> 4;
    int rowa = min(row0 + m, M - 1);
    const bf16x8* arow = (const bf16x8*)(A + (size_t)rowa * K);
    bf16x8 af[4];
#pragma unroll
    for (int kk = 0; kk < 4; ++kk) af[kk] = arow[4 * kk + quad];
    floatx4 acc[NT] = {};
#pragma unroll
    for (int nt = 0; nt < NT; ++nt) {
        const bf16x8* brow = (const bf16x8*)(BT + (size_t)(nt * 16 + m) * K);
#pragma unroll
        for (int kk = 0; kk < 4; ++kk)
            acc[nt] = __builtin_amdgcn_mfma_f32_16x16x32_bf16(af[kk], brow[4 * kk + quad], acc[nt], 0, 0, 0);
    }
    // C/D layout: col = lane&15, row = quad*4 + reg
#pragma unroll
    for (int nt = 0; nt < NT; ++nt)
#pragma unroll
        for (int r = 0; r < 4; ++r) {
            int row = row0 + quad * 4 + r;
            if (row < M) C[(size_t)row * 128 + nt * 16 + m] = f2b(acc[nt][r]);
        }
    float attS[NT], attD[NT];
#pragma unroll
    for (int nt = 0; nt < NT; ++nt) { attS[nt] = att[nt * 16 + m]; attD[nt] = att[128 + nt * 16 + m]; }
#pragma unroll
    for (int r = 0; r < 4; ++r) {
        float ps[4] = {0, 0, 0, 0}, pd[4] = {0, 0, 0, 0};
#pragma unroll
        for (int nt = 0; nt < NT; ++nt) {
            int h = nt / 2;  // layer-1 head = col/32
            ps[h] = fmaf(acc[nt][r], attS[nt], ps[h]);
            pd[h] = fmaf(acc[nt][r], attD[nt], pd[h]);
        }
#pragma unroll
        for (int off = 1; off < 16; off <<= 1) {
#pragma unroll
            for (int h = 0; h < 4; ++h) {
                ps[h] += __shfl_xor(ps[h], off, 64);
                pd[h] += __shfl_xor(pd[h], off, 64);
            }
        }
        int row = row0 + quad * 4 + r;
        if (m == 0 && row < M) {
            asrc4[row] = make_float4(ps[0], ps[1], ps[2], ps[3]);
            adst4[row] = make_float4(pd[0], pd[1], pd[2], pd[3]);
        }
    }
}

// ---------------- agg1: R6 aggregate (h1 -> hL1, bias+ELU) + fused attdot2 epilogue -----------
__global__ __launch_bounds__(256) void agg1_kernel(
    const ushort* __restrict__ hsrc, const float4* __restrict__ a_src4,
    const float4* __restrict__ a_dst4, const int* __restrict__ rowptr,
    const int* __restrict__ ecol, const float* __restrict__ bias,
    const float* __restrict__ w2t8, uint* __restrict__ outz,
    float4* __restrict__ asrc2, float4* __restrict__ adst2, int N) {
    constexpr int SH = 7;
    __shared__ __align__(16) ushort elds[4][4][72];
    int lane = threadIdx.x & 63, wv = threadIdx.x >> 6;
    int n = blockIdx.x * 4 + wv;
    if (n >= N) return;
    int start = rowptr[n], end = rowptr[n + 1], deg = end - start;
    float4 ad = a_dst4[n];
    int hh = lane >> 4;  // layer-1 head owning channels 2*lane,2*lane+1
    uint laneoff = lane * 2;
    float acc0 = 0.f, acc1 = 0.f;
    float i0, i1, i2, i3;

    auto gather = [&](int sv, int len) {
        const uint4* wb = (const uint4*)(&elds[wv][hh][0]);
        for (int e = 0; e < len; e += 8) {
            int s0 = __builtin_amdgcn_readlane(sv, e);
            int s1 = __builtin_amdgcn_readlane(sv, e + 1);
            int s2 = __builtin_amdgcn_readlane(sv, e + 2);
            int s3 = __builtin_amdgcn_readlane(sv, e + 3);
            int s4 = __builtin_amdgcn_readlane(sv, e + 4);
            int s5 = __builtin_amdgcn_readlane(sv, e + 5);
            int s6 = __builtin_amdgcn_readlane(sv, e + 6);
            int s7 = __builtin_amdgcn_readlane(sv, e + 7);
            uint4 w = wb[e >> 3];
            uint h0 = *(const uint*)(hsrc + (((uint)s0) << SH) + laneoff);
            uint h1 = *(const uint*)(hsrc + (((uint)s1) << SH) + laneoff);
            uint h2 = *(const uint*)(hsrc + (((uint)s2) << SH) + laneoff);
            uint h3 = *(const uint*)(hsrc + (((uint)s3) << SH) + laneoff);
            uint h4 = *(const uint*)(hsrc + (((uint)s4) << SH) + laneoff);
            uint h5 = *(const uint*)(hsrc + (((uint)s5) << SH) + laneoff);
            uint h6 = *(const uint*)(hsrc + (((uint)s6) << SH) + laneoff);
            uint h7 = *(const uint*)(hsrc + (((uint)s7) << SH) + laneoff);
            DOT2PAIR(h0, h1, w.x, acc0, acc1);
            DOT2PAIR(h2, h3, w.y, acc0, acc1);
            DOT2PAIR(h4, h5, w.z, acc0, acc1);
            DOT2PAIR(h6, h7, w.w, acc0, acc1);
        }
    };

    if (deg <= 64) {
        bool v = lane < deg;
        int sv = v ? ecol[start + lane] : 0;
        float4 as = a_src4[sv];
        float e0 = v ? __expf(fminf(leaky(as.x + ad.x), 60.f)) : 0.f;
        float e1 = v ? __expf(fminf(leaky(as.y + ad.y), 60.f)) : 0.f;
        float e2 = v ? __expf(fminf(leaky(as.z + ad.z), 60.f)) : 0.f;
        float e3 = v ? __expf(fminf(leaky(as.w + ad.w), 60.f)) : 0.f;
        ushort r0 = f2b(e0), r1 = f2b(e1), r2 = f2b(e2), r3 = f2b(e3);
        elds[wv][0][lane] = r0; elds[wv][1][lane] = r1;
        elds[wv][2][lane] = r2; elds[wv][3][lane] = r3;
        float s0 = b2f(r0), s1 = b2f(r1), s2 = b2f(r2), s3 = b2f(r3);
#pragma unroll
        for (int off = 1; off < 64; off <<= 1) {
            s0 += __shfl_xor(s0, off, 64); s1 += __shfl_xor(s1, off, 64);
            s2 += __shfl_xor(s2, off, 64); s3 += __shfl_xor(s3, off, 64);
        }
        i0 = 1.f / (s0 + 1e-16f); i1 = 1.f / (s1 + 1e-16f);
        i2 = 1.f / (s2 + 1e-16f); i3 = 1.f / (s3 + 1e-16f);
        gather(sv, deg);
    } else {
        float s0 = 0, s1 = 0, s2 = 0, s3 = 0;
        for (int cs = start; cs < end; cs += 64) {
            int j = cs + lane; bool v = j < end;
            int s = v ? ecol[j] : 0;
            float4 as = a_src4[s];
            if (v) {
                s0 += b2f(f2b(__expf(fminf(leaky(as.x + ad.x), 60.f))));
                s1 += b2f(f2b(__expf(fminf(leaky(as.y + ad.y), 60.f))));
                s2 += b2f(f2b(__expf(fminf(leaky(as.z + ad.z), 60.f))));
                s3 += b2f(f2b(__expf(fminf(leaky(as.w + ad.w), 60.f))));
            }
        }
#pragma unroll
        for (int off = 1; off < 64; off <<= 1) {
            s0 += __shfl_xor(s0, off, 64); s1 += __shfl_xor(s1, off, 64);
            s2 += __shfl_xor(s2, off, 64); s3 += __shfl_xor(s3, off, 64);
        }
        i0 = 1.f / (s0 + 1e-16f); i1 = 1.f / (s1 + 1e-16f);
        i2 = 1.f / (s2 + 1e-16f); i3 = 1.f / (s3 + 1e-16f);
        for (int cs = start; cs < end; cs += 64) {
            int j = cs + lane; bool v = j < end;
            int sv = v ? ecol[j] : 0;
            float4 as = a_src4[sv];
            float e0 = v ? __expf(fminf(leaky(as.x + ad.x), 60.f)) : 0.f;
            float e1 = v ? __expf(fminf(leaky(as.y + ad.y), 60.f)) : 0.f;
            float e2 = v ? __expf(fminf(leaky(as.z + ad.z), 60.f)) : 0.f;
            float e3 = v ? __expf(fminf(leaky(as.w + ad.w), 60.f)) : 0.f;
            elds[wv][0][lane] = f2b(e0); elds[wv][1][lane] = f2b(e1);
            elds[wv][2][lane] = f2b(e2); elds[wv][3][lane] = f2b(e3);
            gather(sv, min(64, end - cs));
        }
    }

    float ih = (lane < 32) ? (lane < 16 ? i0 : i1) : (lane < 48 ? i2 : i3);
    float o0 = acc0 * ih + bias[2 * lane + 0];
    float o1 = acc1 * ih + bias[2 * lane + 1];
    o0 = o0 > 0.f ? o0 : __expf(o0) - 1.f;  // ELU
    o1 = o1 > 0.f ? o1 : __expf(o1) - 1.f;
    outz[(size_t)n * 64 + lane] = (uint)f2b(o0) | ((uint)f2b(o1) << 16);

    // fused attdot2: a2[o] = hL1[n] . w2t8[o]
    float po[8];
#pragma unroll
    for (int o = 0; o < 8; ++o) {
        float2 w = ((const float2*)(w2t8 + o * 128))[lane];
        po[o] = fmaf(o0, w.x, o1 * w.y);
    }
#pragma unroll
    for (int off = 1; off < 64; off <<= 1)
#pragma unroll
        for (int o = 0; o < 8; ++o) po[o] += __shfl_xor(po[o], off, 64);
    if (lane == 0) {
        asrc2[n] = make_float4(po[0], po[1], po[2], po[3]);
        adst2[n] = make_float4(po[4], po[5], po[6], po[7]);
    }
}

// ---------------- agg2: per-head aggregate of hL1 -> z2 [N][4][128] bf16 ----------------
__global__ __launch_bounds__(256) void agg2_kernel(
    const ushort* __restrict__ hsrc, const float4* __restrict__ a_src4,
    const float4* __restrict__ a_dst4, const int* __restrict__ rowptr,
    const int* __restrict__ ecol, uint* __restrict__ z2u, int N) {
    constexpr int SH = 7;
    __shared__ __align__(16) ushort elds[4][4][72];
    int lane = threadIdx.x & 63, wv = threadIdx.x >> 6;
    int n = blockIdx.x * 4 + wv;
    if (n >= N) return;
    int start = rowptr[n], end = rowptr[n + 1], deg = end - start;
    float4 ad = a_dst4[n];
    uint laneoff = lane * 2;
    float a00 = 0, a01 = 0, a10 = 0, a11 = 0, a20 = 0, a21 = 0, a30 = 0, a31 = 0;
    float i0, i1, i2, i3;

    auto gather = [&](int sv, int len) {
        const uint4* wb0 = (const uint4*)(&elds[wv][0][0]);
        const uint4* wb1 = (const uint4*)(&elds[wv][1][0]);
        const uint4* wb2 = (const uint4*)(&elds[wv][2][0]);
        const uint4* wb3 = (const uint4*)(&elds[wv][3][0]);
        for (int e = 0; e < len; e += 8) {
            int s0 = __builtin_amdgcn_readlane(sv, e);
            int s1 = __builtin_amdgcn_readlane(sv, e + 1);
            int s2 = __builtin_amdgcn_readlane(sv, e + 2);
            int s3 = __builtin_amdgcn_readlane(sv, e + 3);
            int s4 = __builtin_amdgcn_readlane(sv, e + 4);
            int s5 = __builtin_amdgcn_readlane(sv, e + 5);
            int s6 = __builtin_amdgcn_readlane(sv, e + 6);
            int s7 = __builtin_amdgcn_readlane(sv, e + 7);
            uint h0 = *(const uint*)(hsrc + (((uint)s0) << SH) + laneoff);
            uint h1 = *(const uint*)(hsrc + (((uint)s1) << SH) + laneoff);
            uint h2 = *(const uint*)(hsrc + (((uint)s2) << SH) + laneoff);
            uint h3 = *(const uint*)(hsrc + (((uint)s3) << SH) + laneoff);
            uint h4 = *(const uint*)(hsrc + (((uint)s4) << SH) + laneoff);
            uint h5 = *(const uint*)(hsrc + (((uint)s5) << SH) + laneoff);
            uint h6 = *(const uint*)(hsrc + (((uint)s6) << SH) + laneoff);
            uint h7 = *(const uint*)(hsrc + (((uint)s7) << SH) + laneoff);
            uint4 w0 = wb0[e >> 3], w1 = wb1[e >> 3], w2 = wb2[e >> 3], w3 = wb3[e >> 3];
            DOT2PAIR(h0, h1, w0.x, a00, a01); DOT2PAIR(h0, h1, w1.x, a10, a11);
            DOT2PAIR(h0, h1, w2.x, a20, a21); DOT2PAIR(h0, h1, w3.x, a30, a31);
            DOT2PAIR(h2, h3, w0.y, a00, a01); DOT2PAIR(h2, h3, w1.y, a10, a11);
            DOT2PAIR(h2, h3, w2.y, a20, a21); DOT2PAIR(h2, h3, w3.y, a30, a31);
            DOT2PAIR(h4, h5, w0.z, a00, a01); DOT2PAIR(h4, h5, w1.z, a10, a11);
            DOT2PAIR(h4, h5, w2.z, a20, a21); DOT2PAIR(h4, h5, w3.z, a30, a31);
            DOT2PAIR(h6, h7, w0.w, a00, a01); DOT2PAIR(h6, h7, w1.w, a10, a11);
            DOT2PAIR(h6, h7, w2.w, a20, a21); DOT2PAIR(h6, h7, w3.w, a30, a31);
        }
    };

    if (deg <= 64) {
        bool v = lane < deg;
        int sv = v ? ecol[start + lane] : 0;
        float4 as = a_src4[sv];
        float e0 = v ? __expf(fminf(leaky(as.x + ad.x), 60.f)) : 0.f;
        float e1 = v ? __expf(fminf(leaky(as.y + ad.y), 60.f)) : 0.f;
        float e2 = v ? __expf(fminf(leaky(as.z + ad.z), 60.f)) : 0.f;
        float e3 = v ? __expf(fminf(leaky(as.w + ad.w), 60.f)) : 0.f;
        ushort r0 = f2b(e0), r1 = f2b(e1), r2 = f2b(e2), r3 = f2b(e3);
        elds[wv][0][lane] = r0; elds[wv][1][lane] = r1;
        elds[wv][2][lane] = r2; elds[wv][3][lane] = r3;
        float s0 = b2f(r0), s1 = b2f(r1), s2 = b2f(r2), s3 = b2f(r3);
#pragma unroll
        for (int off = 1; off < 64; off <<= 1) {
            s0 += __shfl_xor(s0, off, 64); s1 += __shfl_xor(s1, off, 64);
            s2 += __shfl_xor(s2, off, 64); s3 += __shfl_xor(s3, off, 64);
        }
        i0 = 1.f / (s0 + 1e-16f); i1 = 1.f / (s1 + 1e-16f);
        i2 = 1.f / (s2 + 1e-16f); i3 = 1.f / (s3 + 1e-16f);
        gather(sv, deg);
    } else {
        float s0 = 0, s1 = 0, s2 = 0, s3 = 0;
        for (int cs = start; cs < end; cs += 64) {
            int j = cs + lane; bool v = j < end;
            int s = v ? ecol[j] : 0;
            float4 as = a_src4[s];
            if (v) {
                s0 += b2f(f2b(__expf(fminf(leaky(as.x + ad.x), 60.f))));
                s1 += b2f(f2b(__expf(fminf(leaky(as.y + ad.y), 60.f))));
                s2 += b2f(f2b(__expf(fminf(leaky(as.z + ad.z), 60.f))));
                s3 += b2f(f2b(__expf(fminf(leaky(as.w + ad.w), 60.f))));
            }
        }
#pragma unroll
        for (int off = 1; off < 64; off <<= 1) {
            s0 += __shfl_xor(s0, off, 64); s1 += __shfl_xor(s1, off, 64);
            s2 += __shfl_xor(s2, off, 64); s3 += __shfl_xor(s3, off, 64);
        }
        i0 = 1.f / (s0 + 1e-16f); i1 = 1.f / (s1 + 1e-16f);
        i2 = 1.f / (s2 + 1e-16f); i3 = 1.f / (s3 + 1e-16f);
        for (int cs = start; cs < end; cs += 64) {
            int j = cs + lane; bool v = j < end;
            int sv = v ? ecol[j] : 0;
            float4 as = a_src4[sv];
            float e0 = v ? __expf(fminf(leaky(as.x + ad.x), 60.f)) : 0.f;
            float e1 = v ? __expf(fminf(leaky(as.y + ad.y), 60.f)) : 0.f;
            float e2 = v ? __expf(fminf(leaky(as.z + ad.z), 60.f)) : 0.f;
            float e3 = v ? __expf(fminf(leaky(as.w + ad.w), 60.f)) : 0.f;
            elds[wv][0][lane] = f2b(e0); elds[wv][1][lane] = f2b(e1);
            elds[wv][2][lane] = f2b(e2); elds[wv][3][lane] = f2b(e3);
            gather(sv, min(64, end - cs));
        }
    }

    size_t base = (size_t)n * 256 + lane;
    z2u[base]       = (uint)f2b(a00 * i0) | ((uint)f2b(a01 * i0) << 16);
    z2u[base + 64]  = (uint)f2b(a10 * i1) | ((uint)f2b(a11 * i1) << 16);
    z2u[base + 128] = (uint)f2b(a20 * i2) | ((uint)f2b(a21 * i2) << 16);
    z2u[base + 192] = (uint)f2b(a30 * i3) | ((uint)f2b(a31 * i3) << 16);
}

// ---------------- gemm2: out = z2 @ W2sT + b2, K=512, f32 out [M][64] ----------------
__global__ __launch_bounds__(256) void gemm2_kernel(
    const ushort* __restrict__ A, const ushort* __restrict__ BT, const float* __restrict__ b2,
    float* __restrict__ outp, int M) {
    constexpr int K = 512, NT = 4;
    int lane = threadIdx.x & 63, wv = threadIdx.x >> 6;
    int row0 = (blockIdx.x * 4 + wv) * 16;
    if (row0 >= M) return;
    int m = lane & 15, quad = lane >> 4;
    int rowa = min(row0 + m, M - 1);
    const bf16x8* arow = (const bf16x8*)(A + (size_t)rowa * K);
    bf16x8 af[16];
#pragma unroll
    for (int kk = 0; kk < 16; ++kk) af[kk] = arow[4 * kk + quad];
    floatx4 acc[NT] = {};
#pragma unroll
    for (int nt = 0; nt < NT; ++nt) {
        const bf16x8* brow = (const bf16x8*)(BT + (size_t)(nt * 16 + m) * K);
#pragma unroll
        for (int kk = 0; kk < 16; ++kk)
            acc[nt] = __builtin_amdgcn_mfma_f32_16x16x32_bf16(af[kk], brow[4 * kk + quad], acc[nt], 0, 0, 0);
    }
#pragma unroll
    for (int nt = 0; nt < NT; ++nt) {
        float b = b2[nt * 16 + m];
#pragma unroll
        for (int r = 0; r < 4; ++r) {
            int row = row0 + quad * 4 + r;
            if (row < M) outp[(size_t)row * 64 + nt * 16 + m] = acc[nt][r] + b;
        }
    }
}

// ---------------- launch ----------------
extern "C" void kernel_launch(void* const* d_in, const int* in_sizes, int n_in,
                              void* d_out, int out_size, void* d_ws, size_t ws_size,
                              hipStream_t stream) {
    // setup_inputs order: x, edge_index, W1, att_src1, att_dst1, bias1, W2, att_src2, att_dst2, bias2
    const void* x_raw = d_in[0];
    const int*  ei    = (const int*)d_in[1];
    const void* W1_p  = d_in[2];
    const void* as1_p = d_in[3];
    const void* ad1_p = d_in[4];
    const void* b1_p  = d_in[5];
    const void* W2_p  = d_in[6];
    const void* as2_p = d_in[7];
    const void* ad2_p = d_in[8];
    const void* b2_p  = d_in[9];

    const int F_IN = 128;
    const int N = in_sizes[0] / F_IN;   // 50000
    const int E = in_sizes[1] / 2;      // 800000
    const int ET = E + N;
    const int NB = (N + 1023) / 1024;

    char* p = (char*)d_ws;
    auto alloc = [&](size_t bytes) { char* r = p; p += (bytes + 255) & ~(size_t)255; return r; };
    ushort* xbf   = (ushort*)alloc((size_t)N * 128 * 2);
    ushort* W1T   = (ushort*)alloc(128 * 128 * 2);
    ushort* W2sT  = (ushort*)alloc(64 * 512 * 2);
    float*  att1f = (float*)alloc(256 * 4);
    float*  w2t8  = (float*)alloc(8 * 128 * 4);
    float*  b1f   = (float*)alloc(128 * 4);
    float*  b2f   = (float*)alloc(64 * 4);
    ushort* h1    = (ushort*)alloc((size_t)N * 128 * 2);
    ushort* hL1   = (ushort*)alloc((size_t)N * 128 * 2);
    ushort* z2    = (ushort*)alloc((size_t)N * 512 * 2);
    float*  asrc1 = (float*)alloc((size_t)N * 4 * 4);
    float*  adst1 = (float*)alloc((size_t)N * 4 * 4);
    float*  asrc2 = (float*)alloc((size_t)N * 4 * 4);
    float*  adst2 = (float*)alloc((size_t)N * 4 * 4);
    int* deg    = (int*)alloc((size_t)2 * N * 4);
    int* cnt    = deg + N;
    int* tmp    = (int*)alloc((size_t)N * 4);
    int* bsum   = (int*)alloc(128 * 4);
    int* rowptr = (int*)alloc((size_t)(N + 1) * 4);
    int* ecol   = (int*)alloc((size_t)ET * 4);
    int* flagI  = (int*)alloc(256);
    int* flagF  = (int*)alloc(256);

    hipMemsetAsync(deg, 0, (size_t)N * 4, stream);  // cnt zeroed in scan3

    detect_kernel<<<1, 256, 0, stream>>>(ei, x_raw, flagI, flagF);

    int NX = N * F_IN;
    int nxb = (NX + 255) / 256;
    int eblocks = (ET + 255) / 256;
    // prep args: x, W1, as1, ad1, b1, b2  (d_in 0, 2, 3, 4, 5, 9)
    prep_kernel<<<nxb + 64 + 2 + eblocks, 256, 0, stream>>>(
        x_raw, W1_p, as1_p, ad1_p, b1_p, b2_p,
        xbf, W1T, att1f, b1f, b2f, ei, E, ET, deg, NX, flagF, flagI);
    // prep2 args: W2, as2, ad2  (d_in 6, 7, 8)
    prep2_kernel<<<4 + 128, 256, 0, stream>>>(W2_p, as2_p, ad2_p, w2t8, W2sT, flagF);

    scan1_kernel<<<NB, 1024, 0, stream>>>(deg, tmp, bsum, N);
    scan2_kernel<<<1, 64, 0, stream>>>(bsum, NB);
    scan3_kernel<<<(N + 256) / 256, 256, 0, stream>>>(tmp, bsum, rowptr, cnt, N, NB);
    scatter_kernel<<<eblocks, 256, 0, stream>>>(ei, E, N, flagI, rowptr, cnt, ecol);

    int nblocks4 = (N + 3) / 4;
    int gblocks = (N + 63) / 64;
    // ---- layer 1 (R6-proven path) ----
    gemm1_kernel<<<gblocks, 256, 0, stream>>>(
        xbf, W1T, h1, att1f, (float4*)asrc1, (float4*)adst1, N);
    agg1_kernel<<<nblocks4, 256, 0, stream>>>(
        h1, (const float4*)asrc1, (const float4*)adst1, rowptr, ecol, b1f, w2t8,
        (uint*)hL1, (float4*)asrc2, (float4*)adst2, N);
    // ---- layer 2 (per-head restructure) ----
    agg2_kernel<<<nblocks4, 256, 0, stream>>>(
        hL1, (const float4*)asrc2, (const float4*)adst2, rowptr, ecol, (uint*)z2, N);
    gemm2_kernel<<<gblocks, 256, 0, stream>>>(z2, W2sT, b2f, (float*)d_out, N);
}

// Round 9
// 327.864 us; speedup vs baseline: 2.3081x; 1.0427x over previous
//
#include <hip/hip_runtime.h>

typedef unsigned int uint;
typedef unsigned short ushort;

// N=50000 nodes, E=800000 edges, F_in=128, heads=4, C1=32 (concat->128), C2=64 (mean->64)
// R9: layer pipeline unchanged from R8 (passing). CSR build rebuilt for write locality:
// bucket (dst>>8) partition with LDS staging -> per-bucket deg + placement (one block per
// bucket => ecol lines assembled in a single XCD's L2; kills the 17x write amplification).

__device__ __forceinline__ float leaky(float x) { return x >= 0.f ? x : 0.2f * x; }
__device__ __forceinline__ float b2f(ushort h) { return __uint_as_float(((uint)h) << 16); }
__device__ __forceinline__ ushort f2b(float f) {
    uint u = __float_as_uint(f);
    return (ushort)((u + 0x7FFF + ((u >> 16) & 1)) >> 16);  // RNE
}

#if defined(__has_builtin)
#if __has_builtin(__builtin_amdgcn_fdot2_f32_bf16)
#define HAS_DOT2 1
#endif
#endif
#ifndef HAS_DOT2
#define HAS_DOT2 0
#endif

#if HAS_DOT2
typedef __bf16 bf16v2 __attribute__((ext_vector_type(2)));
__device__ __forceinline__ float dot2bf(uint h2, uint w2, float c) {
    return __builtin_amdgcn_fdot2_f32_bf16(__builtin_bit_cast(bf16v2, h2),
                                           __builtin_bit_cast(bf16v2, w2), c, false);
}
#define DOT2PAIR(hE, hE1, wpk, a0, a1)                                  \
    a0 = dot2bf(__builtin_amdgcn_perm(hE, hE1, 0x01000504), wpk, a0);   \
    a1 = dot2bf(__builtin_amdgcn_perm(hE, hE1, 0x03020706), wpk, a1);
#else
#define DOT2PAIR(hE, hE1, wpk, a0, a1)                                  \
    {                                                                   \
        float wlo = __uint_as_float((wpk) << 16);                       \
        float whi = __uint_as_float((wpk) & 0xffff0000u);               \
        a0 = fmaf(wlo, __uint_as_float((hE) << 16), a0);                \
        a1 = fmaf(wlo, __uint_as_float((hE) & 0xffff0000u), a1);        \
        a0 = fmaf(whi, __uint_as_float((hE1) << 16), a0);               \
        a1 = fmaf(whi, __uint_as_float((hE1) & 0xffff0000u), a1);       \
    }
#endif

// ---------------- dtype detection ----------------
__global__ void detect_kernel(const int* __restrict__ ei, const void* __restrict__ xin,
                              int* __restrict__ flagI, int* __restrict__ flagF) {
    __shared__ int s_sane, s_odd;
    int t = threadIdx.x;  // 256 threads
    if (t == 0) { s_sane = 0; s_odd = 0; }
    __syncthreads();
    if (t < 64 && ei[2 * t + 1] != 0) atomicOr(&s_odd, 1);
    ushort v = ((const ushort*)xin)[2 * t];
    int ex = (v >> 7) & 0xFF;
    if (v == 0 || (ex >= 100 && ex <= 135)) atomicAdd(&s_sane, 1);
    __syncthreads();
    if (t == 0) { *flagI = (s_odd == 0); *flagF = (s_sane >= 230); }
}

__device__ __forceinline__ float rdf(const void* p_, int i, int bf) {
    return bf ? b2f(((const ushort*)p_)[i]) : ((const float*)p_)[i];
}

// ---------------- prep: x->bf16 (only if f32 input), W1^T, att1/b1/b2 cvts ----------------
__global__ void prep_kernel(const void* __restrict__ x, const void* __restrict__ W1,
                            const void* __restrict__ as1, const void* __restrict__ ad1,
                            const void* __restrict__ b1, const void* __restrict__ b2,
                            ushort* __restrict__ xbf, ushort* __restrict__ W1T,
                            float* __restrict__ att1, float* __restrict__ b1f,
                            float* __restrict__ b2f_, int NX, const int* __restrict__ flagF) {
    int bf = *flagF;
    int b = blockIdx.x, t = threadIdx.x;
    int nxb = (NX + 255) / 256;
    if (b < nxb) {
        if (bf) return;  // bf16 input: gemm1 reads x_raw directly
        int i = b * 256 + t;
        if (i < NX) xbf[i] = f2b(((const float*)x)[i]);
        return;
    }
    b -= nxb;
    if (b < 64) {  // W1 [128 k][128 n] -> W1T [n][k]
        int i = b * 256 + t;
        int k = i >> 7, n = i & 127;
        W1T[n * 128 + k] = bf ? ((const ushort*)W1)[i] : f2b(((const float*)W1)[i]);
        return;
    }
    b -= 64;
    {  // smalls: 512 idx
        int i = b * 256 + t;
        if (i < 128)      att1[i] = rdf(as1, i, bf);
        else if (i < 256) att1[i] = rdf(ad1, i - 128, bf);
        else if (i < 384) b1f[i - 256] = rdf(b1, i - 256, bf);
        else if (i < 448) b2f_[i - 384] = rdf(b2, i - 384, bf);
    }
}

// ---------------- prep2: folded attention-2 vectors + stacked mean-folded W2 ----------------
__global__ void prep2_kernel(const void* __restrict__ W2, const void* __restrict__ as2,
                             const void* __restrict__ ad2, float* __restrict__ w2t8,
                             ushort* __restrict__ W2sT, const int* __restrict__ flagF) {
    int bf = *flagF;
    int b = blockIdx.x, t = threadIdx.x;
    if (b < 4) {
        int idx = b * 256 + t;  // 1024 = 8 o x 128 k
        int o = idx >> 7, k = idx & 127, h = o & 3;
        const void* att = (o < 4) ? as2 : ad2;
        float s = 0.f;
        for (int c = 0; c < 64; ++c) s += rdf(W2, k * 256 + h * 64 + c, bf) * rdf(att, h * 64 + c, bf);
        w2t8[o * 128 + k] = s;
        return;
    }
    b -= 4;
    {  // 128 blocks: 32768 = 64 c x 512 hk
        int idx = b * 256 + t;
        int c = idx >> 9, hk = idx & 511;
        int h = hk >> 7, k = hk & 127;
        W2sT[c * 512 + hk] = f2b(0.25f * rdf(W2, k * 256 + h * 64 + c, bf));
    }
}

// ================= CSR build v2 (N <= 65536): bucketed, locality-aware =================
__device__ __forceinline__ int edge_dst(const int* __restrict__ ei, int E, int e, int is64) {
    return (e >= E) ? (e - E) : (is64 ? ei[2 * E + 2 * e] : ei[E + e]);
}

// bucket histogram (bucket = dst>>8), LDS-aggregated
__global__ __launch_bounds__(256) void bhist_kernel(const int* __restrict__ ei, int E, int ET,
                                                    const int* __restrict__ flagI,
                                                    int* __restrict__ bcnt) {
    __shared__ int bins[256];
    int t = threadIdx.x;
    bins[t] = 0;
    __syncthreads();
    int is64 = *flagI;
    int base = blockIdx.x * 4096;
    for (int i = 0; i < 16; ++i) {
        int e = base + i * 256 + t;
        if (e < ET) atomicAdd(&bins[edge_dst(ei, E, e, is64) >> 8], 1);
    }
    __syncthreads();
    if (bins[t]) atomicAdd(&bcnt[t], bins[t]);
}

// scan bucket counts -> bbase (exclusive) and gcur (running cursors)
__global__ __launch_bounds__(256) void bscan_kernel(const int* __restrict__ bcnt,
                                                    int* __restrict__ bbase,
                                                    int* __restrict__ gcur, int NBUK) {
    __shared__ int sc[256];
    int t = threadIdx.x;
    int v = (t < NBUK) ? bcnt[t] : 0;
    sc[t] = v;
    __syncthreads();
    for (int off = 1; off < 256; off <<= 1) {
        int a = (t >= off) ? sc[t - off] : 0;
        __syncthreads();
        sc[t] += a;
        __syncthreads();
    }
    int excl = sc[t] - v;
    if (t < NBUK) { bbase[t] = excl; gcur[t] = excl; }
    if (t == 255) bbase[NBUK] = sc[255];
}

// LDS-staged partition: 8192 edges/block -> bucket-contiguous runs flushed to ebuf
__global__ __launch_bounds__(256) void part_kernel(const int* __restrict__ ei, int E, int ET,
                                                   const int* __restrict__ flagI,
                                                   int* __restrict__ gcur,
                                                   uint* __restrict__ ebuf, int NBUK) {
    __shared__ uint stage[8192];
    __shared__ int cnt_s[256], sc[256], lbase[257], cur[256], gb[256];
    int t = threadIdx.x;
    int base = blockIdx.x * 8192;
    cnt_s[t] = 0;
    __syncthreads();
    int is64 = *flagI;
    uint pk[32];
    short bk[32];
#pragma unroll
    for (int i = 0; i < 32; ++i) {
        int e = base + i * 256 + t;
        if (e < ET) {
            int src, dst;
            if (e >= E) { src = dst = e - E; }
            else if (is64) { src = ei[2 * e]; dst = ei[2 * E + 2 * e]; }
            else           { src = ei[e];     dst = ei[E + e]; }
            pk[i] = (uint)src | ((uint)dst << 16);
            bk[i] = (short)(dst >> 8);
            atomicAdd(&cnt_s[bk[i]], 1);
        } else bk[i] = -1;
    }
    __syncthreads();
    int v = cnt_s[t];
    sc[t] = v;
    __syncthreads();
    for (int off = 1; off < 256; off <<= 1) {
        int a = (t >= off) ? sc[t - off] : 0;
        __syncthreads();
        sc[t] += a;
        __syncthreads();
    }
    lbase[t + 1] = sc[t];
    cur[t] = sc[t] - v;  // exclusive
    if (t == 0) lbase[0] = 0;
    __syncthreads();
#pragma unroll
    for (int i = 0; i < 32; ++i)
        if (bk[i] >= 0) {
            int slot = atomicAdd(&cur[bk[i]], 1);
            stage[slot] = pk[i];
        }
    __syncthreads();
    if (t < NBUK) {
        int c = lbase[t + 1] - lbase[t];
        if (c > 0) gb[t] = atomicAdd(&gcur[t], c);
    }
    __syncthreads();
    int total = lbase[256];
    for (int i = t; i < total; i += 256) {
        int lo = 0, hi = 255;  // largest b with lbase[b] <= i
        while (lo < hi) { int mid = (lo + hi + 1) >> 1; if (lbase[mid] <= i) lo = mid; else hi = mid - 1; }
        ebuf[gb[lo] + (i - lbase[lo])] = stage[i];
    }
}

// per-bucket degree: contiguous deg stores (no global atomics, no memset needed)
__global__ __launch_bounds__(256) void bdeg_kernel(const uint* __restrict__ ebuf,
                                                   const int* __restrict__ bbase,
                                                   int* __restrict__ deg, int N) {
    __shared__ int hist[256];
    int b = blockIdx.x, t = threadIdx.x;
    hist[t] = 0;
    __syncthreads();
    int d0 = b << 8;
    int s = bbase[b], e2 = bbase[b + 1];
    for (int i = s + t; i < e2; i += 256) atomicAdd(&hist[(ebuf[i] >> 16) - d0], 1);
    __syncthreads();
    int d = d0 + t;
    if (d < N) deg[d] = hist[t];
}

// per-bucket placement: ecol writes confined to one block's L2
__global__ __launch_bounds__(256) void bplace_kernel(const uint* __restrict__ ebuf,
                                                     const int* __restrict__ bbase,
                                                     const int* __restrict__ rowptr,
                                                     int* __restrict__ ecol, int N) {
    __shared__ int cur[256];
    int b = blockIdx.x, t = threadIdx.x;
    int d0 = b << 8, d = d0 + t;
    cur[t] = (d < N) ? rowptr[d] : 0;
    __syncthreads();
    int s = bbase[b], e2 = bbase[b + 1];
    for (int i = s + t; i < e2; i += 256) {
        uint pk = ebuf[i];
        int pos = atomicAdd(&cur[(pk >> 16) - d0], 1);
        ecol[pos] = (int)(pk & 0xffffu);
    }
}

// ---- fallback CSR (N > 65536): old hist + scatter ----
__global__ void hist_kernel(const int* __restrict__ ei, int E, int N,
                            const int* __restrict__ flag, int* __restrict__ deg) {
    int e = blockIdx.x * blockDim.x + threadIdx.x;
    if (e >= E + N) return;
    atomicAdd(&deg[edge_dst(ei, E, e, *flag)], 1);
}
__global__ void scatter_kernel(const int* __restrict__ ei, int E, int N,
                               const int* __restrict__ flag, const int* __restrict__ rowptr,
                               int* __restrict__ cnt, int* __restrict__ ecol) {
    int e = blockIdx.x * blockDim.x + threadIdx.x;
    if (e >= E + N) return;
    int src, dst;
    if (e >= E) { src = dst = e - E; }
    else if (*flag) { src = ei[2 * e]; dst = ei[2 * E + 2 * e]; }
    else            { src = ei[e];     dst = ei[E + e]; }
    int pos = rowptr[dst] + atomicAdd(&cnt[dst], 1);
    ecol[pos] = src;
}

// ---------------- node-degree scans (deg -> rowptr) ----------------
__global__ __launch_bounds__(1024) void scan1_kernel(const int* __restrict__ deg,
                                                     int* __restrict__ tmp,
                                                     int* __restrict__ bsum, int n) {
    __shared__ int ws[16];
    int tid = threadIdx.x, lane = tid & 63, wid = tid >> 6;
    int i = blockIdx.x * 1024 + tid;
    int v = (i < n) ? deg[i] : 0;
    int incl = v;
#pragma unroll
    for (int off = 1; off < 64; off <<= 1) {
        int t2 = __shfl_up(incl, off, 64);
        if (lane >= off) incl += t2;
    }
    if (lane == 63) ws[wid] = incl;
    __syncthreads();
    if (tid < 16) {
        int wv_ = ws[tid], winc = wv_;
#pragma unroll
        for (int off = 1; off < 16; off <<= 1) {
            int t2 = __shfl_up(winc, off, 16);
            if (tid >= off) winc += t2;
        }
        ws[tid] = winc - wv_;
    }
    __syncthreads();
    int excl = incl - v + ws[wid];
    if (i < n) tmp[i] = excl;
    if (tid == 1023) bsum[blockIdx.x] = excl + v;
}

__global__ void scan2_kernel(int* __restrict__ bsum, int nb) {
    int lane = threadIdx.x;
    int v = (lane < nb) ? bsum[lane] : 0;
    int incl = v;
    for (int off = 1; off < 64; off <<= 1) {
        int t = __shfl_up(incl, off, 64);
        if (lane >= off) incl += t;
    }
    int total = __shfl(incl, nb - 1, 64);
    if (lane < nb) bsum[lane] = incl - v;
    if (lane == 0) bsum[nb] = total;
}

__global__ void scan3_kernel(const int* __restrict__ tmp, const int* __restrict__ bsum,
                             int* __restrict__ rowptr, int* __restrict__ cnt, int n, int nb) {
    int i = blockIdx.x * blockDim.x + threadIdx.x;
    if (i > n) return;
    rowptr[i] = (i == n) ? bsum[nb] : tmp[i] + bsum[i >> 10];
    if (i < n) cnt[i] = 0;
}

// ---------------- gemm1: h1 = x@W1 (bf16) + fused attdot1 ----------------
typedef __attribute__((ext_vector_type(8))) short bf16x8;
typedef __attribute__((ext_vector_type(4))) float floatx4;

__global__ __launch_bounds__(256) void gemm1_kernel(
    const void* __restrict__ xraw, const ushort* __restrict__ xbf, const int* __restrict__ flagF,
    const ushort* __restrict__ BT, ushort* __restrict__ C,
    const float* __restrict__ att, float4* __restrict__ asrc4, float4* __restrict__ adst4, int M) {
    constexpr int K = 128, NT = 8;
    const ushort* A = (*flagF) ? (const ushort*)xraw : xbf;
    int lane = threadIdx.x & 63, wv = threadIdx.x >> 6;
    int row0 = (blockIdx.x * 4 + wv) * 16;
    if (row0 >= M) return;
    int m = lane & 15, quad = lane >> 4;
    int rowa = min(row0 + m, M - 1);
    const bf16x8* arow = (const bf16x8*)(A + (size_t)rowa * K);
    bf16x8 af[4];
#pragma unroll
    for (int kk = 0; kk < 4; ++kk) af[kk] = arow[4 * kk + quad];
    floatx4 acc[NT] = {};
#pragma unroll
    for (int nt = 0; nt < NT; ++nt) {
        const bf16x8* brow = (const bf16x8*)(BT + (size_t)(nt * 16 + m) * K);
#pragma unroll
        for (int kk = 0; kk < 4; ++kk)
            acc[nt] = __builtin_amdgcn_mfma_f32_16x16x32_bf16(af[kk], brow[4 * kk + quad], acc[nt], 0, 0, 0);
    }
    // C/D layout: col = lane&15, row = quad*4 + reg
#pragma unroll
    for (int nt = 0; nt < NT; ++nt)
#pragma unroll
        for (int r = 0; r < 4; ++r) {
            int row = row0 + quad * 4 + r;
            if (row < M) C[(size_t)row * 128 + nt * 16 + m] = f2b(acc[nt][r]);
        }
    float attS[NT], attD[NT];
#pragma unroll
    for (int nt = 0; nt < NT; ++nt) { attS[nt] = att[nt * 16 + m]; attD[nt] = att[128 + nt * 16 + m]; }
#pragma unroll
    for (int r = 0; r < 4; ++r) {
        float ps[4] = {0, 0, 0, 0}, pd[4] = {0, 0, 0, 0};
#pragma unroll
        for (int nt = 0; nt < NT; ++nt) {
            int h = nt / 2;  // layer-1 head = col/32
            ps[h] = fmaf(acc[nt][r], attS[nt], ps[h]);
            pd[h] = fmaf(acc[nt][r], attD[nt], pd[h]);
        }
#pragma unroll
        for (int off = 1; off < 16; off <<= 1) {
#pragma unroll
            for (int h = 0; h < 4; ++h) {
                ps[h] += __shfl_xor(ps[h], off, 64);
                pd[h] += __shfl_xor(pd[h], off, 64);
            }
        }
        int row = row0 + quad * 4 + r;
        if (m == 0 && row < M) {
            asrc4[row] = make_float4(ps[0], ps[1], ps[2], ps[3]);
            adst4[row] = make_float4(pd[0], pd[1], pd[2], pd[3]);
        }
    }
}

// ---------------- agg1: aggregate h1 -> hL1 (bias+ELU) + fused attdot2 ----------------
__global__ __launch_bounds__(256) void agg1_kernel(
    const ushort* __restrict__ hsrc, const float4* __restrict__ a_src4,
    const float4* __restrict__ a_dst4, const int* __restrict__ rowptr,
    const int* __restrict__ ecol, const float* __restrict__ bias,
    const float* __restrict__ w2t8, uint* __restrict__ outz,
    float4* __restrict__ asrc2, float4* __restrict__ adst2, int N) {
    constexpr int SH = 7;
    __shared__ __align__(16) ushort elds[4][4][72];
    int lane = threadIdx.x & 63, wv = threadIdx.x >> 6;
    int n = blockIdx.x * 4 + wv;
    if (n >= N) return;
    int start = rowptr[n], end = rowptr[n + 1], deg = end - start;
    float4 ad = a_dst4[n];
    int hh = lane >> 4;
    uint laneoff = lane * 2;
    float acc0 = 0.f, acc1 = 0.f;
    float i0, i1, i2, i3;

    auto gather = [&](int sv, int len) {
        const uint4* wb = (const uint4*)(&elds[wv][hh][0]);
        for (int e = 0; e < len; e += 8) {
            int s0 = __builtin_amdgcn_readlane(sv, e);
            int s1 = __builtin_amdgcn_readlane(sv, e + 1);
            int s2 = __builtin_amdgcn_readlane(sv, e + 2);
            int s3 = __builtin_amdgcn_readlane(sv, e + 3);
            int s4 = __builtin_amdgcn_readlane(sv, e + 4);
            int s5 = __builtin_amdgcn_readlane(sv, e + 5);
            int s6 = __builtin_amdgcn_readlane(sv, e + 6);
            int s7 = __builtin_amdgcn_readlane(sv, e + 7);
            uint4 w = wb[e >> 3];
            uint h0 = *(const uint*)(hsrc + (((uint)s0) << SH) + laneoff);
            uint h1 = *(const uint*)(hsrc + (((uint)s1) << SH) + laneoff);
            uint h2 = *(const uint*)(hsrc + (((uint)s2) << SH) + laneoff);
            uint h3 = *(const uint*)(hsrc + (((uint)s3) << SH) + laneoff);
            uint h4 = *(const uint*)(hsrc + (((uint)s4) << SH) + laneoff);
            uint h5 = *(const uint*)(hsrc + (((uint)s5) << SH) + laneoff);
            uint h6 = *(const uint*)(hsrc + (((uint)s6) << SH) + laneoff);
            uint h7 = *(const uint*)(hsrc + (((uint)s7) << SH) + laneoff);
            DOT2PAIR(h0, h1, w.x, acc0, acc1);
            DOT2PAIR(h2, h3, w.y, acc0, acc1);
            DOT2PAIR(h4, h5, w.z, acc0, acc1);
            DOT2PAIR(h6, h7, w.w, acc0, acc1);
        }
    };

    if (deg <= 64) {
        bool v = lane < deg;
        int sv = v ? ecol[start + lane] : 0;
        float4 as = a_src4[sv];
        float e0 = v ? __expf(fminf(leaky(as.x + ad.x), 60.f)) : 0.f;
        float e1 = v ? __expf(fminf(leaky(as.y + ad.y), 60.f)) : 0.f;
        float e2 = v ? __expf(fminf(leaky(as.z + ad.z), 60.f)) : 0.f;
        float e3 = v ? __expf(fminf(leaky(as.w + ad.w), 60.f)) : 0.f;
        ushort r0 = f2b(e0), r1 = f2b(e1), r2 = f2b(e2), r3 = f2b(e3);
        elds[wv][0][lane] = r0; elds[wv][1][lane] = r1;
        elds[wv][2][lane] = r2; elds[wv][3][lane] = r3;
        float s0 = b2f(r0), s1 = b2f(r1), s2 = b2f(r2), s3 = b2f(r3);
#pragma unroll
        for (int off = 1; off < 64; off <<= 1) {
            s0 += __shfl_xor(s0, off, 64); s1 += __shfl_xor(s1, off, 64);
            s2 += __shfl_xor(s2, off, 64); s3 += __shfl_xor(s3, off, 64);
        }
        i0 = 1.f / (s0 + 1e-16f); i1 = 1.f / (s1 + 1e-16f);
        i2 = 1.f / (s2 + 1e-16f); i3 = 1.f / (s3 + 1e-16f);
        gather(sv, deg);
    } else {
        float s0 = 0, s1 = 0, s2 = 0, s3 = 0;
        for (int cs = start; cs < end; cs += 64) {
            int j = cs + lane; bool v = j < end;
            int s = v ? ecol[j] : 0;
            float4 as = a_src4[s];
            if (v) {
                s0 += b2f(f2b(__expf(fminf(leaky(as.x + ad.x), 60.f))));
                s1 += b2f(f2b(__expf(fminf(leaky(as.y + ad.y), 60.f))));
                s2 += b2f(f2b(__expf(fminf(leaky(as.z + ad.z), 60.f))));
                s3 += b2f(f2b(__expf(fminf(leaky(as.w + ad.w), 60.f))));
            }
        }
#pragma unroll
        for (int off = 1; off < 64; off <<= 1) {
            s0 += __shfl_xor(s0, off, 64); s1 += __shfl_xor(s1, off, 64);
            s2 += __shfl_xor(s2, off, 64); s3 += __shfl_xor(s3, off, 64);
        }
        i0 = 1.f / (s0 + 1e-16f); i1 = 1.f / (s1 + 1e-16f);
        i2 = 1.f / (s2 + 1e-16f); i3 = 1.f / (s3 + 1e-16f);
        for (int cs = start; cs < end; cs += 64) {
            int j = cs + lane; bool v = j < end;
            int sv = v ? ecol[j] : 0;
            float4 as = a_src4[sv];
            float e0 = v ? __expf(fminf(leaky(as.x + ad.x), 60.f)) : 0.f;
            float e1 = v ? __expf(fminf(leaky(as.y + ad.y), 60.f)) : 0.f;
            float e2 = v ? __expf(fminf(leaky(as.z + ad.z), 60.f)) : 0.f;
            float e3 = v ? __expf(fminf(leaky(as.w + ad.w), 60.f)) : 0.f;
            elds[wv][0][lane] = f2b(e0); elds[wv][1][lane] = f2b(e1);
            elds[wv][2][lane] = f2b(e2); elds[wv][3][lane] = f2b(e3);
            gather(sv, min(64, end - cs));
        }
    }

    float ih = (lane < 32) ? (lane < 16 ? i0 : i1) : (lane < 48 ? i2 : i3);
    float o0 = acc0 * ih + bias[2 * lane + 0];
    float o1 = acc1 * ih + bias[2 * lane + 1];
    o0 = o0 > 0.f ? o0 : __expf(o0) - 1.f;  // ELU
    o1 = o1 > 0.f ? o1 : __expf(o1) - 1.f;
    outz[(size_t)n * 64 + lane] = (uint)f2b(o0) | ((uint)f2b(o1) << 16);

    // fused attdot2: a2[o] = hL1[n] . w2t8[o]
    float po[8];
#pragma unroll
    for (int o = 0; o < 8; ++o) {
        float2 w = ((const float2*)(w2t8 + o * 128))[lane];
        po[o] = fmaf(o0, w.x, o1 * w.y);
    }
#pragma unroll
    for (int off = 1; off < 64; off <<= 1)
#pragma unroll
        for (int o = 0; o < 8; ++o) po[o] += __shfl_xor(po[o], off, 64);
    if (lane == 0) {
        asrc2[n] = make_float4(po[0], po[1], po[2], po[3]);
        adst2[n] = make_float4(po[4], po[5], po[6], po[7]);
    }
}

// ---------------- agg2: per-head aggregate of hL1 -> z2 [N][4][128] bf16 ----------------
__global__ __launch_bounds__(256) void agg2_kernel(
    const ushort* __restrict__ hsrc, const float4* __restrict__ a_src4,
    const float4* __restrict__ a_dst4, const int* __restrict__ rowptr,
    const int* __restrict__ ecol, uint* __restrict__ z2u, int N) {
    constexpr int SH = 7;
    __shared__ __align__(16) ushort elds[4][4][72];
    int lane = threadIdx.x & 63, wv = threadIdx.x >> 6;
    int n = blockIdx.x * 4 + wv;
    if (n >= N) return;
    int start = rowptr[n], end = rowptr[n + 1], deg = end - start;
    float4 ad = a_dst4[n];
    uint laneoff = lane * 2;
    float a00 = 0, a01 = 0, a10 = 0, a11 = 0, a20 = 0, a21 = 0, a30 = 0, a31 = 0;
    float i0, i1, i2, i3;

    auto gather = [&](int sv, int len) {
        const uint4* wb0 = (const uint4*)(&elds[wv][0][0]);
        const uint4* wb1 = (const uint4*)(&elds[wv][1][0]);
        const uint4* wb2 = (const uint4*)(&elds[wv][2][0]);
        const uint4* wb3 = (const uint4*)(&elds[wv][3][0]);
        for (int e = 0; e < len; e += 8) {
            int s0 = __builtin_amdgcn_readlane(sv, e);
            int s1 = __builtin_amdgcn_readlane(sv, e + 1);
            int s2 = __builtin_amdgcn_readlane(sv, e + 2);
            int s3 = __builtin_amdgcn_readlane(sv, e + 3);
            int s4 = __builtin_amdgcn_readlane(sv, e + 4);
            int s5 = __builtin_amdgcn_readlane(sv, e + 5);
            int s6 = __builtin_amdgcn_readlane(sv, e + 6);
            int s7 = __builtin_amdgcn_readlane(sv, e + 7);
            uint h0 = *(const uint*)(hsrc + (((uint)s0) << SH) + laneoff);
            uint h1 = *(const uint*)(hsrc + (((uint)s1) << SH) + laneoff);
            uint h2 = *(const uint*)(hsrc + (((uint)s2) << SH) + laneoff);
            uint h3 = *(const uint*)(hsrc + (((uint)s3) << SH) + laneoff);
            uint h4 = *(const uint*)(hsrc + (((uint)s4) << SH) + laneoff);
            uint h5 = *(const uint*)(hsrc + (((uint)s5) << SH) + laneoff);
            uint h6 = *(const uint*)(hsrc + (((uint)s6) << SH) + laneoff);
            uint h7 = *(const uint*)(hsrc + (((uint)s7) << SH) + laneoff);
            uint4 w0 = wb0[e >> 3], w1 = wb1[e >> 3], w2 = wb2[e >> 3], w3 = wb3[e >> 3];
            DOT2PAIR(h0, h1, w0.x, a00, a01); DOT2PAIR(h0, h1, w1.x, a10, a11);
            DOT2PAIR(h0, h1, w2.x, a20, a21); DOT2PAIR(h0, h1, w3.x, a30, a31);
            DOT2PAIR(h2, h3, w0.y, a00, a01); DOT2PAIR(h2, h3, w1.y, a10, a11);
            DOT2PAIR(h2, h3, w2.y, a20, a21); DOT2PAIR(h2, h3, w3.y, a30, a31);
            DOT2PAIR(h4, h5, w0.z, a00, a01); DOT2PAIR(h4, h5, w1.z, a10, a11);
            DOT2PAIR(h4, h5, w2.z, a20, a21); DOT2PAIR(h4, h5, w3.z, a30, a31);
            DOT2PAIR(h6, h7, w0.w, a00, a01); DOT2PAIR(h6, h7, w1.w, a10, a11);
            DOT2PAIR(h6, h7, w2.w, a20, a21); DOT2PAIR(h6, h7, w3.w, a30, a31);
        }
    };

    if (deg <= 64) {
        bool v = lane < deg;
        int sv = v ? ecol[start + lane] : 0;
        float4 as = a_src4[sv];
        float e0 = v ? __expf(fminf(leaky(as.x + ad.x), 60.f)) : 0.f;
        float e1 = v ? __expf(fminf(leaky(as.y + ad.y), 60.f)) : 0.f;
        float e2 = v ? __expf(fminf(leaky(as.z + ad.z), 60.f)) : 0.f;
        float e3 = v ? __expf(fminf(leaky(as.w + ad.w), 60.f)) : 0.f;
        ushort r0 = f2b(e0), r1 = f2b(e1), r2 = f2b(e2), r3 = f2b(e3);
        elds[wv][0][lane] = r0; elds[wv][1][lane] = r1;
        elds[wv][2][lane] = r2; elds[wv][3][lane] = r3;
        float s0 = b2f(r0), s1 = b2f(r1), s2 = b2f(r2), s3 = b2f(r3);
#pragma unroll
        for (int off = 1; off < 64; off <<= 1) {
            s0 += __shfl_xor(s0, off, 64); s1 += __shfl_xor(s1, off, 64);
            s2 += __shfl_xor(s2, off, 64); s3 += __shfl_xor(s3, off, 64);
        }
        i0 = 1.f / (s0 + 1e-16f); i1 = 1.f / (s1 + 1e-16f);
        i2 = 1.f / (s2 + 1e-16f); i3 = 1.f / (s3 + 1e-16f);
        gather(sv, deg);
    } else {
        float s0 = 0, s1 = 0, s2 = 0, s3 = 0;
        for (int cs = start; cs < end; cs += 64) {
            int j = cs + lane; bool v = j < end;
            int s = v ? ecol[j] : 0;
            float4 as = a_src4[s];
            if (v) {
                s0 += b2f(f2b(__expf(fminf(leaky(as.x + ad.x), 60.f))));
                s1 += b2f(f2b(__expf(fminf(leaky(as.y + ad.y), 60.f))));
                s2 += b2f(f2b(__expf(fminf(leaky(as.z + ad.z), 60.f))));
                s3 += b2f(f2b(__expf(fminf(leaky(as.w + ad.w), 60.f))));
            }
        }
#pragma unroll
        for (int off = 1; off < 64; off <<= 1) {
            s0 += __shfl_xor(s0, off, 64); s1 += __shfl_xor(s1, off, 64);
            s2 += __shfl_xor(s2, off, 64); s3 += __shfl_xor(s3, off, 64);
        }
        i0 = 1.f / (s0 + 1e-16f); i1 = 1.f / (s1 + 1e-16f);
        i2 = 1.f / (s2 + 1e-16f); i3 = 1.f / (s3 + 1e-16f);
        for (int cs = start; cs < end; cs += 64) {
            int j = cs + lane; bool v = j < end;
            int sv = v ? ecol[j] : 0;
            float4 as = a_src4[sv];
            float e0 = v ? __expf(fminf(leaky(as.x + ad.x), 60.f)) : 0.f;
            float e1 = v ? __expf(fminf(leaky(as.y + ad.y), 60.f)) : 0.f;
            float e2 = v ? __expf(fminf(leaky(as.z + ad.z), 60.f)) : 0.f;
            float e3 = v ? __expf(fminf(leaky(as.w + ad.w), 60.f)) : 0.f;
            elds[wv][0][lane] = f2b(e0); elds[wv][1][lane] = f2b(e1);
            elds[wv][2][lane] = f2b(e2); elds[wv][3][lane] = f2b(e3);
            gather(sv, min(64, end - cs));
        }
    }

    size_t base = (size_t)n * 256 + lane;
    z2u[base]       = (uint)f2b(a00 * i0) | ((uint)f2b(a01 * i0) << 16);
    z2u[base + 64]  = (uint)f2b(a10 * i1) | ((uint)f2b(a11 * i1) << 16);
    z2u[base + 128] = (uint)f2b(a20 * i2) | ((uint)f2b(a21 * i2) << 16);
    z2u[base + 192] = (uint)f2b(a30 * i3) | ((uint)f2b(a31 * i3) << 16);
}

// ---------------- gemm2: out = z2 @ W2sT + b2, K=512, f32 out [M][64] ----------------
__global__ __launch_bounds__(256) void gemm2_kernel(
    const ushort* __restrict__ A, const ushort* __restrict__ BT, const float* __restrict__ b2,
    float* __restrict__ outp, int M) {
    constexpr int K = 512, NT = 4;
    int lane = threadIdx.x & 63, wv = threadIdx.x >> 6;
    int row0 = (blockIdx.x * 4 + wv) * 16;
    if (row0 >= M) return;
    int m = lane & 15, quad = lane >> 4;
    int rowa = min(row0 + m, M - 1);
    const bf16x8* arow = (const bf16x8*)(A + (size_t)rowa * K);
    bf16x8 af[16];
#pragma unroll
    for (int kk = 0; kk < 16; ++kk) af[kk] = arow[4 * kk + quad];
    floatx4 acc[NT] = {};
#pragma unroll
    for (int nt = 0; nt < NT; ++nt) {
        const bf16x8* brow = (const bf16x8*)(BT + (size_t)(nt * 16 + m) * K);
#pragma unroll
        for (int kk = 0; kk < 16; ++kk)
            acc[nt] = __builtin_amdgcn_mfma_f32_16x16x32_bf16(af[kk], brow[4 * kk + quad], acc[nt], 0, 0, 0);
    }
#pragma unroll
    for (int nt = 0; nt < NT; ++nt) {
        float b = b2[nt * 16 + m];
#pragma unroll
        for (int r = 0; r < 4; ++r) {
            int row = row0 + quad * 4 + r;
            if (row < M) outp[(size_t)row * 64 + nt * 16 + m] = acc[nt][r] + b;
        }
    }
}

// ---------------- launch ----------------
extern "C" void kernel_launch(void* const* d_in, const int* in_sizes, int n_in,
                              void* d_out, int out_size, void* d_ws, size_t ws_size,
                              hipStream_t stream) {
    // setup_inputs order: x, edge_index, W1, att_src1, att_dst1, bias1, W2, att_src2, att_dst2, bias2
    const void* x_raw = d_in[0];
    const int*  ei    = (const int*)d_in[1];
    const void* W1_p  = d_in[2];
    const void* as1_p = d_in[3];
    const void* ad1_p = d_in[4];
    const void* b1_p  = d_in[5];
    const void* W2_p  = d_in[6];
    const void* as2_p = d_in[7];
    const void* ad2_p = d_in[8];
    const void* b2_p  = d_in[9];

    const int F_IN = 128;
    const int N = in_sizes[0] / F_IN;   // 50000
    const int E = in_sizes[1] / 2;      // 800000
    const int ET = E + N;
    const int NB = (N + 1023) / 1024;
    const int NBUK = (N + 255) >> 8;    // buckets (dst>>8); packed path needs N<=65536

    char* p = (char*)d_ws;
    auto alloc = [&](size_t bytes) { char* r = p; p += (bytes + 255) & ~(size_t)255; return r; };
    ushort* xbf   = (ushort*)alloc((size_t)N * 128 * 2);
    ushort* W1T   = (ushort*)alloc(128 * 128 * 2);
    ushort* W2sT  = (ushort*)alloc(64 * 512 * 2);
    float*  att1f = (float*)alloc(256 * 4);
    float*  w2t8  = (float*)alloc(8 * 128 * 4);
    float*  b1f   = (float*)alloc(128 * 4);
    float*  b2f   = (float*)alloc(64 * 4);
    ushort* h1    = (ushort*)alloc((size_t)N * 128 * 2);
    ushort* hL1   = (ushort*)alloc((size_t)N * 128 * 2);
    ushort* z2    = (ushort*)alloc((size_t)N * 512 * 2);
    float*  asrc1 = (float*)alloc((size_t)N * 4 * 4);
    float*  adst1 = (float*)alloc((size_t)N * 4 * 4);
    float*  asrc2 = (float*)alloc((size_t)N * 4 * 4);
    float*  adst2 = (float*)alloc((size_t)N * 4 * 4);
    int* deg    = (int*)alloc((size_t)N * 4);
    int* cnt    = (int*)alloc((size_t)N * 4);   // fallback only
    int* tmp    = (int*)alloc((size_t)N * 4);
    int* bsum   = (int*)alloc(128 * 4);
    int* rowptr = (int*)alloc((size_t)(N + 1) * 4);
    int* ecol   = (int*)alloc((size_t)ET * 4);
    uint* ebuf  = (uint*)alloc((size_t)ET * 4);
    int* bcnt   = (int*)alloc(256 * 4);
    int* bbase  = (int*)alloc(257 * 4);
    int* gcur   = (int*)alloc(256 * 4);
    int* flagI  = (int*)alloc(256);
    int* flagF  = (int*)alloc(256);

    detect_kernel<<<1, 256, 0, stream>>>(ei, x_raw, flagI, flagF);

    int NX = N * F_IN;
    int nxb = (NX + 255) / 256;
    // prep args: x, W1, as1, ad1, b1, b2  (d_in 0, 2, 3, 4, 5, 9)
    prep_kernel<<<nxb + 64 + 2, 256, 0, stream>>>(
        x_raw, W1_p, as1_p, ad1_p, b1_p, b2_p, xbf, W1T, att1f, b1f, b2f, NX, flagF);
    // prep2 args: W2, as2, ad2  (d_in 6, 7, 8)
    prep2_kernel<<<4 + 128, 256, 0, stream>>>(W2_p, as2_p, ad2_p, w2t8, W2sT, flagF);

    if (N <= 65536) {  // bucketed locality-aware CSR build
        hipMemsetAsync(bcnt, 0, 256 * 4, stream);
        bhist_kernel<<<(ET + 4095) / 4096, 256, 0, stream>>>(ei, E, ET, flagI, bcnt);
        bscan_kernel<<<1, 256, 0, stream>>>(bcnt, bbase, gcur, NBUK);
        part_kernel<<<(ET + 8191) / 8192, 256, 0, stream>>>(ei, E, ET, flagI, gcur, ebuf, NBUK);
        bdeg_kernel<<<NBUK, 256, 0, stream>>>(ebuf, bbase, deg, N);
        scan1_kernel<<<NB, 1024, 0, stream>>>(deg, tmp, bsum, N);
        scan2_kernel<<<1, 64, 0, stream>>>(bsum, NB);
        scan3_kernel<<<(N + 256) / 256, 256, 0, stream>>>(tmp, bsum, rowptr, cnt, N, NB);
        bplace_kernel<<<NBUK, 256, 0, stream>>>(ebuf, bbase, rowptr, ecol, N);
    } else {  // fallback: old random-scatter path
        hipMemsetAsync(deg, 0, (size_t)N * 4, stream);
        int eblocks = (ET + 255) / 256;
        hist_kernel<<<eblocks, 256, 0, stream>>>(ei, E, N, flagI, deg);
        scan1_kernel<<<NB, 1024, 0, stream>>>(deg, tmp, bsum, N);
        scan2_kernel<<<1, 64, 0, stream>>>(bsum, NB);
        scan3_kernel<<<(N + 256) / 256, 256, 0, stream>>>(tmp, bsum, rowptr, cnt, N, NB);
        scatter_kernel<<<eblocks, 256, 0, stream>>>(ei, E, N, flagI, rowptr, cnt, ecol);
    }

    int nblocks4 = (N + 3) / 4;
    int gblocks = (N + 63) / 64;
    // ---- layer 1 ----
    gemm1_kernel<<<gblocks, 256, 0, stream>>>(
        x_raw, xbf, flagF, W1T, h1, att1f, (float4*)asrc1, (float4*)adst1, N);
    agg1_kernel<<<nblocks4, 256, 0, stream>>>(
        h1, (const float4*)asrc1, (const float4*)adst1, rowptr, ecol, b1f, w2t8,
        (uint*)hL1, (float4*)asrc2, (float4*)adst2, N);
    // ---- layer 2 ----
    agg2_kernel<<<nblocks4, 256, 0, stream>>>(
        hL1, (const float4*)asrc2, (const float4*)adst2, rowptr, ecol, (uint*)z2, N);
    gemm2_kernel<<<gblocks, 256, 0, stream>>>(z2, W2sT, b2f, (float*)d_out, N);
}

// Round 10
// 312.311 us; speedup vs baseline: 2.4230x; 1.0498x over previous
//
#include <hip/hip_runtime.h>

typedef unsigned int uint;
typedef unsigned short ushort;

// N=50000 nodes, E=800000 edges, F_in=128, heads=4, C1=32 (concat->128), C2=64 (mean->64)
// R10: agg kernels process 2 nodes/wave (half-wave each, deg chunked by 32, uniform path).
// CSR build: bhist -> bscan -> part -> bfinal (fused deg+scan+rowptr+place per bucket).

__device__ __forceinline__ float leaky(float x) { return x >= 0.f ? x : 0.2f * x; }
__device__ __forceinline__ float b2f(ushort h) { return __uint_as_float(((uint)h) << 16); }
__device__ __forceinline__ ushort f2b(float f) {
    uint u = __float_as_uint(f);
    return (ushort)((u + 0x7FFF + ((u >> 16) & 1)) >> 16);  // RNE
}

#if defined(__has_builtin)
#if __has_builtin(__builtin_amdgcn_fdot2_f32_bf16)
#define HAS_DOT2 1
#endif
#endif
#ifndef HAS_DOT2
#define HAS_DOT2 0
#endif

#if HAS_DOT2
typedef __bf16 bf16v2 __attribute__((ext_vector_type(2)));
__device__ __forceinline__ float dot2bf(uint h2, uint w2, float c) {
    return __builtin_amdgcn_fdot2_f32_bf16(__builtin_bit_cast(bf16v2, h2),
                                           __builtin_bit_cast(bf16v2, w2), c, false);
}
#define DOT2PAIR(hE, hE1, wpk, a0, a1)                                  \
    a0 = dot2bf(__builtin_amdgcn_perm(hE, hE1, 0x01000504), wpk, a0);   \
    a1 = dot2bf(__builtin_amdgcn_perm(hE, hE1, 0x03020706), wpk, a1);
#else
#define DOT2PAIR(hE, hE1, wpk, a0, a1)                                  \
    {                                                                   \
        float wlo = __uint_as_float((wpk) << 16);                       \
        float whi = __uint_as_float((wpk) & 0xffff0000u);               \
        a0 = fmaf(wlo, __uint_as_float((hE) << 16), a0);                \
        a1 = fmaf(wlo, __uint_as_float((hE) & 0xffff0000u), a1);        \
        a0 = fmaf(whi, __uint_as_float((hE1) << 16), a0);               \
        a1 = fmaf(whi, __uint_as_float((hE1) & 0xffff0000u), a1);       \
    }
#endif

// ---------------- dtype detection ----------------
__global__ void detect_kernel(const int* __restrict__ ei, const void* __restrict__ xin,
                              int* __restrict__ flagI, int* __restrict__ flagF) {
    __shared__ int s_sane, s_odd;
    int t = threadIdx.x;  // 256 threads
    if (t == 0) { s_sane = 0; s_odd = 0; }
    __syncthreads();
    if (t < 64 && ei[2 * t + 1] != 0) atomicOr(&s_odd, 1);
    ushort v = ((const ushort*)xin)[2 * t];
    int ex = (v >> 7) & 0xFF;
    if (v == 0 || (ex >= 100 && ex <= 135)) atomicAdd(&s_sane, 1);
    __syncthreads();
    if (t == 0) { *flagI = (s_odd == 0); *flagF = (s_sane >= 230); }
}

__device__ __forceinline__ float rdf(const void* p_, int i, int bf) {
    return bf ? b2f(((const ushort*)p_)[i]) : ((const float*)p_)[i];
}

// ---------------- prep: x->bf16 (only if f32 input), W1^T, att1/b1/b2 cvts ----------------
__global__ void prep_kernel(const void* __restrict__ x, const void* __restrict__ W1,
                            const void* __restrict__ as1, const void* __restrict__ ad1,
                            const void* __restrict__ b1, const void* __restrict__ b2,
                            ushort* __restrict__ xbf, ushort* __restrict__ W1T,
                            float* __restrict__ att1, float* __restrict__ b1f,
                            float* __restrict__ b2f_, int NX, const int* __restrict__ flagF) {
    int bf = *flagF;
    int b = blockIdx.x, t = threadIdx.x;
    int nxb = (NX + 255) / 256;
    if (b < nxb) {
        if (bf) return;  // bf16 input: gemm1 reads x_raw directly
        int i = b * 256 + t;
        if (i < NX) xbf[i] = f2b(((const float*)x)[i]);
        return;
    }
    b -= nxb;
    if (b < 64) {  // W1 [128 k][128 n] -> W1T [n][k]
        int i = b * 256 + t;
        int k = i >> 7, n = i & 127;
        W1T[n * 128 + k] = bf ? ((const ushort*)W1)[i] : f2b(((const float*)W1)[i]);
        return;
    }
    b -= 64;
    {  // smalls: 512 idx
        int i = b * 256 + t;
        if (i < 128)      att1[i] = rdf(as1, i, bf);
        else if (i < 256) att1[i] = rdf(ad1, i - 128, bf);
        else if (i < 384) b1f[i - 256] = rdf(b1, i - 256, bf);
        else if (i < 448) b2f_[i - 384] = rdf(b2, i - 384, bf);
    }
}

// ---------------- prep2: folded attention-2 vectors + stacked mean-folded W2 ----------------
__global__ void prep2_kernel(const void* __restrict__ W2, const void* __restrict__ as2,
                             const void* __restrict__ ad2, float* __restrict__ w2t8,
                             ushort* __restrict__ W2sT, const int* __restrict__ flagF) {
    int bf = *flagF;
    int b = blockIdx.x, t = threadIdx.x;
    if (b < 4) {
        int idx = b * 256 + t;  // 1024 = 8 o x 128 k
        int o = idx >> 7, k = idx & 127, h = o & 3;
        const void* att = (o < 4) ? as2 : ad2;
        float s = 0.f;
        for (int c = 0; c < 64; ++c) s += rdf(W2, k * 256 + h * 64 + c, bf) * rdf(att, h * 64 + c, bf);
        w2t8[o * 128 + k] = s;
        return;
    }
    b -= 4;
    {  // 128 blocks: 32768 = 64 c x 512 hk
        int idx = b * 256 + t;
        int c = idx >> 9, hk = idx & 511;
        int h = hk >> 7, k = hk & 127;
        W2sT[c * 512 + hk] = f2b(0.25f * rdf(W2, k * 256 + h * 64 + c, bf));
    }
}

// ================= CSR build (N <= 65536): bucketed, locality-aware =================
__device__ __forceinline__ int edge_dst(const int* __restrict__ ei, int E, int e, int is64) {
    return (e >= E) ? (e - E) : (is64 ? ei[2 * E + 2 * e] : ei[E + e]);
}

__global__ __launch_bounds__(256) void bhist_kernel(const int* __restrict__ ei, int E, int ET,
                                                    const int* __restrict__ flagI,
                                                    int* __restrict__ bcnt) {
    __shared__ int bins[256];
    int t = threadIdx.x;
    bins[t] = 0;
    __syncthreads();
    int is64 = *flagI;
    int base = blockIdx.x * 4096;
    for (int i = 0; i < 16; ++i) {
        int e = base + i * 256 + t;
        if (e < ET) atomicAdd(&bins[edge_dst(ei, E, e, is64) >> 8], 1);
    }
    __syncthreads();
    if (bins[t]) atomicAdd(&bcnt[t], bins[t]);
}

__global__ __launch_bounds__(256) void bscan_kernel(const int* __restrict__ bcnt,
                                                    int* __restrict__ bbase,
                                                    int* __restrict__ gcur, int NBUK) {
    __shared__ int sc[256];
    int t = threadIdx.x;
    int v = (t < NBUK) ? bcnt[t] : 0;
    sc[t] = v;
    __syncthreads();
    for (int off = 1; off < 256; off <<= 1) {
        int a = (t >= off) ? sc[t - off] : 0;
        __syncthreads();
        sc[t] += a;
        __syncthreads();
    }
    int excl = sc[t] - v;
    if (t < NBUK) { bbase[t] = excl; gcur[t] = excl; }
    if (t == 255) bbase[NBUK] = sc[255];
}

__global__ __launch_bounds__(256) void part_kernel(const int* __restrict__ ei, int E, int ET,
                                                   const int* __restrict__ flagI,
                                                   int* __restrict__ gcur,
                                                   uint* __restrict__ ebuf, int NBUK) {
    __shared__ uint stage[8192];
    __shared__ int cnt_s[256], sc[256], lbase[257], cur[256], gb[256];
    int t = threadIdx.x;
    int base = blockIdx.x * 8192;
    cnt_s[t] = 0;
    __syncthreads();
    int is64 = *flagI;
    uint pk[32];
    short bk[32];
#pragma unroll
    for (int i = 0; i < 32; ++i) {
        int e = base + i * 256 + t;
        if (e < ET) {
            int src, dst;
            if (e >= E) { src = dst = e - E; }
            else if (is64) { src = ei[2 * e]; dst = ei[2 * E + 2 * e]; }
            else           { src = ei[e];     dst = ei[E + e]; }
            pk[i] = (uint)src | ((uint)dst << 16);
            bk[i] = (short)(dst >> 8);
            atomicAdd(&cnt_s[bk[i]], 1);
        } else bk[i] = -1;
    }
    __syncthreads();
    int v = cnt_s[t];
    sc[t] = v;
    __syncthreads();
    for (int off = 1; off < 256; off <<= 1) {
        int a = (t >= off) ? sc[t - off] : 0;
        __syncthreads();
        sc[t] += a;
        __syncthreads();
    }
    lbase[t + 1] = sc[t];
    cur[t] = sc[t] - v;  // exclusive
    if (t == 0) lbase[0] = 0;
    __syncthreads();
#pragma unroll
    for (int i = 0; i < 32; ++i)
        if (bk[i] >= 0) {
            int slot = atomicAdd(&cur[bk[i]], 1);
            stage[slot] = pk[i];
        }
    __syncthreads();
    if (t < NBUK) {
        int c = lbase[t + 1] - lbase[t];
        if (c > 0) gb[t] = atomicAdd(&gcur[t], c);
    }
    __syncthreads();
    int total = lbase[256];
    for (int i = t; i < total; i += 256) {
        int lo = 0, hi = 255;  // largest b with lbase[b] <= i
        while (lo < hi) { int mid = (lo + hi + 1) >> 1; if (lbase[mid] <= i) lo = mid; else hi = mid - 1; }
        ebuf[gb[lo] + (i - lbase[lo])] = stage[i];
    }
}

// fused per-bucket: hist -> scan -> rowptr -> place (one block per bucket)
__global__ __launch_bounds__(256) void bfinal_kernel(const uint* __restrict__ ebuf,
                                                     const int* __restrict__ bbase,
                                                     int* __restrict__ rowptr,
                                                     int* __restrict__ ecol, int N, int NBUK) {
    __shared__ int hist[256], cur[256], ws[4];
    int b = blockIdx.x, t = threadIdx.x;
    int lane = t & 63, wid = t >> 6;
    int d0 = b << 8;
    hist[t] = 0;
    __syncthreads();
    int s = bbase[b], e2 = bbase[b + 1];
    for (int i = s + t; i < e2; i += 256) atomicAdd(&hist[(ebuf[i] >> 16) - d0], 1);
    __syncthreads();
    int v = hist[t];
    int incl = v;
#pragma unroll
    for (int off = 1; off < 64; off <<= 1) {
        int a = __shfl_up(incl, off, 64);
        if (lane >= off) incl += a;
    }
    if (lane == 63) ws[wid] = incl;
    __syncthreads();
    if (t == 0) {
        int acc = 0;
        for (int j = 0; j < 4; ++j) { int x = ws[j]; ws[j] = acc; acc += x; }
    }
    __syncthreads();
    int excl = incl - v + ws[wid];
    int d = d0 + t;
    if (d < N) rowptr[d] = s + excl;
    cur[t] = s + excl;
    if (b == NBUK - 1 && t == 0) rowptr[N] = bbase[NBUK];
    __syncthreads();
    for (int i = s + t; i < e2; i += 256) {
        uint pk = ebuf[i];
        int pos = atomicAdd(&cur[(pk >> 16) - d0], 1);
        ecol[pos] = (int)(pk & 0xffffu);
    }
}

// ---- fallback CSR (N > 65536) ----
__global__ void hist_kernel(const int* __restrict__ ei, int E, int N,
                            const int* __restrict__ flag, int* __restrict__ deg) {
    int e = blockIdx.x * blockDim.x + threadIdx.x;
    if (e >= E + N) return;
    atomicAdd(&deg[edge_dst(ei, E, e, *flag)], 1);
}
__global__ void scatter_kernel(const int* __restrict__ ei, int E, int N,
                               const int* __restrict__ flag, const int* __restrict__ rowptr,
                               int* __restrict__ cnt, int* __restrict__ ecol) {
    int e = blockIdx.x * blockDim.x + threadIdx.x;
    if (e >= E + N) return;
    int src, dst;
    if (e >= E) { src = dst = e - E; }
    else if (*flag) { src = ei[2 * e]; dst = ei[2 * E + 2 * e]; }
    else            { src = ei[e];     dst = ei[E + e]; }
    int pos = rowptr[dst] + atomicAdd(&cnt[dst], 1);
    ecol[pos] = src;
}
__global__ __launch_bounds__(1024) void scan1_kernel(const int* __restrict__ deg,
                                                     int* __restrict__ tmp,
                                                     int* __restrict__ bsum, int n) {
    __shared__ int ws[16];
    int tid = threadIdx.x, lane = tid & 63, wid = tid >> 6;
    int i = blockIdx.x * 1024 + tid;
    int v = (i < n) ? deg[i] : 0;
    int incl = v;
#pragma unroll
    for (int off = 1; off < 64; off <<= 1) {
        int t2 = __shfl_up(incl, off, 64);
        if (lane >= off) incl += t2;
    }
    if (lane == 63) ws[wid] = incl;
    __syncthreads();
    if (tid < 16) {
        int wv_ = ws[tid], winc = wv_;
#pragma unroll
        for (int off = 1; off < 16; off <<= 1) {
            int t2 = __shfl_up(winc, off, 16);
            if (tid >= off) winc += t2;
        }
        ws[tid] = winc - wv_;
    }
    __syncthreads();
    int excl = incl - v + ws[wid];
    if (i < n) tmp[i] = excl;
    if (tid == 1023) bsum[blockIdx.x] = excl + v;
}
__global__ void scan2_kernel(int* __restrict__ bsum, int nb) {
    int lane = threadIdx.x;
    int v = (lane < nb) ? bsum[lane] : 0;
    int incl = v;
    for (int off = 1; off < 64; off <<= 1) {
        int t = __shfl_up(incl, off, 64);
        if (lane >= off) incl += t;
    }
    int total = __shfl(incl, nb - 1, 64);
    if (lane < nb) bsum[lane] = incl - v;
    if (lane == 0) bsum[nb] = total;
}
__global__ void scan3_kernel(const int* __restrict__ tmp, const int* __restrict__ bsum,
                             int* __restrict__ rowptr, int* __restrict__ cnt, int n, int nb) {
    int i = blockIdx.x * blockDim.x + threadIdx.x;
    if (i > n) return;
    rowptr[i] = (i == n) ? bsum[nb] : tmp[i] + bsum[i >> 10];
    if (i < n) cnt[i] = 0;
}

// ---------------- gemm1: h1 = x@W1 (bf16) + fused attdot1 ----------------
typedef __attribute__((ext_vector_type(8))) short bf16x8;
typedef __attribute__((ext_vector_type(4))) float floatx4;

__global__ __launch_bounds__(256) void gemm1_kernel(
    const void* __restrict__ xraw, const ushort* __restrict__ xbf, const int* __restrict__ flagF,
    const ushort* __restrict__ BT, ushort* __restrict__ C,
    const float* __restrict__ att, float4* __restrict__ asrc4, float4* __restrict__ adst4, int M) {
    constexpr int K = 128, NT = 8;
    const ushort* A = (*flagF) ? (const ushort*)xraw : xbf;
    int lane = threadIdx.x & 63, wv = threadIdx.x >> 6;
    int row0 = (blockIdx.x * 4 + wv) * 16;
    if (row0 >= M) return;
    int m = lane & 15, quad = lane >> 4;
    int rowa = min(row0 + m, M - 1);
    const bf16x8* arow = (const bf16x8*)(A + (size_t)rowa * K);
    bf16x8 af[4];
#pragma unroll
    for (int kk = 0; kk < 4; ++kk) af[kk] = arow[4 * kk + quad];
    floatx4 acc[NT] = {};
#pragma unroll
    for (int nt = 0; nt < NT; ++nt) {
        const bf16x8* brow = (const bf16x8*)(BT + (size_t)(nt * 16 + m) * K);
#pragma unroll
        for (int kk = 0; kk < 4; ++kk)
            acc[nt] = __builtin_amdgcn_mfma_f32_16x16x32_bf16(af[kk], brow[4 * kk + quad], acc[nt], 0, 0, 0);
    }
    // C/D layout: col = lane&15, row = quad*4 + reg
#pragma unroll
    for (int nt = 0; nt < NT; ++nt)
#pragma unroll
        for (int r = 0; r < 4; ++r) {
            int row = row0 + quad * 4 + r;
            if (row < M) C[(size_t)row * 128 + nt * 16 + m] = f2b(acc[nt][r]);
        }
    float attS[NT], attD[NT];
#pragma unroll
    for (int nt = 0; nt < NT; ++nt) { attS[nt] = att[nt * 16 + m]; attD[nt] = att[128 + nt * 16 + m]; }
#pragma unroll
    for (int r = 0; r < 4; ++r) {
        float ps[4] = {0, 0, 0, 0}, pd[4] = {0, 0, 0, 0};
#pragma unroll
        for (int nt = 0; nt < NT; ++nt) {
            int h = nt / 2;  // layer-1 head = col/32
            ps[h] = fmaf(acc[nt][r], attS[nt], ps[h]);
            pd[h] = fmaf(acc[nt][r], attD[nt], pd[h]);
        }
#pragma unroll
        for (int off = 1; off < 16; off <<= 1) {
#pragma unroll
            for (int h = 0; h < 4; ++h) {
                ps[h] += __shfl_xor(ps[h], off, 64);
                pd[h] += __shfl_xor(pd[h], off, 64);
            }
        }
        int row = row0 + quad * 4 + r;
        if (m == 0 && row < M) {
            asrc4[row] = make_float4(ps[0], ps[1], ps[2], ps[3]);
            adst4[row] = make_float4(pd[0], pd[1], pd[2], pd[3]);
        }
    }
}

// ---------------- agg1: 2 nodes/wave; h1 -> hL1 (bias+ELU) + fused attdot2 ----------------
// Half-wave (32 lanes) per node; deg chunked by 32; lane c owns channels 4c..4c+3 (head c>>3).
__global__ __launch_bounds__(256) void agg1_kernel(
    const ushort* __restrict__ hsrc, const float4* __restrict__ a_src4,
    const float4* __restrict__ a_dst4, const int* __restrict__ rowptr,
    const int* __restrict__ ecol, const float* __restrict__ bias,
    const float* __restrict__ w2t8, uint2* __restrict__ outz,
    float4* __restrict__ asrc2, float4* __restrict__ adst2, int N) {
    constexpr int SH = 7;  // row = 128 ush
    __shared__ __align__(16) ushort elds[4][4][2][40];  // [wave][head][half][32+pad]
    int lane = threadIdx.x & 63, wv = threadIdx.x >> 6;
    int p = lane >> 5, c = lane & 31, pbase = p << 5;
    int n = blockIdx.x * 8 + wv * 2 + p;
    bool nv = n < N;
    int start = 0, end = 0;
    if (nv) { start = rowptr[n]; end = rowptr[n + 1]; }
    int deg = end - start;
    float4 ad = nv ? a_dst4[n] : make_float4(0.f, 0.f, 0.f, 0.f);
    int hh = c >> 3;
    uint laneoff = c * 4;  // ushort offset (4 ch/lane)
    float acc[4] = {};
    float ss0 = 0.f, ss1 = 0.f, ss2 = 0.f, ss3 = 0.f;
    const uint4* wb = (const uint4*)&elds[wv][hh][p][0];

    for (int cs = 0; cs < deg; cs += 32) {
        int len = min(32, deg - cs);
        bool v = c < len;
        int sv = v ? ecol[start + cs + c] : 0;
        float4 as = a_src4[sv];
        float e0 = v ? __expf(fminf(leaky(as.x + ad.x), 60.f)) : 0.f;
        float e1 = v ? __expf(fminf(leaky(as.y + ad.y), 60.f)) : 0.f;
        float e2 = v ? __expf(fminf(leaky(as.z + ad.z), 60.f)) : 0.f;
        float e3 = v ? __expf(fminf(leaky(as.w + ad.w), 60.f)) : 0.f;
        ushort r0 = f2b(e0), r1 = f2b(e1), r2 = f2b(e2), r3 = f2b(e3);
        elds[wv][0][p][c] = r0; elds[wv][1][p][c] = r1;
        elds[wv][2][p][c] = r2; elds[wv][3][p][c] = r3;
        ss0 += b2f(r0); ss1 += b2f(r1); ss2 += b2f(r2); ss3 += b2f(r3);
        for (int e = 0; e < len; e += 8) {
            int s0 = __shfl(sv, pbase + e + 0, 64);
            int s1 = __shfl(sv, pbase + e + 1, 64);
            int s2 = __shfl(sv, pbase + e + 2, 64);
            int s3 = __shfl(sv, pbase + e + 3, 64);
            int s4 = __shfl(sv, pbase + e + 4, 64);
            int s5 = __shfl(sv, pbase + e + 5, 64);
            int s6 = __shfl(sv, pbase + e + 6, 64);
            int s7 = __shfl(sv, pbase + e + 7, 64);
            uint4 w = wb[e >> 3];
            uint2 h0 = *(const uint2*)(hsrc + (((uint)s0) << SH) + laneoff);
            uint2 h1 = *(const uint2*)(hsrc + (((uint)s1) << SH) + laneoff);
            uint2 h2 = *(const uint2*)(hsrc + (((uint)s2) << SH) + laneoff);
            uint2 h3 = *(const uint2*)(hsrc + (((uint)s3) << SH) + laneoff);
            uint2 h4 = *(const uint2*)(hsrc + (((uint)s4) << SH) + laneoff);
            uint2 h5 = *(const uint2*)(hsrc + (((uint)s5) << SH) + laneoff);
            uint2 h6 = *(const uint2*)(hsrc + (((uint)s6) << SH) + laneoff);
            uint2 h7 = *(const uint2*)(hsrc + (((uint)s7) << SH) + laneoff);
            DOT2PAIR(h0.x, h1.x, w.x, acc[0], acc[1]); DOT2PAIR(h0.y, h1.y, w.x, acc[2], acc[3]);
            DOT2PAIR(h2.x, h3.x, w.y, acc[0], acc[1]); DOT2PAIR(h2.y, h3.y, w.y, acc[2], acc[3]);
            DOT2PAIR(h4.x, h5.x, w.z, acc[0], acc[1]); DOT2PAIR(h4.y, h5.y, w.z, acc[2], acc[3]);
            DOT2PAIR(h6.x, h7.x, w.w, acc[0], acc[1]); DOT2PAIR(h6.y, h7.y, w.w, acc[2], acc[3]);
        }
    }
#pragma unroll
    for (int off = 1; off < 32; off <<= 1) {  // within-half reduce
        ss0 += __shfl_xor(ss0, off, 64); ss1 += __shfl_xor(ss1, off, 64);
        ss2 += __shfl_xor(ss2, off, 64); ss3 += __shfl_xor(ss3, off, 64);
    }
    if (!nv) return;
    float ih = (hh == 0) ? 1.f / (ss0 + 1e-16f) : (hh == 1) ? 1.f / (ss1 + 1e-16f)
             : (hh == 2) ? 1.f / (ss2 + 1e-16f) : 1.f / (ss3 + 1e-16f);
    float o0 = acc[0] * ih + bias[4 * c + 0];
    float o1 = acc[1] * ih + bias[4 * c + 1];
    float o2 = acc[2] * ih + bias[4 * c + 2];
    float o3 = acc[3] * ih + bias[4 * c + 3];
    o0 = o0 > 0.f ? o0 : __expf(o0) - 1.f;
    o1 = o1 > 0.f ? o1 : __expf(o1) - 1.f;
    o2 = o2 > 0.f ? o2 : __expf(o2) - 1.f;
    o3 = o3 > 0.f ? o3 : __expf(o3) - 1.f;
    uint2 pk;
    pk.x = (uint)f2b(o0) | ((uint)f2b(o1) << 16);
    pk.y = (uint)f2b(o2) | ((uint)f2b(o3) << 16);
    outz[(size_t)n * 32 + c] = pk;

    // fused attdot2: a2[o] = hL1[n] . w2t8[o]
    float po[8];
#pragma unroll
    for (int o = 0; o < 8; ++o) {
        float4 w = ((const float4*)(w2t8 + o * 128))[c];
        po[o] = fmaf(o0, w.x, fmaf(o1, w.y, fmaf(o2, w.z, o3 * w.w)));
    }
#pragma unroll
    for (int off = 1; off < 32; off <<= 1)
#pragma unroll
        for (int o = 0; o < 8; ++o) po[o] += __shfl_xor(po[o], off, 64);
    if (c == 0) {
        asrc2[n] = make_float4(po[0], po[1], po[2], po[3]);
        adst2[n] = make_float4(po[4], po[5], po[6], po[7]);
    }
}

// ---------------- agg2: 2 nodes/wave per-head aggregate of hL1 -> z2 [N][4][128] ----------------
__global__ __launch_bounds__(256) void agg2_kernel(
    const ushort* __restrict__ hsrc, const float4* __restrict__ a_src4,
    const float4* __restrict__ a_dst4, const int* __restrict__ rowptr,
    const int* __restrict__ ecol, uint2* __restrict__ z2u, int N) {
    constexpr int SH = 7;
    __shared__ __align__(16) ushort elds[4][4][2][40];
    int lane = threadIdx.x & 63, wv = threadIdx.x >> 6;
    int p = lane >> 5, c = lane & 31, pbase = p << 5;
    int n = blockIdx.x * 8 + wv * 2 + p;
    bool nv = n < N;
    int start = 0, end = 0;
    if (nv) { start = rowptr[n]; end = rowptr[n + 1]; }
    int deg = end - start;
    float4 ad = nv ? a_dst4[n] : make_float4(0.f, 0.f, 0.f, 0.f);
    uint laneoff = c * 4;
    float a0_[4] = {}, a1_[4] = {}, a2_[4] = {}, a3_[4] = {};  // [head][ch]
    float ss0 = 0.f, ss1 = 0.f, ss2 = 0.f, ss3 = 0.f;
    const uint4* wb0 = (const uint4*)&elds[wv][0][p][0];
    const uint4* wb1 = (const uint4*)&elds[wv][1][p][0];
    const uint4* wb2 = (const uint4*)&elds[wv][2][p][0];
    const uint4* wb3 = (const uint4*)&elds[wv][3][p][0];

    for (int cs = 0; cs < deg; cs += 32) {
        int len = min(32, deg - cs);
        bool v = c < len;
        int sv = v ? ecol[start + cs + c] : 0;
        float4 as = a_src4[sv];
        float e0 = v ? __expf(fminf(leaky(as.x + ad.x), 60.f)) : 0.f;
        float e1 = v ? __expf(fminf(leaky(as.y + ad.y), 60.f)) : 0.f;
        float e2 = v ? __expf(fminf(leaky(as.z + ad.z), 60.f)) : 0.f;
        float e3 = v ? __expf(fminf(leaky(as.w + ad.w), 60.f)) : 0.f;
        ushort r0 = f2b(e0), r1 = f2b(e1), r2 = f2b(e2), r3 = f2b(e3);
        elds[wv][0][p][c] = r0; elds[wv][1][p][c] = r1;
        elds[wv][2][p][c] = r2; elds[wv][3][p][c] = r3;
        ss0 += b2f(r0); ss1 += b2f(r1); ss2 += b2f(r2); ss3 += b2f(r3);
        for (int e = 0; e < len; e += 8) {
            int s0 = __shfl(sv, pbase + e + 0, 64);
            int s1 = __shfl(sv, pbase + e + 1, 64);
            int s2 = __shfl(sv, pbase + e + 2, 64);
            int s3 = __shfl(sv, pbase + e + 3, 64);
            int s4 = __shfl(sv, pbase + e + 4, 64);
            int s5 = __shfl(sv, pbase + e + 5, 64);
            int s6 = __shfl(sv, pbase + e + 6, 64);
            int s7 = __shfl(sv, pbase + e + 7, 64);
            uint2 h0 = *(const uint2*)(hsrc + (((uint)s0) << SH) + laneoff);
            uint2 h1 = *(const uint2*)(hsrc + (((uint)s1) << SH) + laneoff);
            uint2 h2 = *(const uint2*)(hsrc + (((uint)s2) << SH) + laneoff);
            uint2 h3 = *(const uint2*)(hsrc + (((uint)s3) << SH) + laneoff);
            uint2 h4 = *(const uint2*)(hsrc + (((uint)s4) << SH) + laneoff);
            uint2 h5 = *(const uint2*)(hsrc + (((uint)s5) << SH) + laneoff);
            uint2 h6 = *(const uint2*)(hsrc + (((uint)s6) << SH) + laneoff);
            uint2 h7 = *(const uint2*)(hsrc + (((uint)s7) << SH) + laneoff);
            uint4 w0 = wb0[e >> 3], w1 = wb1[e >> 3], w2 = wb2[e >> 3], w3 = wb3[e >> 3];
            // perms across heads are CSE'd by the compiler
            DOT2PAIR(h0.x, h1.x, w0.x, a0_[0], a0_[1]); DOT2PAIR(h0.y, h1.y, w0.x, a0_[2], a0_[3]);
            DOT2PAIR(h0.x, h1.x, w1.x, a1_[0], a1_[1]); DOT2PAIR(h0.y, h1.y, w1.x, a1_[2], a1_[3]);
            DOT2PAIR(h0.x, h1.x, w2.x, a2_[0], a2_[1]); DOT2PAIR(h0.y, h1.y, w2.x, a2_[2], a2_[3]);
            DOT2PAIR(h0.x, h1.x, w3.x, a3_[0], a3_[1]); DOT2PAIR(h0.y, h1.y, w3.x, a3_[2], a3_[3]);
            DOT2PAIR(h2.x, h3.x, w0.y, a0_[0], a0_[1]); DOT2PAIR(h2.y, h3.y, w0.y, a0_[2], a0_[3]);
            DOT2PAIR(h2.x, h3.x, w1.y, a1_[0], a1_[1]); DOT2PAIR(h2.y, h3.y, w1.y, a1_[2], a1_[3]);
            DOT2PAIR(h2.x, h3.x, w2.y, a2_[0], a2_[1]); DOT2PAIR(h2.y, h3.y, w2.y, a2_[2], a2_[3]);
            DOT2PAIR(h2.x, h3.x, w3.y, a3_[0], a3_[1]); DOT2PAIR(h2.y, h3.y, w3.y, a3_[2], a3_[3]);
            DOT2PAIR(h4.x, h5.x, w0.z, a0_[0], a0_[1]); DOT2PAIR(h4.y, h5.y, w0.z, a0_[2], a0_[3]);
            DOT2PAIR(h4.x, h5.x, w1.z, a1_[0], a1_[1]); DOT2PAIR(h4.y, h5.y, w1.z, a1_[2], a1_[3]);
            DOT2PAIR(h4.x, h5.x, w2.z, a2_[0], a2_[1]); DOT2PAIR(h4.y, h5.y, w2.z, a2_[2], a2_[3]);
            DOT2PAIR(h4.x, h5.x, w3.z, a3_[0], a3_[1]); DOT2PAIR(h4.y, h5.y, w3.z, a3_[2], a3_[3]);
            DOT2PAIR(h6.x, h7.x, w0.w, a0_[0], a0_[1]); DOT2PAIR(h6.y, h7.y, w0.w, a0_[2], a0_[3]);
            DOT2PAIR(h6.x, h7.x, w1.w, a1_[0], a1_[1]); DOT2PAIR(h6.y, h7.y, w1.w, a1_[2], a1_[3]);
            DOT2PAIR(h6.x, h7.x, w2.w, a2_[0], a2_[1]); DOT2PAIR(h6.y, h7.y, w2.w, a2_[2], a2_[3]);
            DOT2PAIR(h6.x, h7.x, w3.w, a3_[0], a3_[1]); DOT2PAIR(h6.y, h7.y, w3.w, a3_[2], a3_[3]);
        }
    }
#pragma unroll
    for (int off = 1; off < 32; off <<= 1) {
        ss0 += __shfl_xor(ss0, off, 64); ss1 += __shfl_xor(ss1, off, 64);
        ss2 += __shfl_xor(ss2, off, 64); ss3 += __shfl_xor(ss3, off, 64);
    }
    if (!nv) return;
    float i0 = 1.f / (ss0 + 1e-16f), i1 = 1.f / (ss1 + 1e-16f);
    float i2 = 1.f / (ss2 + 1e-16f), i3 = 1.f / (ss3 + 1e-16f);
    size_t base = (size_t)n * 128 + c;  // uint2 units: [n][4][32]
    uint2 pk;
    pk.x = (uint)f2b(a0_[0] * i0) | ((uint)f2b(a0_[1] * i0) << 16);
    pk.y = (uint)f2b(a0_[2] * i0) | ((uint)f2b(a0_[3] * i0) << 16);
    z2u[base] = pk;
    pk.x = (uint)f2b(a1_[0] * i1) | ((uint)f2b(a1_[1] * i1) << 16);
    pk.y = (uint)f2b(a1_[2] * i1) | ((uint)f2b(a1_[3] * i1) << 16);
    z2u[base + 32] = pk;
    pk.x = (uint)f2b(a2_[0] * i2) | ((uint)f2b(a2_[1] * i2) << 16);
    pk.y = (uint)f2b(a2_[2] * i2) | ((uint)f2b(a2_[3] * i2) << 16);
    z2u[base + 64] = pk;
    pk.x = (uint)f2b(a3_[0] * i3) | ((uint)f2b(a3_[1] * i3) << 16);
    pk.y = (uint)f2b(a3_[2] * i3) | ((uint)f2b(a3_[3] * i3) << 16);
    z2u[base + 96] = pk;
}

// ---------------- gemm2: out = z2 @ W2sT + b2, K=512, f32 out [M][64] ----------------
__global__ __launch_bounds__(256) void gemm2_kernel(
    const ushort* __restrict__ A, const ushort* __restrict__ BT, const float* __restrict__ b2,
    float* __restrict__ outp, int M) {
    constexpr int K = 512, NT = 4;
    int lane = threadIdx.x & 63, wv = threadIdx.x >> 6;
    int row0 = (blockIdx.x * 4 + wv) * 16;
    if (row0 >= M) return;
    int m = lane & 15, quad = lane >> 4;
    int rowa = min(row0 + m, M - 1);
    const bf16x8* arow = (const bf16x8*)(A + (size_t)rowa * K);
    bf16x8 af[16];
#pragma unroll
    for (int kk = 0; kk < 16; ++kk) af[kk] = arow[4 * kk + quad];
    floatx4 acc[NT] = {};
#pragma unroll
    for (int nt = 0; nt < NT; ++nt) {
        const bf16x8* brow = (const bf16x8*)(BT + (size_t)(nt * 16 + m) * K);
#pragma unroll
        for (int kk = 0; kk < 16; ++kk)
            acc[nt] = __builtin_amdgcn_mfma_f32_16x16x32_bf16(af[kk], brow[4 * kk + quad], acc[nt], 0, 0, 0);
    }
#pragma unroll
    for (int nt = 0; nt < NT; ++nt) {
        float b = b2[nt * 16 + m];
#pragma unroll
        for (int r = 0; r < 4; ++r) {
            int row = row0 + quad * 4 + r;
            if (row < M) outp[(size_t)row * 64 + nt * 16 + m] = acc[nt][r] + b;
        }
    }
}

// ---------------- launch ----------------
extern "C" void kernel_launch(void* const* d_in, const int* in_sizes, int n_in,
                              void* d_out, int out_size, void* d_ws, size_t ws_size,
                              hipStream_t stream) {
    // setup_inputs order: x, edge_index, W1, att_src1, att_dst1, bias1, W2, att_src2, att_dst2, bias2
    const void* x_raw = d_in[0];
    const int*  ei    = (const int*)d_in[1];
    const void* W1_p  = d_in[2];
    const void* as1_p = d_in[3];
    const void* ad1_p = d_in[4];
    const void* b1_p  = d_in[5];
    const void* W2_p  = d_in[6];
    const void* as2_p = d_in[7];
    const void* ad2_p = d_in[8];
    const void* b2_p  = d_in[9];

    const int F_IN = 128;
    const int N = in_sizes[0] / F_IN;   // 50000
    const int E = in_sizes[1] / 2;      // 800000
    const int ET = E + N;
    const int NB = (N + 1023) / 1024;
    const int NBUK = (N + 255) >> 8;    // buckets; packed path needs N<=65536

    char* p = (char*)d_ws;
    auto alloc = [&](size_t bytes) { char* r = p; p += (bytes + 255) & ~(size_t)255; return r; };
    ushort* xbf   = (ushort*)alloc((size_t)N * 128 * 2);
    ushort* W1T   = (ushort*)alloc(128 * 128 * 2);
    ushort* W2sT  = (ushort*)alloc(64 * 512 * 2);
    float*  att1f = (float*)alloc(256 * 4);
    float*  w2t8  = (float*)alloc(8 * 128 * 4);
    float*  b1f   = (float*)alloc(128 * 4);
    float*  b2f   = (float*)alloc(64 * 4);
    ushort* h1    = (ushort*)alloc((size_t)N * 128 * 2);
    ushort* hL1   = (ushort*)alloc((size_t)N * 128 * 2);
    ushort* z2    = (ushort*)alloc((size_t)N * 512 * 2);
    float*  asrc1 = (float*)alloc((size_t)N * 4 * 4);
    float*  adst1 = (float*)alloc((size_t)N * 4 * 4);
    float*  asrc2 = (float*)alloc((size_t)N * 4 * 4);
    float*  adst2 = (float*)alloc((size_t)N * 4 * 4);
    int* deg    = (int*)alloc((size_t)N * 4);   // fallback only
    int* cnt    = (int*)alloc((size_t)N * 4);   // fallback only
    int* tmp    = (int*)alloc((size_t)N * 4);   // fallback only
    int* bsum   = (int*)alloc(128 * 4);         // fallback only
    int* rowptr = (int*)alloc((size_t)(N + 1) * 4);
    int* ecol   = (int*)alloc((size_t)ET * 4);
    uint* ebuf  = (uint*)alloc((size_t)ET * 4);
    int* bcnt   = (int*)alloc(256 * 4);
    int* bbase  = (int*)alloc(257 * 4);
    int* gcur   = (int*)alloc(256 * 4);
    int* flagI  = (int*)alloc(256);
    int* flagF  = (int*)alloc(256);

    detect_kernel<<<1, 256, 0, stream>>>(ei, x_raw, flagI, flagF);

    int NX = N * F_IN;
    int nxb = (NX + 255) / 256;
    // prep args: x, W1, as1, ad1, b1, b2  (d_in 0, 2, 3, 4, 5, 9)
    prep_kernel<<<nxb + 64 + 2, 256, 0, stream>>>(
        x_raw, W1_p, as1_p, ad1_p, b1_p, b2_p, xbf, W1T, att1f, b1f, b2f, NX, flagF);
    // prep2 args: W2, as2, ad2  (d_in 6, 7, 8)
    prep2_kernel<<<4 + 128, 256, 0, stream>>>(W2_p, as2_p, ad2_p, w2t8, W2sT, flagF);

    if (N <= 65536) {  // bucketed locality-aware CSR: 4 dispatches
        hipMemsetAsync(bcnt, 0, 256 * 4, stream);
        bhist_kernel<<<(ET + 4095) / 4096, 256, 0, stream>>>(ei, E, ET, flagI, bcnt);
        bscan_kernel<<<1, 256, 0, stream>>>(bcnt, bbase, gcur, NBUK);
        part_kernel<<<(ET + 8191) / 8192, 256, 0, stream>>>(ei, E, ET, flagI, gcur, ebuf, NBUK);
        bfinal_kernel<<<NBUK, 256, 0, stream>>>(ebuf, bbase, rowptr, ecol, N, NBUK);
    } else {  // fallback: random-scatter path
        hipMemsetAsync(deg, 0, (size_t)N * 4, stream);
        int eblocks = (ET + 255) / 256;
        hist_kernel<<<eblocks, 256, 0, stream>>>(ei, E, N, flagI, deg);
        scan1_kernel<<<NB, 1024, 0, stream>>>(deg, tmp, bsum, N);
        scan2_kernel<<<1, 64, 0, stream>>>(bsum, NB);
        scan3_kernel<<<(N + 256) / 256, 256, 0, stream>>>(tmp, bsum, rowptr, cnt, N, NB);
        scatter_kernel<<<eblocks, 256, 0, stream>>>(ei, E, N, flagI, rowptr, cnt, ecol);
    }

    int nblocks8 = (N + 7) / 8;
    int gblocks = (N + 63) / 64;
    // ---- layer 1 ----
    gemm1_kernel<<<gblocks, 256, 0, stream>>>(
        x_raw, xbf, flagF, W1T, h1, att1f, (float4*)asrc1, (float4*)adst1, N);
    agg1_kernel<<<nblocks8, 256, 0, stream>>>(
        h1, (const float4*)asrc1, (const float4*)adst1, rowptr, ecol, b1f, w2t8,
        (uint2*)hL1, (float4*)asrc2, (float4*)adst2, N);
    // ---- layer 2 ----
    agg2_kernel<<<nblocks8, 256, 0, stream>>>(
        hL1, (const float4*)asrc2, (const float4*)adst2, rowptr, ecol, (uint2*)z2, N);
    gemm2_kernel<<<gblocks, 256, 0, stream>>>(z2, W2sT, b2f, (float*)d_out, N);
}

// Round 11
// 308.874 us; speedup vs baseline: 2.4500x; 1.0111x over previous
//
#include <hip/hip_runtime.h>

typedef unsigned int uint;
typedef unsigned short ushort;

// N=50000 nodes, E=800000 edges, F_in=128, heads=4, C1=32 (concat->128), C2=64 (mean->64)
// R11: gemm2 fused into agg2's epilogue (z2 never leaves the block: LDS A-tile + K=512 MFMA
// against W2sT, direct out+b2 write). Rest = R10 (passing): 2 nodes/wave aggs, bucketed CSR.

__device__ __forceinline__ float leaky(float x) { return x >= 0.f ? x : 0.2f * x; }
__device__ __forceinline__ float b2f(ushort h) { return __uint_as_float(((uint)h) << 16); }
__device__ __forceinline__ ushort f2b(float f) {
    uint u = __float_as_uint(f);
    return (ushort)((u + 0x7FFF + ((u >> 16) & 1)) >> 16);  // RNE
}

#if defined(__has_builtin)
#if __has_builtin(__builtin_amdgcn_fdot2_f32_bf16)
#define HAS_DOT2 1
#endif
#endif
#ifndef HAS_DOT2
#define HAS_DOT2 0
#endif

#if HAS_DOT2
typedef __bf16 bf16v2 __attribute__((ext_vector_type(2)));
__device__ __forceinline__ float dot2bf(uint h2, uint w2, float c) {
    return __builtin_amdgcn_fdot2_f32_bf16(__builtin_bit_cast(bf16v2, h2),
                                           __builtin_bit_cast(bf16v2, w2), c, false);
}
#define DOT2PAIR(hE, hE1, wpk, a0, a1)                                  \
    a0 = dot2bf(__builtin_amdgcn_perm(hE, hE1, 0x01000504), wpk, a0);   \
    a1 = dot2bf(__builtin_amdgcn_perm(hE, hE1, 0x03020706), wpk, a1);
#else
#define DOT2PAIR(hE, hE1, wpk, a0, a1)                                  \
    {                                                                   \
        float wlo = __uint_as_float((wpk) << 16);                       \
        float whi = __uint_as_float((wpk) & 0xffff0000u);               \
        a0 = fmaf(wlo, __uint_as_float((hE) << 16), a0);                \
        a1 = fmaf(wlo, __uint_as_float((hE) & 0xffff0000u), a1);        \
        a0 = fmaf(whi, __uint_as_float((hE1) << 16), a0);               \
        a1 = fmaf(whi, __uint_as_float((hE1) & 0xffff0000u), a1);       \
    }
#endif

// ---------------- dtype detection ----------------
__global__ void detect_kernel(const int* __restrict__ ei, const void* __restrict__ xin,
                              int* __restrict__ flagI, int* __restrict__ flagF) {
    __shared__ int s_sane, s_odd;
    int t = threadIdx.x;  // 256 threads
    if (t == 0) { s_sane = 0; s_odd = 0; }
    __syncthreads();
    if (t < 64 && ei[2 * t + 1] != 0) atomicOr(&s_odd, 1);
    ushort v = ((const ushort*)xin)[2 * t];
    int ex = (v >> 7) & 0xFF;
    if (v == 0 || (ex >= 100 && ex <= 135)) atomicAdd(&s_sane, 1);
    __syncthreads();
    if (t == 0) { *flagI = (s_odd == 0); *flagF = (s_sane >= 230); }
}

__device__ __forceinline__ float rdf(const void* p_, int i, int bf) {
    return bf ? b2f(((const ushort*)p_)[i]) : ((const float*)p_)[i];
}

// ---------------- prep: x->bf16 (only if f32 input), W1^T, att1/b1/b2 cvts ----------------
__global__ void prep_kernel(const void* __restrict__ x, const void* __restrict__ W1,
                            const void* __restrict__ as1, const void* __restrict__ ad1,
                            const void* __restrict__ b1, const void* __restrict__ b2,
                            ushort* __restrict__ xbf, ushort* __restrict__ W1T,
                            float* __restrict__ att1, float* __restrict__ b1f,
                            float* __restrict__ b2f_, int NX, const int* __restrict__ flagF) {
    int bf = *flagF;
    int b = blockIdx.x, t = threadIdx.x;
    int nxb = (NX + 255) / 256;
    if (b < nxb) {
        if (bf) return;  // bf16 input: gemm1 reads x_raw directly
        int i = b * 256 + t;
        if (i < NX) xbf[i] = f2b(((const float*)x)[i]);
        return;
    }
    b -= nxb;
    if (b < 64) {  // W1 [128 k][128 n] -> W1T [n][k]
        int i = b * 256 + t;
        int k = i >> 7, n = i & 127;
        W1T[n * 128 + k] = bf ? ((const ushort*)W1)[i] : f2b(((const float*)W1)[i]);
        return;
    }
    b -= 64;
    {  // smalls: 512 idx
        int i = b * 256 + t;
        if (i < 128)      att1[i] = rdf(as1, i, bf);
        else if (i < 256) att1[i] = rdf(ad1, i - 128, bf);
        else if (i < 384) b1f[i - 256] = rdf(b1, i - 256, bf);
        else if (i < 448) b2f_[i - 384] = rdf(b2, i - 384, bf);
    }
}

// ---------------- prep2: folded attention-2 vectors + stacked mean-folded W2 ----------------
__global__ void prep2_kernel(const void* __restrict__ W2, const void* __restrict__ as2,
                             const void* __restrict__ ad2, float* __restrict__ w2t8,
                             ushort* __restrict__ W2sT, const int* __restrict__ flagF) {
    int bf = *flagF;
    int b = blockIdx.x, t = threadIdx.x;
    if (b < 4) {
        int idx = b * 256 + t;  // 1024 = 8 o x 128 k
        int o = idx >> 7, k = idx & 127, h = o & 3;
        const void* att = (o < 4) ? as2 : ad2;
        float s = 0.f;
        for (int c = 0; c < 64; ++c) s += rdf(W2, k * 256 + h * 64 + c, bf) * rdf(att, h * 64 + c, bf);
        w2t8[o * 128 + k] = s;
        return;
    }
    b -= 4;
    {  // 128 blocks: 32768 = 64 c x 512 hk
        int idx = b * 256 + t;
        int c = idx >> 9, hk = idx & 511;
        int h = hk >> 7, k = hk & 127;
        W2sT[c * 512 + hk] = f2b(0.25f * rdf(W2, k * 256 + h * 64 + c, bf));
    }
}

// ================= CSR build (N <= 65536): bucketed, locality-aware =================
__device__ __forceinline__ int edge_dst(const int* __restrict__ ei, int E, int e, int is64) {
    return (e >= E) ? (e - E) : (is64 ? ei[2 * E + 2 * e] : ei[E + e]);
}

__global__ __launch_bounds__(256) void bhist_kernel(const int* __restrict__ ei, int E, int ET,
                                                    const int* __restrict__ flagI,
                                                    int* __restrict__ bcnt) {
    __shared__ int bins[256];
    int t = threadIdx.x;
    bins[t] = 0;
    __syncthreads();
    int is64 = *flagI;
    int base = blockIdx.x * 4096;
    for (int i = 0; i < 16; ++i) {
        int e = base + i * 256 + t;
        if (e < ET) atomicAdd(&bins[edge_dst(ei, E, e, is64) >> 8], 1);
    }
    __syncthreads();
    if (bins[t]) atomicAdd(&bcnt[t], bins[t]);
}

__global__ __launch_bounds__(256) void bscan_kernel(const int* __restrict__ bcnt,
                                                    int* __restrict__ bbase,
                                                    int* __restrict__ gcur, int NBUK) {
    __shared__ int sc[256];
    int t = threadIdx.x;
    int v = (t < NBUK) ? bcnt[t] : 0;
    sc[t] = v;
    __syncthreads();
    for (int off = 1; off < 256; off <<= 1) {
        int a = (t >= off) ? sc[t - off] : 0;
        __syncthreads();
        sc[t] += a;
        __syncthreads();
    }
    int excl = sc[t] - v;
    if (t < NBUK) { bbase[t] = excl; gcur[t] = excl; }
    if (t == 255) bbase[NBUK] = sc[255];
}

__global__ __launch_bounds__(256) void part_kernel(const int* __restrict__ ei, int E, int ET,
                                                   const int* __restrict__ flagI,
                                                   int* __restrict__ gcur,
                                                   uint* __restrict__ ebuf, int NBUK) {
    __shared__ uint stage[8192];
    __shared__ int cnt_s[256], sc[256], lbase[257], cur[256], gb[256];
    int t = threadIdx.x;
    int base = blockIdx.x * 8192;
    cnt_s[t] = 0;
    __syncthreads();
    int is64 = *flagI;
    uint pk[32];
    short bk[32];
#pragma unroll
    for (int i = 0; i < 32; ++i) {
        int e = base + i * 256 + t;
        if (e < ET) {
            int src, dst;
            if (e >= E) { src = dst = e - E; }
            else if (is64) { src = ei[2 * e]; dst = ei[2 * E + 2 * e]; }
            else           { src = ei[e];     dst = ei[E + e]; }
            pk[i] = (uint)src | ((uint)dst << 16);
            bk[i] = (short)(dst >> 8);
            atomicAdd(&cnt_s[bk[i]], 1);
        } else bk[i] = -1;
    }
    __syncthreads();
    int v = cnt_s[t];
    sc[t] = v;
    __syncthreads();
    for (int off = 1; off < 256; off <<= 1) {
        int a = (t >= off) ? sc[t - off] : 0;
        __syncthreads();
        sc[t] += a;
        __syncthreads();
    }
    lbase[t + 1] = sc[t];
    cur[t] = sc[t] - v;  // exclusive
    if (t == 0) lbase[0] = 0;
    __syncthreads();
#pragma unroll
    for (int i = 0; i < 32; ++i)
        if (bk[i] >= 0) {
            int slot = atomicAdd(&cur[bk[i]], 1);
            stage[slot] = pk[i];
        }
    __syncthreads();
    if (t < NBUK) {
        int c = lbase[t + 1] - lbase[t];
        if (c > 0) gb[t] = atomicAdd(&gcur[t], c);
    }
    __syncthreads();
    int total = lbase[256];
    for (int i = t; i < total; i += 256) {
        int lo = 0, hi = 255;  // largest b with lbase[b] <= i
        while (lo < hi) { int mid = (lo + hi + 1) >> 1; if (lbase[mid] <= i) lo = mid; else hi = mid - 1; }
        ebuf[gb[lo] + (i - lbase[lo])] = stage[i];
    }
}

// fused per-bucket: hist -> scan -> rowptr -> place (one block per bucket)
__global__ __launch_bounds__(256) void bfinal_kernel(const uint* __restrict__ ebuf,
                                                     const int* __restrict__ bbase,
                                                     int* __restrict__ rowptr,
                                                     int* __restrict__ ecol, int N, int NBUK) {
    __shared__ int hist[256], cur[256], ws[4];
    int b = blockIdx.x, t = threadIdx.x;
    int lane = t & 63, wid = t >> 6;
    int d0 = b << 8;
    hist[t] = 0;
    __syncthreads();
    int s = bbase[b], e2 = bbase[b + 1];
    for (int i = s + t; i < e2; i += 256) atomicAdd(&hist[(ebuf[i] >> 16) - d0], 1);
    __syncthreads();
    int v = hist[t];
    int incl = v;
#pragma unroll
    for (int off = 1; off < 64; off <<= 1) {
        int a = __shfl_up(incl, off, 64);
        if (lane >= off) incl += a;
    }
    if (lane == 63) ws[wid] = incl;
    __syncthreads();
    if (t == 0) {
        int acc = 0;
        for (int j = 0; j < 4; ++j) { int x = ws[j]; ws[j] = acc; acc += x; }
    }
    __syncthreads();
    int excl = incl - v + ws[wid];
    int d = d0 + t;
    if (d < N) rowptr[d] = s + excl;
    cur[t] = s + excl;
    if (b == NBUK - 1 && t == 0) rowptr[N] = bbase[NBUK];
    __syncthreads();
    for (int i = s + t; i < e2; i += 256) {
        uint pk = ebuf[i];
        int pos = atomicAdd(&cur[(pk >> 16) - d0], 1);
        ecol[pos] = (int)(pk & 0xffffu);
    }
}

// ---- fallback CSR (N > 65536) ----
__global__ void hist_kernel(const int* __restrict__ ei, int E, int N,
                            const int* __restrict__ flag, int* __restrict__ deg) {
    int e = blockIdx.x * blockDim.x + threadIdx.x;
    if (e >= E + N) return;
    atomicAdd(&deg[edge_dst(ei, E, e, *flag)], 1);
}
__global__ void scatter_kernel(const int* __restrict__ ei, int E, int N,
                               const int* __restrict__ flag, const int* __restrict__ rowptr,
                               int* __restrict__ cnt, int* __restrict__ ecol) {
    int e = blockIdx.x * blockDim.x + threadIdx.x;
    if (e >= E + N) return;
    int src, dst;
    if (e >= E) { src = dst = e - E; }
    else if (*flag) { src = ei[2 * e]; dst = ei[2 * E + 2 * e]; }
    else            { src = ei[e];     dst = ei[E + e]; }
    int pos = rowptr[dst] + atomicAdd(&cnt[dst], 1);
    ecol[pos] = src;
}
__global__ __launch_bounds__(1024) void scan1_kernel(const int* __restrict__ deg,
                                                     int* __restrict__ tmp,
                                                     int* __restrict__ bsum, int n) {
    __shared__ int ws[16];
    int tid = threadIdx.x, lane = tid & 63, wid = tid >> 6;
    int i = blockIdx.x * 1024 + tid;
    int v = (i < n) ? deg[i] : 0;
    int incl = v;
#pragma unroll
    for (int off = 1; off < 64; off <<= 1) {
        int t2 = __shfl_up(incl, off, 64);
        if (lane >= off) incl += t2;
    }
    if (lane == 63) ws[wid] = incl;
    __syncthreads();
    if (tid < 16) {
        int wv_ = ws[tid], winc = wv_;
#pragma unroll
        for (int off = 1; off < 16; off <<= 1) {
            int t2 = __shfl_up(winc, off, 16);
            if (tid >= off) winc += t2;
        }
        ws[tid] = winc - wv_;
    }
    __syncthreads();
    int excl = incl - v + ws[wid];
    if (i < n) tmp[i] = excl;
    if (tid == 1023) bsum[blockIdx.x] = excl + v;
}
__global__ void scan2_kernel(int* __restrict__ bsum, int nb) {
    int lane = threadIdx.x;
    int v = (lane < nb) ? bsum[lane] : 0;
    int incl = v;
    for (int off = 1; off < 64; off <<= 1) {
        int t = __shfl_up(incl, off, 64);
        if (lane >= off) incl += t;
    }
    int total = __shfl(incl, nb - 1, 64);
    if (lane < nb) bsum[lane] = incl - v;
    if (lane == 0) bsum[nb] = total;
}
__global__ void scan3_kernel(const int* __restrict__ tmp, const int* __restrict__ bsum,
                             int* __restrict__ rowptr, int* __restrict__ cnt, int n, int nb) {
    int i = blockIdx.x * blockDim.x + threadIdx.x;
    if (i > n) return;
    rowptr[i] = (i == n) ? bsum[nb] : tmp[i] + bsum[i >> 10];
    if (i < n) cnt[i] = 0;
}

// ---------------- gemm1: h1 = x@W1 (bf16) + fused attdot1 ----------------
typedef __attribute__((ext_vector_type(8))) short bf16x8;
typedef __attribute__((ext_vector_type(4))) float floatx4;

__global__ __launch_bounds__(256) void gemm1_kernel(
    const void* __restrict__ xraw, const ushort* __restrict__ xbf, const int* __restrict__ flagF,
    const ushort* __restrict__ BT, ushort* __restrict__ C,
    const float* __restrict__ att, float4* __restrict__ asrc4, float4* __restrict__ adst4, int M) {
    constexpr int K = 128, NT = 8;
    const ushort* A = (*flagF) ? (const ushort*)xraw : xbf;
    int lane = threadIdx.x & 63, wv = threadIdx.x >> 6;
    int row0 = (blockIdx.x * 4 + wv) * 16;
    if (row0 >= M) return;
    int m = lane & 15, quad = lane >> 4;
    int rowa = min(row0 + m, M - 1);
    const bf16x8* arow = (const bf16x8*)(A + (size_t)rowa * K);
    bf16x8 af[4];
#pragma unroll
    for (int kk = 0; kk < 4; ++kk) af[kk] = arow[4 * kk + quad];
    floatx4 acc[NT] = {};
#pragma unroll
    for (int nt = 0; nt < NT; ++nt) {
        const bf16x8* brow = (const bf16x8*)(BT + (size_t)(nt * 16 + m) * K);
#pragma unroll
        for (int kk = 0; kk < 4; ++kk)
            acc[nt] = __builtin_amdgcn_mfma_f32_16x16x32_bf16(af[kk], brow[4 * kk + quad], acc[nt], 0, 0, 0);
    }
    // C/D layout: col = lane&15, row = quad*4 + reg
#pragma unroll
    for (int nt = 0; nt < NT; ++nt)
#pragma unroll
        for (int r = 0; r < 4; ++r) {
            int row = row0 + quad * 4 + r;
            if (row < M) C[(size_t)row * 128 + nt * 16 + m] = f2b(acc[nt][r]);
        }
    float attS[NT], attD[NT];
#pragma unroll
    for (int nt = 0; nt < NT; ++nt) { attS[nt] = att[nt * 16 + m]; attD[nt] = att[128 + nt * 16 + m]; }
#pragma unroll
    for (int r = 0; r < 4; ++r) {
        float ps[4] = {0, 0, 0, 0}, pd[4] = {0, 0, 0, 0};
#pragma unroll
        for (int nt = 0; nt < NT; ++nt) {
            int h = nt / 2;  // layer-1 head = col/32
            ps[h] = fmaf(acc[nt][r], attS[nt], ps[h]);
            pd[h] = fmaf(acc[nt][r], attD[nt], pd[h]);
        }
#pragma unroll
        for (int off = 1; off < 16; off <<= 1) {
#pragma unroll
            for (int h = 0; h < 4; ++h) {
                ps[h] += __shfl_xor(ps[h], off, 64);
                pd[h] += __shfl_xor(pd[h], off, 64);
            }
        }
        int row = row0 + quad * 4 + r;
        if (m == 0 && row < M) {
            asrc4[row] = make_float4(ps[0], ps[1], ps[2], ps[3]);
            adst4[row] = make_float4(pd[0], pd[1], pd[2], pd[3]);
        }
    }
}

// ---------------- agg1: 2 nodes/wave; h1 -> hL1 (bias+ELU) + fused attdot2 ----------------
__global__ __launch_bounds__(256) void agg1_kernel(
    const ushort* __restrict__ hsrc, const float4* __restrict__ a_src4,
    const float4* __restrict__ a_dst4, const int* __restrict__ rowptr,
    const int* __restrict__ ecol, const float* __restrict__ bias,
    const float* __restrict__ w2t8, uint2* __restrict__ outz,
    float4* __restrict__ asrc2, float4* __restrict__ adst2, int N) {
    constexpr int SH = 7;  // row = 128 ush
    __shared__ __align__(16) ushort elds[4][4][2][40];  // [wave][head][half][32+pad]
    int lane = threadIdx.x & 63, wv = threadIdx.x >> 6;
    int p = lane >> 5, c = lane & 31, pbase = p << 5;
    int n = blockIdx.x * 8 + wv * 2 + p;
    bool nv = n < N;
    int start = 0, end = 0;
    if (nv) { start = rowptr[n]; end = rowptr[n + 1]; }
    int deg = end - start;
    float4 ad = nv ? a_dst4[n] : make_float4(0.f, 0.f, 0.f, 0.f);
    int hh = c >> 3;
    uint laneoff = c * 4;  // ushort offset (4 ch/lane)
    float acc[4] = {};
    float ss0 = 0.f, ss1 = 0.f, ss2 = 0.f, ss3 = 0.f;
    const uint4* wb = (const uint4*)&elds[wv][hh][p][0];

    for (int cs = 0; cs < deg; cs += 32) {
        int len = min(32, deg - cs);
        bool v = c < len;
        int sv = v ? ecol[start + cs + c] : 0;
        float4 as = a_src4[sv];
        float e0 = v ? __expf(fminf(leaky(as.x + ad.x), 60.f)) : 0.f;
        float e1 = v ? __expf(fminf(leaky(as.y + ad.y), 60.f)) : 0.f;
        float e2 = v ? __expf(fminf(leaky(as.z + ad.z), 60.f)) : 0.f;
        float e3 = v ? __expf(fminf(leaky(as.w + ad.w), 60.f)) : 0.f;
        ushort r0 = f2b(e0), r1 = f2b(e1), r2 = f2b(e2), r3 = f2b(e3);
        elds[wv][0][p][c] = r0; elds[wv][1][p][c] = r1;
        elds[wv][2][p][c] = r2; elds[wv][3][p][c] = r3;
        ss0 += b2f(r0); ss1 += b2f(r1); ss2 += b2f(r2); ss3 += b2f(r3);
        for (int e = 0; e < len; e += 8) {
            int s0 = __shfl(sv, pbase + e + 0, 64);
            int s1 = __shfl(sv, pbase + e + 1, 64);
            int s2 = __shfl(sv, pbase + e + 2, 64);
            int s3 = __shfl(sv, pbase + e + 3, 64);
            int s4 = __shfl(sv, pbase + e + 4, 64);
            int s5 = __shfl(sv, pbase + e + 5, 64);
            int s6 = __shfl(sv, pbase + e + 6, 64);
            int s7 = __shfl(sv, pbase + e + 7, 64);
            uint4 w = wb[e >> 3];
            uint2 h0 = *(const uint2*)(hsrc + (((uint)s0) << SH) + laneoff);
            uint2 h1 = *(const uint2*)(hsrc + (((uint)s1) << SH) + laneoff);
            uint2 h2 = *(const uint2*)(hsrc + (((uint)s2) << SH) + laneoff);
            uint2 h3 = *(const uint2*)(hsrc + (((uint)s3) << SH) + laneoff);
            uint2 h4 = *(const uint2*)(hsrc + (((uint)s4) << SH) + laneoff);
            uint2 h5 = *(const uint2*)(hsrc + (((uint)s5) << SH) + laneoff);
            uint2 h6 = *(const uint2*)(hsrc + (((uint)s6) << SH) + laneoff);
            uint2 h7 = *(const uint2*)(hsrc + (((uint)s7) << SH) + laneoff);
            DOT2PAIR(h0.x, h1.x, w.x, acc[0], acc[1]); DOT2PAIR(h0.y, h1.y, w.x, acc[2], acc[3]);
            DOT2PAIR(h2.x, h3.x, w.y, acc[0], acc[1]); DOT2PAIR(h2.y, h3.y, w.y, acc[2], acc[3]);
            DOT2PAIR(h4.x, h5.x, w.z, acc[0], acc[1]); DOT2PAIR(h4.y, h5.y, w.z, acc[2], acc[3]);
            DOT2PAIR(h6.x, h7.x, w.w, acc[0], acc[1]); DOT2PAIR(h6.y, h7.y, w.w, acc[2], acc[3]);
        }
    }
#pragma unroll
    for (int off = 1; off < 32; off <<= 1) {  // within-half reduce
        ss0 += __shfl_xor(ss0, off, 64); ss1 += __shfl_xor(ss1, off, 64);
        ss2 += __shfl_xor(ss2, off, 64); ss3 += __shfl_xor(ss3, off, 64);
    }
    if (!nv) return;
    float ih = (hh == 0) ? 1.f / (ss0 + 1e-16f) : (hh == 1) ? 1.f / (ss1 + 1e-16f)
             : (hh == 2) ? 1.f / (ss2 + 1e-16f) : 1.f / (ss3 + 1e-16f);
    float o0 = acc[0] * ih + bias[4 * c + 0];
    float o1 = acc[1] * ih + bias[4 * c + 1];
    float o2 = acc[2] * ih + bias[4 * c + 2];
    float o3 = acc[3] * ih + bias[4 * c + 3];
    o0 = o0 > 0.f ? o0 : __expf(o0) - 1.f;
    o1 = o1 > 0.f ? o1 : __expf(o1) - 1.f;
    o2 = o2 > 0.f ? o2 : __expf(o2) - 1.f;
    o3 = o3 > 0.f ? o3 : __expf(o3) - 1.f;
    uint2 pk;
    pk.x = (uint)f2b(o0) | ((uint)f2b(o1) << 16);
    pk.y = (uint)f2b(o2) | ((uint)f2b(o3) << 16);
    outz[(size_t)n * 32 + c] = pk;

    // fused attdot2: a2[o] = hL1[n] . w2t8[o]
    float po[8];
#pragma unroll
    for (int o = 0; o < 8; ++o) {
        float4 w = ((const float4*)(w2t8 + o * 128))[c];
        po[o] = fmaf(o0, w.x, fmaf(o1, w.y, fmaf(o2, w.z, o3 * w.w)));
    }
#pragma unroll
    for (int off = 1; off < 32; off <<= 1)
#pragma unroll
        for (int o = 0; o < 8; ++o) po[o] += __shfl_xor(po[o], off, 64);
    if (c == 0) {
        asrc2[n] = make_float4(po[0], po[1], po[2], po[3]);
        adst2[n] = make_float4(po[4], po[5], po[6], po[7]);
    }
}

// ---- agg2: 2 nodes/wave per-head aggregate of hL1, FUSED output GEMM (K=512 vs W2sT) ----
__global__ __launch_bounds__(256) void agg2_kernel(
    const ushort* __restrict__ hsrc, const float4* __restrict__ a_src4,
    const float4* __restrict__ a_dst4, const int* __restrict__ rowptr,
    const int* __restrict__ ecol, const ushort* __restrict__ W2sT,
    const float* __restrict__ b2, float* __restrict__ outp, int N) {
    constexpr int SH = 7;
    __shared__ __align__(16) ushort elds[4][4][2][40];
    __shared__ __align__(16) ushort lds_a[8][520];  // 8 z2-rows (K=512), +8 pad vs bank conflicts
    int lane = threadIdx.x & 63, wv = threadIdx.x >> 6;
    int p = lane >> 5, c = lane & 31, pbase = p << 5;
    int n = blockIdx.x * 8 + wv * 2 + p;
    bool nv = n < N;
    int start = 0, end = 0;
    if (nv) { start = rowptr[n]; end = rowptr[n + 1]; }
    int deg = end - start;
    float4 ad = nv ? a_dst4[n] : make_float4(0.f, 0.f, 0.f, 0.f);
    uint laneoff = c * 4;
    float a0_[4] = {}, a1_[4] = {}, a2_[4] = {}, a3_[4] = {};  // [head][ch]
    float ss0 = 0.f, ss1 = 0.f, ss2 = 0.f, ss3 = 0.f;
    const uint4* wb0 = (const uint4*)&elds[wv][0][p][0];
    const uint4* wb1 = (const uint4*)&elds[wv][1][p][0];
    const uint4* wb2 = (const uint4*)&elds[wv][2][p][0];
    const uint4* wb3 = (const uint4*)&elds[wv][3][p][0];

    for (int cs = 0; cs < deg; cs += 32) {
        int len = min(32, deg - cs);
        bool v = c < len;
        int sv = v ? ecol[start + cs + c] : 0;
        float4 as = a_src4[sv];
        float e0 = v ? __expf(fminf(leaky(as.x + ad.x), 60.f)) : 0.f;
        float e1 = v ? __expf(fminf(leaky(as.y + ad.y), 60.f)) : 0.f;
        float e2 = v ? __expf(fminf(leaky(as.z + ad.z), 60.f)) : 0.f;
        float e3 = v ? __expf(fminf(leaky(as.w + ad.w), 60.f)) : 0.f;
        ushort r0 = f2b(e0), r1 = f2b(e1), r2 = f2b(e2), r3 = f2b(e3);
        elds[wv][0][p][c] = r0; elds[wv][1][p][c] = r1;
        elds[wv][2][p][c] = r2; elds[wv][3][p][c] = r3;
        ss0 += b2f(r0); ss1 += b2f(r1); ss2 += b2f(r2); ss3 += b2f(r3);
        for (int e = 0; e < len; e += 8) {
            int s0 = __shfl(sv, pbase + e + 0, 64);
            int s1 = __shfl(sv, pbase + e + 1, 64);
            int s2 = __shfl(sv, pbase + e + 2, 64);
            int s3 = __shfl(sv, pbase + e + 3, 64);
            int s4 = __shfl(sv, pbase + e + 4, 64);
            int s5 = __shfl(sv, pbase + e + 5, 64);
            int s6 = __shfl(sv, pbase + e + 6, 64);
            int s7 = __shfl(sv, pbase + e + 7, 64);
            uint2 h0 = *(const uint2*)(hsrc + (((uint)s0) << SH) + laneoff);
            uint2 h1 = *(const uint2*)(hsrc + (((uint)s1) << SH) + laneoff);
            uint2 h2 = *(const uint2*)(hsrc + (((uint)s2) << SH) + laneoff);
            uint2 h3 = *(const uint2*)(hsrc + (((uint)s3) << SH) + laneoff);
            uint2 h4 = *(const uint2*)(hsrc + (((uint)s4) << SH) + laneoff);
            uint2 h5 = *(const uint2*)(hsrc + (((uint)s5) << SH) + laneoff);
            uint2 h6 = *(const uint2*)(hsrc + (((uint)s6) << SH) + laneoff);
            uint2 h7 = *(const uint2*)(hsrc + (((uint)s7) << SH) + laneoff);
            uint4 w0 = wb0[e >> 3], w1 = wb1[e >> 3], w2 = wb2[e >> 3], w3 = wb3[e >> 3];
            // perms across heads are CSE'd by the compiler
            DOT2PAIR(h0.x, h1.x, w0.x, a0_[0], a0_[1]); DOT2PAIR(h0.y, h1.y, w0.x, a0_[2], a0_[3]);
            DOT2PAIR(h0.x, h1.x, w1.x, a1_[0], a1_[1]); DOT2PAIR(h0.y, h1.y, w1.x, a1_[2], a1_[3]);
            DOT2PAIR(h0.x, h1.x, w2.x, a2_[0], a2_[1]); DOT2PAIR(h0.y, h1.y, w2.x, a2_[2], a2_[3]);
            DOT2PAIR(h0.x, h1.x, w3.x, a3_[0], a3_[1]); DOT2PAIR(h0.y, h1.y, w3.x, a3_[2], a3_[3]);
            DOT2PAIR(h2.x, h3.x, w0.y, a0_[0], a0_[1]); DOT2PAIR(h2.y, h3.y, w0.y, a0_[2], a0_[3]);
            DOT2PAIR(h2.x, h3.x, w1.y, a1_[0], a1_[1]); DOT2PAIR(h2.y, h3.y, w1.y, a1_[2], a1_[3]);
            DOT2PAIR(h2.x, h3.x, w2.y, a2_[0], a2_[1]); DOT2PAIR(h2.y, h3.y, w2.y, a2_[2], a2_[3]);
            DOT2PAIR(h2.x, h3.x, w3.y, a3_[0], a3_[1]); DOT2PAIR(h2.y, h3.y, w3.y, a3_[2], a3_[3]);
            DOT2PAIR(h4.x, h5.x, w0.z, a0_[0], a0_[1]); DOT2PAIR(h4.y, h5.y, w0.z, a0_[2], a0_[3]);
            DOT2PAIR(h4.x, h5.x, w1.z, a1_[0], a1_[1]); DOT2PAIR(h4.y, h5.y, w1.z, a1_[2], a1_[3]);
            DOT2PAIR(h4.x, h5.x, w2.z, a2_[0], a2_[1]); DOT2PAIR(h4.y, h5.y, w2.z, a2_[2], a2_[3]);
            DOT2PAIR(h4.x, h5.x, w3.z, a3_[0], a3_[1]); DOT2PAIR(h4.y, h5.y, w3.z, a3_[2], a3_[3]);
            DOT2PAIR(h6.x, h7.x, w0.w, a0_[0], a0_[1]); DOT2PAIR(h6.y, h7.y, w0.w, a0_[2], a0_[3]);
            DOT2PAIR(h6.x, h7.x, w1.w, a1_[0], a1_[1]); DOT2PAIR(h6.y, h7.y, w1.w, a1_[2], a1_[3]);
            DOT2PAIR(h6.x, h7.x, w2.w, a2_[0], a2_[1]); DOT2PAIR(h6.y, h7.y, w2.w, a2_[2], a2_[3]);
            DOT2PAIR(h6.x, h7.x, w3.w, a3_[0], a3_[1]); DOT2PAIR(h6.y, h7.y, w3.w, a3_[2], a3_[3]);
        }
    }
#pragma unroll
    for (int off = 1; off < 32; off <<= 1) {
        ss0 += __shfl_xor(ss0, off, 64); ss1 += __shfl_xor(ss1, off, 64);
        ss2 += __shfl_xor(ss2, off, 64); ss3 += __shfl_xor(ss3, off, 64);
    }
    // normalize (invalid nodes: acc=0 -> z=0) and stage z2 rows into LDS A-tile
    float i0 = 1.f / (ss0 + 1e-16f), i1 = 1.f / (ss1 + 1e-16f);
    float i2 = 1.f / (ss2 + 1e-16f), i3 = 1.f / (ss3 + 1e-16f);
    int slot = wv * 2 + p;
    uint2 pk;
    pk.x = (uint)f2b(a0_[0] * i0) | ((uint)f2b(a0_[1] * i0) << 16);
    pk.y = (uint)f2b(a0_[2] * i0) | ((uint)f2b(a0_[3] * i0) << 16);
    *(uint2*)&lds_a[slot][0 * 128 + 4 * c] = pk;
    pk.x = (uint)f2b(a1_[0] * i1) | ((uint)f2b(a1_[1] * i1) << 16);
    pk.y = (uint)f2b(a1_[2] * i1) | ((uint)f2b(a1_[3] * i1) << 16);
    *(uint2*)&lds_a[slot][1 * 128 + 4 * c] = pk;
    pk.x = (uint)f2b(a2_[0] * i2) | ((uint)f2b(a2_[1] * i2) << 16);
    pk.y = (uint)f2b(a2_[2] * i2) | ((uint)f2b(a2_[3] * i2) << 16);
    *(uint2*)&lds_a[slot][2 * 128 + 4 * c] = pk;
    pk.x = (uint)f2b(a3_[0] * i3) | ((uint)f2b(a3_[1] * i3) << 16);
    pk.y = (uint)f2b(a3_[2] * i3) | ((uint)f2b(a3_[3] * i3) << 16);
    *(uint2*)&lds_a[slot][3 * 128 + 4 * c] = pk;
    __syncthreads();

    // fused gemm2: wave wv computes out cols wv*16..+15 for the block's 8 nodes (K=512 MFMA)
    int m = lane & 15, quad = lane >> 4;
    const bf16x8* arow = (const bf16x8*)&lds_a[m & 7][0];  // rows 8..15 alias 0..7 (discarded)
    const bf16x8* brow = (const bf16x8*)(W2sT + (size_t)(wv * 16 + m) * 512);
    floatx4 acc2 = {};
#pragma unroll
    for (int kk = 0; kk < 16; ++kk)
        acc2 = __builtin_amdgcn_mfma_f32_16x16x32_bf16(arow[4 * kk + quad], brow[4 * kk + quad], acc2, 0, 0, 0);
    float bb = b2[wv * 16 + m];
#pragma unroll
    for (int r = 0; r < 4; ++r) {
        int row = quad * 4 + r;  // C/D: col=lane&15, row=quad*4+r
        if (row < 8) {
            int node = blockIdx.x * 8 + row;
            if (node < N) outp[(size_t)node * 64 + wv * 16 + m] = acc2[r] + bb;
        }
    }
}

// ---------------- launch ----------------
extern "C" void kernel_launch(void* const* d_in, const int* in_sizes, int n_in,
                              void* d_out, int out_size, void* d_ws, size_t ws_size,
                              hipStream_t stream) {
    // setup_inputs order: x, edge_index, W1, att_src1, att_dst1, bias1, W2, att_src2, att_dst2, bias2
    const void* x_raw = d_in[0];
    const int*  ei    = (const int*)d_in[1];
    const void* W1_p  = d_in[2];
    const void* as1_p = d_in[3];
    const void* ad1_p = d_in[4];
    const void* b1_p  = d_in[5];
    const void* W2_p  = d_in[6];
    const void* as2_p = d_in[7];
    const void* ad2_p = d_in[8];
    const void* b2_p  = d_in[9];

    const int F_IN = 128;
    const int N = in_sizes[0] / F_IN;   // 50000
    const int E = in_sizes[1] / 2;      // 800000
    const int ET = E + N;
    const int NB = (N + 1023) / 1024;
    const int NBUK = (N + 255) >> 8;    // buckets; packed path needs N<=65536

    char* p = (char*)d_ws;
    auto alloc = [&](size_t bytes) { char* r = p; p += (bytes + 255) & ~(size_t)255; return r; };
    ushort* xbf   = (ushort*)alloc((size_t)N * 128 * 2);
    ushort* W1T   = (ushort*)alloc(128 * 128 * 2);
    ushort* W2sT  = (ushort*)alloc(64 * 512 * 2);
    float*  att1f = (float*)alloc(256 * 4);
    float*  w2t8  = (float*)alloc(8 * 128 * 4);
    float*  b1f   = (float*)alloc(128 * 4);
    float*  b2f   = (float*)alloc(64 * 4);
    ushort* h1    = (ushort*)alloc((size_t)N * 128 * 2);
    ushort* hL1   = (ushort*)alloc((size_t)N * 128 * 2);
    float*  asrc1 = (float*)alloc((size_t)N * 4 * 4);
    float*  adst1 = (float*)alloc((size_t)N * 4 * 4);
    float*  asrc2 = (float*)alloc((size_t)N * 4 * 4);
    float*  adst2 = (float*)alloc((size_t)N * 4 * 4);
    int* deg    = (int*)alloc((size_t)N * 4);   // fallback only
    int* cnt    = (int*)alloc((size_t)N * 4);   // fallback only
    int* tmp    = (int*)alloc((size_t)N * 4);   // fallback only
    int* bsum   = (int*)alloc(128 * 4);         // fallback only
    int* rowptr = (int*)alloc((size_t)(N + 1) * 4);
    int* ecol   = (int*)alloc((size_t)ET * 4);
    uint* ebuf  = (uint*)alloc((size_t)ET * 4);
    int* bcnt   = (int*)alloc(256 * 4);
    int* bbase  = (int*)alloc(257 * 4);
    int* gcur   = (int*)alloc(256 * 4);
    int* flagI  = (int*)alloc(256);
    int* flagF  = (int*)alloc(256);

    detect_kernel<<<1, 256, 0, stream>>>(ei, x_raw, flagI, flagF);

    int NX = N * F_IN;
    int nxb = (NX + 255) / 256;
    // prep args: x, W1, as1, ad1, b1, b2  (d_in 0, 2, 3, 4, 5, 9)
    prep_kernel<<<nxb + 64 + 2, 256, 0, stream>>>(
        x_raw, W1_p, as1_p, ad1_p, b1_p, b2_p, xbf, W1T, att1f, b1f, b2f, NX, flagF);
    // prep2 args: W2, as2, ad2  (d_in 6, 7, 8)
    prep2_kernel<<<4 + 128, 256, 0, stream>>>(W2_p, as2_p, ad2_p, w2t8, W2sT, flagF);

    if (N <= 65536) {  // bucketed locality-aware CSR: 4 dispatches
        hipMemsetAsync(bcnt, 0, 256 * 4, stream);
        bhist_kernel<<<(ET + 4095) / 4096, 256, 0, stream>>>(ei, E, ET, flagI, bcnt);
        bscan_kernel<<<1, 256, 0, stream>>>(bcnt, bbase, gcur, NBUK);
        part_kernel<<<(ET + 8191) / 8192, 256, 0, stream>>>(ei, E, ET, flagI, gcur, ebuf, NBUK);
        bfinal_kernel<<<NBUK, 256, 0, stream>>>(ebuf, bbase, rowptr, ecol, N, NBUK);
    } else {  // fallback: random-scatter path
        hipMemsetAsync(deg, 0, (size_t)N * 4, stream);
        int eblocks = (ET + 255) / 256;
        hist_kernel<<<eblocks, 256, 0, stream>>>(ei, E, N, flagI, deg);
        scan1_kernel<<<NB, 1024, 0, stream>>>(deg, tmp, bsum, N);
        scan2_kernel<<<1, 64, 0, stream>>>(bsum, NB);
        scan3_kernel<<<(N + 256) / 256, 256, 0, stream>>>(tmp, bsum, rowptr, cnt, N, NB);
        scatter_kernel<<<eblocks, 256, 0, stream>>>(ei, E, N, flagI, rowptr, cnt, ecol);
    }

    int nblocks8 = (N + 7) / 8;
    int gblocks = (N + 63) / 64;
    // ---- layer 1 ----
    gemm1_kernel<<<gblocks, 256, 0, stream>>>(
        x_raw, xbf, flagF, W1T, h1, att1f, (float4*)asrc1, (float4*)adst1, N);
    agg1_kernel<<<nblocks8, 256, 0, stream>>>(
        h1, (const float4*)asrc1, (const float4*)adst1, rowptr, ecol, b1f, w2t8,
        (uint2*)hL1, (float4*)asrc2, (float4*)adst2, N);
    // ---- layer 2 (agg + output GEMM fused) ----
    agg2_kernel<<<nblocks8, 256, 0, stream>>>(
        hL1, (const float4*)asrc2, (const float4*)adst2, rowptr, ecol, W2sT, b2f,
        (float*)d_out, N);
}